// Round 1
// baseline (5379.641 us; speedup 1.0000x reference)
//
#include <hip/hip_runtime.h>
#include <math.h>

#define N_NODES 100000
#define N_EDGES 1600000   // directed; doubled logically
#define H 10              // node/edge feature dim
#define HID 64            // hidden

#define E2 (2 * N_EDGES)

__device__ __forceinline__ float sigmoidf_(float x) {
    return 1.0f / (1.0f + __expf(-x));
}
__device__ __forceinline__ float tanhf_(float x) {
    float ax = fabsf(x);
    float t = 1.0f - 2.0f / (__expf(2.0f * ax) + 1.0f);
    return copysignf(t, x);
}

// One thread per directed edge. Weights staged in LDS (wave-uniform broadcast
// reads). Activations in registers with fully-static indexing. Layer 3 fused
// into layer-2 output loop so only one 64-wide live array (m1) is needed.
__global__ __launch_bounds__(256) void edge_mlp_kernel(
    const float* __restrict__ h,       // [N, H]
    const int*   __restrict__ edges,   // [2, E] flat
    const float* __restrict__ W1, const float* __restrict__ b1,   // [64,20],[64]
    const float* __restrict__ W2, const float* __restrict__ b2,   // [64,64],[64]
    const float* __restrict__ W3, const float* __restrict__ b3,   // [10,64],[10]
    float* __restrict__ a)             // [N, H] accumulators (pre-zeroed)
{
    __shared__ float sW1T[2 * H * HID];   // [k][j] transposed: 1280
    __shared__ float sb1[HID];
    __shared__ float sW2[HID * HID];      // row-major [j][k]: 4096
    __shared__ float sb2[HID];
    __shared__ float sW3T[HID * H];       // [j][o] transposed: 640
    __shared__ float sb3[H];

    for (int i = threadIdx.x; i < 2 * H * HID; i += blockDim.x) {
        int k = i >> 6, j = i & 63;
        sW1T[i] = W1[j * (2 * H) + k];
    }
    for (int i = threadIdx.x; i < HID * HID; i += blockDim.x) sW2[i] = W2[i];
    for (int i = threadIdx.x; i < HID * H; i += blockDim.x) {
        int j = i / H, o = i - j * H;
        sW3T[i] = W3[o * HID + j];
    }
    if (threadIdx.x < HID) { sb1[threadIdx.x] = b1[threadIdx.x]; sb2[threadIdx.x] = b2[threadIdx.x]; }
    if (threadIdx.x < H)   { sb3[threadIdx.x] = b3[threadIdx.x]; }
    __syncthreads();

    int e = blockIdx.x * blockDim.x + threadIdx.x;
    if (e >= E2) return;

    // src = concat(edges[0], edges[1]) => edges_flat[e] for all e in [0,2E)
    // dst = concat(edges[1], edges[0])
    int s = edges[e];
    int d = (e < N_EDGES) ? edges[N_EDGES + e] : edges[e - N_EDGES];

    const float* hs = h + (size_t)s * H;
    const float* hd = h + (size_t)d * H;

    // ---- layer 1: m1[j] = relu(b1[j] + sum_k W1[j][k]*hs[k] + W1[j][10+k]*hd[k])
    float m1[HID];
    #pragma unroll
    for (int j = 0; j < HID; ++j) m1[j] = sb1[j];

    for (int k = 0; k < H; ++k) {           // dynamic outer (small)
        float xs = hs[k];
        float xd = hd[k];
        const float* w_s = &sW1T[k * HID];
        const float* w_d = &sW1T[(H + k) * HID];
        #pragma unroll
        for (int j = 0; j < HID; ++j) {
            m1[j] = fmaf(w_s[j], xs, m1[j]);
            m1[j] = fmaf(w_d[j], xd, m1[j]);
        }
    }
    #pragma unroll
    for (int j = 0; j < HID; ++j) m1[j] = fmaxf(m1[j], 0.0f);

    // ---- layer 2 (relu) fused with layer 3 accumulation
    float out[H];
    #pragma unroll
    for (int o = 0; o < H; ++o) out[o] = sb3[o];

    for (int j = 0; j < HID; ++j) {         // dynamic outer
        float acc = sb2[j];
        const float* w = &sW2[j * HID];
        #pragma unroll
        for (int k = 0; k < HID; ++k) acc = fmaf(w[k], m1[k], acc);
        acc = fmaxf(acc, 0.0f);
        const float* w3 = &sW3T[j * H];
        #pragma unroll
        for (int o = 0; o < H; ++o) out[o] = fmaf(w3[o], acc, out[o]);
    }

    // ---- scatter-add into a[src]
    float* as = a + (size_t)s * H;
    #pragma unroll
    for (int o = 0; o < H; ++o) atomicAdd(&as[o], out[o]);
}

// One thread per node: single-step GRU. h update is elementwise per node, so
// in-place (h_in == h_out) is safe.
__global__ __launch_bounds__(256) void gru_kernel(
    const float* __restrict__ h_in,    // [N, H]
    const float* __restrict__ a,       // [N, H]
    float* __restrict__ h_out,         // [N, H]
    const float* __restrict__ W_ih, const float* __restrict__ b_ih,  // [30,10],[30]
    const float* __restrict__ W_hh, const float* __restrict__ b_hh)  // [30,10],[30]
{
    __shared__ float sWih[3 * H * H];   // 300
    __shared__ float sWhh[3 * H * H];   // 300
    __shared__ float sbih[3 * H];
    __shared__ float sbhh[3 * H];
    for (int i = threadIdx.x; i < 3 * H * H; i += blockDim.x) { sWih[i] = W_ih[i]; sWhh[i] = W_hh[i]; }
    if (threadIdx.x < 3 * H) { sbih[threadIdx.x] = b_ih[threadIdx.x]; sbhh[threadIdx.x] = b_hh[threadIdx.x]; }
    __syncthreads();

    int n = blockIdx.x * blockDim.x + threadIdx.x;
    if (n >= N_NODES) return;

    float av[H], hv[H];
    #pragma unroll
    for (int k = 0; k < H; ++k) { av[k] = a[(size_t)n * H + k]; hv[k] = h_in[(size_t)n * H + k]; }

    float gi[3 * H], gh[3 * H];
    #pragma unroll
    for (int g = 0; g < 3 * H; ++g) {
        float ai = sbih[g], hh = sbhh[g];
        const float* wi = &sWih[g * H];
        const float* wh = &sWhh[g * H];
        #pragma unroll
        for (int k = 0; k < H; ++k) {
            ai = fmaf(wi[k], av[k], ai);
            hh = fmaf(wh[k], hv[k], hh);
        }
        gi[g] = ai; gh[g] = hh;
    }

    #pragma unroll
    for (int o = 0; o < H; ++o) {
        float r = sigmoidf_(gi[o] + gh[o]);
        float z = sigmoidf_(gi[H + o] + gh[H + o]);
        float nn = tanhf_(gi[2 * H + o] + r * gh[2 * H + o]);
        h_out[(size_t)n * H + o] = (1.0f - z) * nn + z * hv[o];
    }
}

extern "C" void kernel_launch(void* const* d_in, const int* in_sizes, int n_in,
                              void* d_out, int out_size, void* d_ws, size_t ws_size,
                              hipStream_t stream) {
    const float* node_features = (const float*)d_in[0];
    const int*   edges         = (const int*)d_in[1];
    const float* W1 = (const float*)d_in[2];
    const float* b1 = (const float*)d_in[3];
    const float* W2 = (const float*)d_in[4];
    const float* b2 = (const float*)d_in[5];
    const float* W3 = (const float*)d_in[6];
    const float* b3 = (const float*)d_in[7];
    const float* W_ih = (const float*)d_in[8];
    const float* b_ih = (const float*)d_in[9];
    const float* W_hh = (const float*)d_in[10];
    const float* b_hh = (const float*)d_in[11];

    float* a    = (float*)d_ws;            // N_NODES*H floats = 4 MB
    float* hbuf = (float*)d_out;           // h lives in d_out; GRU updates in place

    const int edge_blocks = E2 / 256;              // 12500 exact
    const int node_blocks = (N_NODES + 255) / 256;

    for (int it = 0; it < 3; ++it) {
        hipMemsetAsync(a, 0, (size_t)N_NODES * H * sizeof(float), stream);
        const float* hin = (it == 0) ? node_features : hbuf;
        edge_mlp_kernel<<<edge_blocks, 256, 0, stream>>>(
            hin, edges, W1, b1, W2, b2, W3, b3, a);
        gru_kernel<<<node_blocks, 256, 0, stream>>>(
            hin, a, hbuf, W_ih, b_ih, W_hh, b_hh);
    }
}

// Round 2
// 4473.262 us; speedup vs baseline: 1.2026x; 1.2026x over previous
//
#include <hip/hip_runtime.h>
#include <math.h>

#define N_NODES 100000
#define N_EDGES 1600000
#define H 10
#define HID 64
#define E2 (2 * N_EDGES)          // 3,200,000 (divisible by 256: 12500 blocks)
#define SCAN_CHUNK 1024           // elements per scan1 block (256 thr x 4)
#define NB_SCAN ((N_NODES + SCAN_CHUNK - 1) / SCAN_CHUNK)   // 98

__device__ __forceinline__ float sigmoidf_(float x) {
    return 1.0f / (1.0f + __expf(-x));
}
__device__ __forceinline__ float tanhf_(float x) {
    float ax = fabsf(x);
    float t = 1.0f - 2.0f / (__expf(2.0f * ax) + 1.0f);
    return copysignf(t, x);
}

// ---------------- CSR build (once per launch; edges are static) -------------

__global__ __launch_bounds__(256) void hist_kernel(
    const int* __restrict__ edges, int* __restrict__ cnt)
{
    int e = blockIdx.x * 256 + threadIdx.x;   // e in [0, E2); src list = edges[0..2E)
    if (e < E2) atomicAdd(&cnt[edges[e]], 1);
}

// per-block (1024-elem) exclusive scan; partials[b] = block total
__global__ __launch_bounds__(256) void scan1_kernel(
    const int* __restrict__ cnt, int* __restrict__ excl, int* __restrict__ partials)
{
    __shared__ int sdata[256];
    int tid = threadIdx.x;
    int base = blockIdx.x * SCAN_CHUNK + tid * 4;
    int v0 = (base + 0 < N_NODES) ? cnt[base + 0] : 0;
    int v1 = (base + 1 < N_NODES) ? cnt[base + 1] : 0;
    int v2 = (base + 2 < N_NODES) ? cnt[base + 2] : 0;
    int v3 = (base + 3 < N_NODES) ? cnt[base + 3] : 0;
    int sum = v0 + v1 + v2 + v3;
    sdata[tid] = sum;
    __syncthreads();
    for (int off = 1; off < 256; off <<= 1) {
        int t = (tid >= off) ? sdata[tid - off] : 0;
        __syncthreads();
        sdata[tid] += t;
        __syncthreads();
    }
    int run = sdata[tid] - sum;   // exclusive base for this thread
    if (tid == 255) partials[blockIdx.x] = sdata[255];
    if (base + 0 < N_NODES) { excl[base + 0] = run; run += v0; }
    if (base + 1 < N_NODES) { excl[base + 1] = run; run += v1; }
    if (base + 2 < N_NODES) { excl[base + 2] = run; run += v2; }
    if (base + 3 < N_NODES) { excl[base + 3] = run; run += v3; }
}

__global__ void scan2_kernel(int* partials, int nb) {
    if (threadIdx.x == 0 && blockIdx.x == 0) {
        int run = 0;
        for (int b = 0; b < nb; ++b) { int t = partials[b]; partials[b] = run; run += t; }
    }
}

__global__ __launch_bounds__(256) void scan3_kernel(
    int* __restrict__ excl, const int* __restrict__ partials)
{
    int i = blockIdx.x * 256 + threadIdx.x;
    if (i < N_NODES) excl[i] += partials[i / SCAN_CHUNK];
}

// scatter edge pairs into src-sorted order; cursor starts as exclusive offsets
__global__ __launch_bounds__(256) void scatter_kernel(
    const int* __restrict__ edges, int* __restrict__ cursor, int2* __restrict__ pairs)
{
    int e = blockIdx.x * 256 + threadIdx.x;
    if (e >= E2) return;
    int s = edges[e];
    int d = (e < N_EDGES) ? edges[N_EDGES + e] : edges[e - N_EDGES];
    int pos = atomicAdd(&cursor[s], 1);
    pairs[pos] = make_int2(s, d);
}

// ---------------- per-iteration kernels -------------------------------------

// One thread per (src-sorted) edge. Weights in LDS; block-level segmented
// reduction over the sorted src runs: only segment leaders atomicAdd.
__global__ __launch_bounds__(256) void edge_mlp_csr_kernel(
    const float* __restrict__ h,
    const int2*  __restrict__ pairs,
    const float* __restrict__ W1, const float* __restrict__ b1,
    const float* __restrict__ W2, const float* __restrict__ b2,
    const float* __restrict__ W3, const float* __restrict__ b3,
    float* __restrict__ a)
{
    __shared__ float sW1T[2 * H * HID];
    __shared__ float sb1[HID];
    __shared__ float sW2[HID * HID];
    __shared__ float sb2[HID];
    __shared__ float sW3T[HID * H];
    __shared__ float sb3[H];
    __shared__ int   sseg[256];
    __shared__ float smsg[256 * (H + 1)];   // pad 11: odd stride -> conflict-free

    for (int i = threadIdx.x; i < 2 * H * HID; i += blockDim.x) {
        int k = i >> 6, j = i & 63;
        sW1T[i] = W1[j * (2 * H) + k];
    }
    for (int i = threadIdx.x; i < HID * HID; i += blockDim.x) sW2[i] = W2[i];
    for (int i = threadIdx.x; i < HID * H; i += blockDim.x) {
        int j = i / H, o = i - j * H;
        sW3T[i] = W3[o * HID + j];
    }
    if (threadIdx.x < HID) { sb1[threadIdx.x] = b1[threadIdx.x]; sb2[threadIdx.x] = b2[threadIdx.x]; }
    if (threadIdx.x < H)   { sb3[threadIdx.x] = b3[threadIdx.x]; }
    __syncthreads();

    const int tid = threadIdx.x;
    const int k = blockIdx.x * 256 + tid;   // E2 % 256 == 0, no guard needed
    int2 p = pairs[k];
    const float* hs = h + (size_t)p.x * H;
    const float* hd = h + (size_t)p.y * H;

    float m1[HID];
    #pragma unroll
    for (int j = 0; j < HID; ++j) m1[j] = sb1[j];
    for (int kk = 0; kk < H; ++kk) {
        float xs = hs[kk];
        float xd = hd[kk];
        const float* w_s = &sW1T[kk * HID];
        const float* w_d = &sW1T[(H + kk) * HID];
        #pragma unroll
        for (int j = 0; j < HID; ++j) {
            m1[j] = fmaf(w_s[j], xs, m1[j]);
            m1[j] = fmaf(w_d[j], xd, m1[j]);
        }
    }
    #pragma unroll
    for (int j = 0; j < HID; ++j) m1[j] = fmaxf(m1[j], 0.0f);

    float out[H];
    #pragma unroll
    for (int o = 0; o < H; ++o) out[o] = sb3[o];
    for (int j = 0; j < HID; ++j) {
        float acc = sb2[j];
        const float* w = &sW2[j * HID];
        #pragma unroll
        for (int kk = 0; kk < HID; ++kk) acc = fmaf(w[kk], m1[kk], acc);
        acc = fmaxf(acc, 0.0f);
        const float* w3 = &sW3T[j * H];
        #pragma unroll
        for (int o = 0; o < H; ++o) out[o] = fmaf(w3[o], acc, out[o]);
    }

    // ---- block-level segmented reduction over sorted src ----
    sseg[tid] = p.x;
    #pragma unroll
    for (int o = 0; o < H; ++o) smsg[tid * (H + 1) + o] = out[o];
    __syncthreads();

    bool leader = (tid == 0) || (sseg[tid - 1] != p.x);
    if (leader) {
        float acc[H];
        #pragma unroll
        for (int o = 0; o < H; ++o) acc[o] = smsg[tid * (H + 1) + o];
        int i = tid + 1;
        while (i < 256 && sseg[i] == p.x) {
            #pragma unroll
            for (int o = 0; o < H; ++o) acc[o] += smsg[i * (H + 1) + o];
            ++i;
        }
        float* as = a + (size_t)p.x * H;
        #pragma unroll
        for (int o = 0; o < H; ++o) atomicAdd(&as[o], acc[o]);
    }
}

// Fallback path (no CSR workspace): round-1 edge kernel
__global__ __launch_bounds__(256) void edge_mlp_kernel(
    const float* __restrict__ h,
    const int*   __restrict__ edges,
    const float* __restrict__ W1, const float* __restrict__ b1,
    const float* __restrict__ W2, const float* __restrict__ b2,
    const float* __restrict__ W3, const float* __restrict__ b3,
    float* __restrict__ a)
{
    __shared__ float sW1T[2 * H * HID];
    __shared__ float sb1[HID];
    __shared__ float sW2[HID * HID];
    __shared__ float sb2[HID];
    __shared__ float sW3T[HID * H];
    __shared__ float sb3[H];
    for (int i = threadIdx.x; i < 2 * H * HID; i += blockDim.x) {
        int k = i >> 6, j = i & 63;
        sW1T[i] = W1[j * (2 * H) + k];
    }
    for (int i = threadIdx.x; i < HID * HID; i += blockDim.x) sW2[i] = W2[i];
    for (int i = threadIdx.x; i < HID * H; i += blockDim.x) {
        int j = i / H, o = i - j * H;
        sW3T[i] = W3[o * HID + j];
    }
    if (threadIdx.x < HID) { sb1[threadIdx.x] = b1[threadIdx.x]; sb2[threadIdx.x] = b2[threadIdx.x]; }
    if (threadIdx.x < H)   { sb3[threadIdx.x] = b3[threadIdx.x]; }
    __syncthreads();
    int e = blockIdx.x * blockDim.x + threadIdx.x;
    if (e >= E2) return;
    int s = edges[e];
    int d = (e < N_EDGES) ? edges[N_EDGES + e] : edges[e - N_EDGES];
    const float* hs = h + (size_t)s * H;
    const float* hd = h + (size_t)d * H;
    float m1[HID];
    #pragma unroll
    for (int j = 0; j < HID; ++j) m1[j] = sb1[j];
    for (int k = 0; k < H; ++k) {
        float xs = hs[k], xd = hd[k];
        const float* w_s = &sW1T[k * HID];
        const float* w_d = &sW1T[(H + k) * HID];
        #pragma unroll
        for (int j = 0; j < HID; ++j) {
            m1[j] = fmaf(w_s[j], xs, m1[j]);
            m1[j] = fmaf(w_d[j], xd, m1[j]);
        }
    }
    #pragma unroll
    for (int j = 0; j < HID; ++j) m1[j] = fmaxf(m1[j], 0.0f);
    float out[H];
    #pragma unroll
    for (int o = 0; o < H; ++o) out[o] = sb3[o];
    for (int j = 0; j < HID; ++j) {
        float acc = sb2[j];
        const float* w = &sW2[j * HID];
        #pragma unroll
        for (int k = 0; k < HID; ++k) acc = fmaf(w[k], m1[k], acc);
        acc = fmaxf(acc, 0.0f);
        const float* w3 = &sW3T[j * H];
        #pragma unroll
        for (int o = 0; o < H; ++o) out[o] = fmaf(w3[o], acc, out[o]);
    }
    float* as = a + (size_t)s * H;
    #pragma unroll
    for (int o = 0; o < H; ++o) atomicAdd(&as[o], out[o]);
}

__global__ __launch_bounds__(256) void gru_kernel(
    const float* __restrict__ h_in,
    const float* __restrict__ a,
    float* __restrict__ h_out,
    const float* __restrict__ W_ih, const float* __restrict__ b_ih,
    const float* __restrict__ W_hh, const float* __restrict__ b_hh)
{
    __shared__ float sWih[3 * H * H];
    __shared__ float sWhh[3 * H * H];
    __shared__ float sbih[3 * H];
    __shared__ float sbhh[3 * H];
    for (int i = threadIdx.x; i < 3 * H * H; i += blockDim.x) { sWih[i] = W_ih[i]; sWhh[i] = W_hh[i]; }
    if (threadIdx.x < 3 * H) { sbih[threadIdx.x] = b_ih[threadIdx.x]; sbhh[threadIdx.x] = b_hh[threadIdx.x]; }
    __syncthreads();

    int n = blockIdx.x * blockDim.x + threadIdx.x;
    if (n >= N_NODES) return;

    float av[H], hv[H];
    #pragma unroll
    for (int k = 0; k < H; ++k) { av[k] = a[(size_t)n * H + k]; hv[k] = h_in[(size_t)n * H + k]; }

    float gi[3 * H], gh[3 * H];
    #pragma unroll
    for (int g = 0; g < 3 * H; ++g) {
        float ai = sbih[g], hh = sbhh[g];
        const float* wi = &sWih[g * H];
        const float* wh = &sWhh[g * H];
        #pragma unroll
        for (int k = 0; k < H; ++k) {
            ai = fmaf(wi[k], av[k], ai);
            hh = fmaf(wh[k], hv[k], hh);
        }
        gi[g] = ai; gh[g] = hh;
    }

    #pragma unroll
    for (int o = 0; o < H; ++o) {
        float r = sigmoidf_(gi[o] + gh[o]);
        float z = sigmoidf_(gi[H + o] + gh[H + o]);
        float nn = tanhf_(gi[2 * H + o] + r * gh[2 * H + o]);
        h_out[(size_t)n * H + o] = (1.0f - z) * nn + z * hv[o];
    }
}

static inline size_t align256(size_t x) { return (x + 255) & ~(size_t)255; }

extern "C" void kernel_launch(void* const* d_in, const int* in_sizes, int n_in,
                              void* d_out, int out_size, void* d_ws, size_t ws_size,
                              hipStream_t stream) {
    const float* node_features = (const float*)d_in[0];
    const int*   edges         = (const int*)d_in[1];
    const float* W1 = (const float*)d_in[2];
    const float* b1 = (const float*)d_in[3];
    const float* W2 = (const float*)d_in[4];
    const float* b2 = (const float*)d_in[5];
    const float* W3 = (const float*)d_in[6];
    const float* b3 = (const float*)d_in[7];
    const float* W_ih = (const float*)d_in[8];
    const float* b_ih = (const float*)d_in[9];
    const float* W_hh = (const float*)d_in[10];
    const float* b_hh = (const float*)d_in[11];

    char* ws = (char*)d_ws;
    size_t off = 0;
    float* a = (float*)(ws + off);          off = align256(off + (size_t)N_NODES * H * sizeof(float));
    int* cnt = (int*)(ws + off);            off = align256(off + (size_t)N_NODES * sizeof(int));
    int* cursor = (int*)(ws + off);         off = align256(off + (size_t)N_NODES * sizeof(int));
    int* partials = (int*)(ws + off);       off = align256(off + (size_t)NB_SCAN * sizeof(int));
    int2* pairs = (int2*)(ws + off);        off = align256(off + (size_t)E2 * sizeof(int2));
    const bool use_csr = (ws_size >= off);

    float* hbuf = (float*)d_out;
    const int edge_blocks = E2 / 256;                 // 12500
    const int node_blocks = (N_NODES + 255) / 256;    // 391

    if (use_csr) {
        hipMemsetAsync(cnt, 0, (size_t)N_NODES * sizeof(int), stream);
        hist_kernel<<<edge_blocks, 256, 0, stream>>>(edges, cnt);
        scan1_kernel<<<NB_SCAN, 256, 0, stream>>>(cnt, cursor, partials);
        scan2_kernel<<<1, 64, 0, stream>>>(partials, NB_SCAN);
        scan3_kernel<<<node_blocks, 256, 0, stream>>>(cursor, partials);
        scatter_kernel<<<edge_blocks, 256, 0, stream>>>(edges, cursor, pairs);
    }

    for (int it = 0; it < 3; ++it) {
        hipMemsetAsync(a, 0, (size_t)N_NODES * H * sizeof(float), stream);
        const float* hin = (it == 0) ? node_features : hbuf;
        if (use_csr) {
            edge_mlp_csr_kernel<<<edge_blocks, 256, 0, stream>>>(
                hin, pairs, W1, b1, W2, b2, W3, b3, a);
        } else {
            edge_mlp_kernel<<<edge_blocks, 256, 0, stream>>>(
                hin, edges, W1, b1, W2, b2, W3, b3, a);
        }
        gru_kernel<<<node_blocks, 256, 0, stream>>>(
            hin, a, hbuf, W_ih, b_ih, W_hh, b_hh);
    }
}

// Round 3
// 1356.913 us; speedup vs baseline: 3.9646x; 3.2966x over previous
//
#include <hip/hip_runtime.h>
#include <hip/hip_bf16.h>
#include <math.h>

#define N_NODES 100000
#define N_EDGES 1600000
#define H 10
#define HID 64
#define E2 (2 * N_EDGES)          // 3,200,000 (12500 blocks of 256)
#define SCAN_CHUNK 1024
#define NB_SCAN ((N_NODES + SCAN_CHUNK - 1) / SCAN_CHUNK)   // 98

typedef __attribute__((ext_vector_type(8))) short short8;
typedef __attribute__((ext_vector_type(4))) float f32x4;
typedef __attribute__((ext_vector_type(2))) unsigned int uint2v;
typedef __attribute__((ext_vector_type(4))) unsigned int uint4v;

#define MFMA16(a, b, c) __builtin_amdgcn_mfma_f32_16x16x32_bf16((a), (b), (c), 0, 0, 0)

__device__ __forceinline__ float sigmoidf_(float x) {
    return 1.0f / (1.0f + __expf(-x));
}
__device__ __forceinline__ float tanhf_(float x) {
    float ax = fabsf(x);
    float t = 1.0f - 2.0f / (__expf(2.0f * ax) + 1.0f);
    return copysignf(t, x);
}
__device__ __forceinline__ unsigned short f2bf(float f) {
    union { __hip_bfloat16 b; unsigned short u; } cv;
    cv.b = __float2bfloat16(f);   // RNE
    return cv.u;
}
__device__ __forceinline__ unsigned pack2(float lo, float hi) {
    return (unsigned)f2bf(lo) | ((unsigned)f2bf(hi) << 16);
}

// ---------------- CSR build (once per launch; edges static) -----------------

__global__ __launch_bounds__(256) void hist_kernel(
    const int* __restrict__ edges, int* __restrict__ cnt)
{
    int e = blockIdx.x * 256 + threadIdx.x;
    if (e < E2) atomicAdd(&cnt[edges[e]], 1);
}

__global__ __launch_bounds__(256) void scan1_kernel(
    const int* __restrict__ cnt, int* __restrict__ excl, int* __restrict__ partials)
{
    __shared__ int sdata[256];
    int tid = threadIdx.x;
    int base = blockIdx.x * SCAN_CHUNK + tid * 4;
    int v0 = (base + 0 < N_NODES) ? cnt[base + 0] : 0;
    int v1 = (base + 1 < N_NODES) ? cnt[base + 1] : 0;
    int v2 = (base + 2 < N_NODES) ? cnt[base + 2] : 0;
    int v3 = (base + 3 < N_NODES) ? cnt[base + 3] : 0;
    int sum = v0 + v1 + v2 + v3;
    sdata[tid] = sum;
    __syncthreads();
    for (int off = 1; off < 256; off <<= 1) {
        int t = (tid >= off) ? sdata[tid - off] : 0;
        __syncthreads();
        sdata[tid] += t;
        __syncthreads();
    }
    int run = sdata[tid] - sum;
    if (tid == 255) partials[blockIdx.x] = sdata[255];
    if (base + 0 < N_NODES) { excl[base + 0] = run; run += v0; }
    if (base + 1 < N_NODES) { excl[base + 1] = run; run += v1; }
    if (base + 2 < N_NODES) { excl[base + 2] = run; run += v2; }
    if (base + 3 < N_NODES) { excl[base + 3] = run; run += v3; }
}

__global__ void scan2_kernel(int* partials, int nb) {
    if (threadIdx.x == 0 && blockIdx.x == 0) {
        int run = 0;
        for (int b = 0; b < nb; ++b) { int t = partials[b]; partials[b] = run; run += t; }
    }
}

__global__ __launch_bounds__(256) void scan3_kernel(
    int* __restrict__ excl, const int* __restrict__ partials)
{
    int i = blockIdx.x * 256 + threadIdx.x;
    if (i < N_NODES) excl[i] += partials[i / SCAN_CHUNK];
}

__global__ __launch_bounds__(256) void scatter_kernel(
    const int* __restrict__ edges, int* __restrict__ cursor, int2* __restrict__ pairs)
{
    int e = blockIdx.x * 256 + threadIdx.x;
    if (e >= E2) return;
    int s = edges[e];
    int d = (e < N_EDGES) ? edges[N_EDGES + e] : edges[e - N_EDGES];
    int pos = atomicAdd(&cursor[s], 1);
    pairs[pos] = make_int2(s, d);
}

// ---------------- MFMA edge MLP ---------------------------------------------
// Block = 256 threads = 4 waves; block processes 256 src-sorted edges.
// Wave w owns edge-rows [w*64, w*64+64) as 4 m-tiles of 16.
// X buffer [256][72 bf16] (144B stride); GEMMs computed as D = W * X^T so each
// thread holds 4 consecutive next-layer-k values for one edge-row.

#define XSTRIDE 144   // bytes per row (72 bf16), 16B-aligned, 2-way-free banks
#define OSTRIDE 80    // bytes per row of f32 out (20 f32)

__global__ __launch_bounds__(256) void edge_mlp_mfma_kernel(
    const float* __restrict__ h,
    const int2*  __restrict__ pairs,
    const float* __restrict__ W1, const float* __restrict__ b1,
    const float* __restrict__ W2, const float* __restrict__ b2,
    const float* __restrict__ W3, const float* __restrict__ b3,
    float* __restrict__ a)
{
    __shared__ __align__(16) unsigned char sX[256 * XSTRIDE];  // 36864 B
    __shared__ int sseg[256];
    __shared__ __align__(16) float sB1[64];
    __shared__ __align__(16) float sB2[64];
    __shared__ __align__(16) float sB3[16];

    char* sXp = (char*)sX;
    const int t = threadIdx.x;
    const int l = t & 63, w = t >> 6;
    const int lo4 = l >> 4, l15 = l & 15;
    const int mbase = w * 64;

    // ---- bias staging
    if (t < 64) { sB1[t] = b1[t]; sB2[t] = b2[t]; }
    if (t < 16) { sB3[t] = (t < 10) ? b3[t] : 0.0f; }

    // ---- weight fragments (A-operand: lane l15 = W-row, lo4*8+i = k)
    short8 W1f[4];
    #pragma unroll
    for (int nt = 0; nt < 4; ++nt) {
        const float* wr = W1 + (nt * 16 + l15) * 20;
        #pragma unroll
        for (int i = 0; i < 8; ++i) {
            int k = lo4 * 8 + i;
            W1f[nt][i] = (short)((k < 20) ? f2bf(wr[k]) : (unsigned short)0);
        }
    }
    short8 W2f[4][2];
    #pragma unroll
    for (int nt = 0; nt < 4; ++nt) {
        #pragma unroll
        for (int ks = 0; ks < 2; ++ks) {
            const float* wr = W2 + (nt * 16 + l15) * 64 + ks * 32 + lo4 * 8;
            #pragma unroll
            for (int i = 0; i < 8; ++i) W2f[nt][ks][i] = (short)f2bf(wr[i]);
        }
    }
    short8 W3f[2];
    #pragma unroll
    for (int ks = 0; ks < 2; ++ks) {
        #pragma unroll
        for (int i = 0; i < 8; ++i) {
            W3f[ks][i] = (short)((l15 < 10)
                ? f2bf(W3[l15 * 64 + ks * 32 + lo4 * 8 + i]) : (unsigned short)0);
        }
    }

    // ---- gather: edge t -> X row t (cols 0..9 = h[src], 10..19 = h[dst], pad 0)
    int2 p = pairs[blockIdx.x * 256 + t];
    sseg[t] = p.x;
    const float2* hp = (const float2*)h;
    float2 s0 = hp[(size_t)p.x * 5 + 0];
    float2 s1 = hp[(size_t)p.x * 5 + 1];
    float2 s2 = hp[(size_t)p.x * 5 + 2];
    float2 s3 = hp[(size_t)p.x * 5 + 3];
    float2 s4 = hp[(size_t)p.x * 5 + 4];
    float2 d0 = hp[(size_t)p.y * 5 + 0];
    float2 d1 = hp[(size_t)p.y * 5 + 1];
    float2 d2 = hp[(size_t)p.y * 5 + 2];
    float2 d3 = hp[(size_t)p.y * 5 + 3];
    float2 d4 = hp[(size_t)p.y * 5 + 4];
    uint4v z0 = { pack2(s0.x, s0.y), pack2(s1.x, s1.y), pack2(s2.x, s2.y), pack2(s3.x, s3.y) };
    uint4v z1 = { pack2(s4.x, s4.y), pack2(d0.x, d0.y), pack2(d1.x, d1.y), pack2(d2.x, d2.y) };
    uint4v z2 = { pack2(d3.x, d3.y), pack2(d4.x, d4.y), 0u, 0u };
    uint4v z3 = { 0u, 0u, 0u, 0u };
    {
        char* row = sXp + (size_t)t * XSTRIDE;
        *(uint4v*)(row + 0)  = z0;
        *(uint4v*)(row + 16) = z1;
        *(uint4v*)(row + 32) = z2;
        *(uint4v*)(row + 48) = z3;
    }
    __syncthreads();

    // ---- GEMM1: Y1 = relu(X1 @ W1^T + b1); K=32 (1 step)
    {
        short8 Bf[4];
        #pragma unroll
        for (int mt = 0; mt < 4; ++mt)
            Bf[mt] = *(const short8*)(sXp + (size_t)(mbase + mt * 16 + l15) * XSTRIDE + lo4 * 16);
        __syncthreads();
        #pragma unroll
        for (int nt = 0; nt < 4; ++nt) {
            f32x4 bb = *(const f32x4*)(&sB1[nt * 16 + lo4 * 4]);
            #pragma unroll
            for (int mt = 0; mt < 4; ++mt) {
                f32x4 acc = bb;
                acc = MFMA16(W1f[nt], Bf[mt], acc);
                acc[0] = fmaxf(acc[0], 0.0f); acc[1] = fmaxf(acc[1], 0.0f);
                acc[2] = fmaxf(acc[2], 0.0f); acc[3] = fmaxf(acc[3], 0.0f);
                uint2v pk = { pack2(acc[0], acc[1]), pack2(acc[2], acc[3]) };
                *(uint2v*)(sXp + (size_t)(mbase + mt * 16 + l15) * XSTRIDE + nt * 32 + lo4 * 8) = pk;
            }
        }
        __syncthreads();
    }

    // ---- GEMM2: Y2 = relu(Y1 @ W2^T + b2); K=64 (2 steps)
    {
        short8 Bf[4][2];
        #pragma unroll
        for (int mt = 0; mt < 4; ++mt)
            #pragma unroll
            for (int ks = 0; ks < 2; ++ks)
                Bf[mt][ks] = *(const short8*)(sXp + (size_t)(mbase + mt * 16 + l15) * XSTRIDE + ks * 64 + lo4 * 16);
        __syncthreads();
        #pragma unroll
        for (int nt = 0; nt < 4; ++nt) {
            f32x4 bb = *(const f32x4*)(&sB2[nt * 16 + lo4 * 4]);
            #pragma unroll
            for (int mt = 0; mt < 4; ++mt) {
                f32x4 acc = bb;
                acc = MFMA16(W2f[nt][0], Bf[mt][0], acc);
                acc = MFMA16(W2f[nt][1], Bf[mt][1], acc);
                acc[0] = fmaxf(acc[0], 0.0f); acc[1] = fmaxf(acc[1], 0.0f);
                acc[2] = fmaxf(acc[2], 0.0f); acc[3] = fmaxf(acc[3], 0.0f);
                uint2v pk = { pack2(acc[0], acc[1]), pack2(acc[2], acc[3]) };
                *(uint2v*)(sXp + (size_t)(mbase + mt * 16 + l15) * XSTRIDE + nt * 32 + lo4 * 8) = pk;
            }
        }
        __syncthreads();
    }

    // ---- GEMM3: out = Y2 @ W3^T + b3; N=16 (10 valid), K=64. f32 out to LDS.
    {
        short8 Bf[4][2];
        #pragma unroll
        for (int mt = 0; mt < 4; ++mt)
            #pragma unroll
            for (int ks = 0; ks < 2; ++ks)
                Bf[mt][ks] = *(const short8*)(sXp + (size_t)(mbase + mt * 16 + l15) * XSTRIDE + ks * 64 + lo4 * 16);
        __syncthreads();
        #pragma unroll
        for (int mt = 0; mt < 4; ++mt) {
            f32x4 acc = *(const f32x4*)(&sB3[lo4 * 4]);
            acc = MFMA16(W3f[0], Bf[mt][0], acc);
            acc = MFMA16(W3f[1], Bf[mt][1], acc);
            *(f32x4*)(sXp + (size_t)(mbase + mt * 16 + l15) * OSTRIDE + lo4 * 16) = acc;
        }
        __syncthreads();
    }

    // ---- segmented inclusive scan (Hillis-Steele, 8 steps) over sorted src
    f32x4 va = *(const f32x4*)(sXp + (size_t)t * OSTRIDE + 0);
    f32x4 vb = *(const f32x4*)(sXp + (size_t)t * OSTRIDE + 16);
    float2 vc = *(const float2*)(sXp + (size_t)t * OSTRIDE + 32);
    const int myseg = p.x;
    #pragma unroll
    for (int s = 1; s < 256; s <<= 1) {
        int idx = (t >= s) ? (t - s) : 0;
        f32x4 na = *(const f32x4*)(sXp + (size_t)idx * OSTRIDE + 0);
        f32x4 nb = *(const f32x4*)(sXp + (size_t)idx * OSTRIDE + 16);
        float2 nc = *(const float2*)(sXp + (size_t)idx * OSTRIDE + 32);
        bool ok = (t >= s) && (sseg[idx] == myseg);
        __syncthreads();
        if (ok) { va += na; vb += nb; vc.x += nc.x; vc.y += nc.y; }
        *(f32x4*)(sXp + (size_t)t * OSTRIDE + 0)  = va;
        *(f32x4*)(sXp + (size_t)t * OSTRIDE + 16) = vb;
        *(float2*)(sXp + (size_t)t * OSTRIDE + 32) = vc;
        __syncthreads();
    }

    // ---- segment tails do the atomics
    if (t == 255 || sseg[t + 1] != myseg) {
        float* as = a + (size_t)myseg * H;
        atomicAdd(as + 0, va[0]); atomicAdd(as + 1, va[1]);
        atomicAdd(as + 2, va[2]); atomicAdd(as + 3, va[3]);
        atomicAdd(as + 4, vb[0]); atomicAdd(as + 5, vb[1]);
        atomicAdd(as + 6, vb[2]); atomicAdd(as + 7, vb[3]);
        atomicAdd(as + 8, vc.x);  atomicAdd(as + 9, vc.y);
    }
}

// ---------------- fallback VALU edge kernel (no CSR workspace) --------------

__global__ __launch_bounds__(256) void edge_mlp_kernel(
    const float* __restrict__ h,
    const int*   __restrict__ edges,
    const float* __restrict__ W1, const float* __restrict__ b1,
    const float* __restrict__ W2, const float* __restrict__ b2,
    const float* __restrict__ W3, const float* __restrict__ b3,
    float* __restrict__ a)
{
    __shared__ float sW1T[2 * H * HID];
    __shared__ float sb1[HID];
    __shared__ float sW2[HID * HID];
    __shared__ float sb2[HID];
    __shared__ float sW3T[HID * H];
    __shared__ float sb3[H];
    for (int i = threadIdx.x; i < 2 * H * HID; i += blockDim.x) {
        int k = i >> 6, j = i & 63;
        sW1T[i] = W1[j * (2 * H) + k];
    }
    for (int i = threadIdx.x; i < HID * HID; i += blockDim.x) sW2[i] = W2[i];
    for (int i = threadIdx.x; i < HID * H; i += blockDim.x) {
        int j = i / H, o = i - j * H;
        sW3T[i] = W3[o * HID + j];
    }
    if (threadIdx.x < HID) { sb1[threadIdx.x] = b1[threadIdx.x]; sb2[threadIdx.x] = b2[threadIdx.x]; }
    if (threadIdx.x < H)   { sb3[threadIdx.x] = b3[threadIdx.x]; }
    __syncthreads();
    int e = blockIdx.x * blockDim.x + threadIdx.x;
    if (e >= E2) return;
    int s = edges[e];
    int d = (e < N_EDGES) ? edges[N_EDGES + e] : edges[e - N_EDGES];
    const float* hs = h + (size_t)s * H;
    const float* hd = h + (size_t)d * H;
    float m1[HID];
    #pragma unroll
    for (int j = 0; j < HID; ++j) m1[j] = sb1[j];
    for (int k = 0; k < H; ++k) {
        float xs = hs[k], xd = hd[k];
        const float* w_s = &sW1T[k * HID];
        const float* w_d = &sW1T[(H + k) * HID];
        #pragma unroll
        for (int j = 0; j < HID; ++j) {
            m1[j] = fmaf(w_s[j], xs, m1[j]);
            m1[j] = fmaf(w_d[j], xd, m1[j]);
        }
    }
    #pragma unroll
    for (int j = 0; j < HID; ++j) m1[j] = fmaxf(m1[j], 0.0f);
    float out[H];
    #pragma unroll
    for (int o = 0; o < H; ++o) out[o] = sb3[o];
    for (int j = 0; j < HID; ++j) {
        float acc = sb2[j];
        const float* wv = &sW2[j * HID];
        #pragma unroll
        for (int k = 0; k < HID; ++k) acc = fmaf(wv[k], m1[k], acc);
        acc = fmaxf(acc, 0.0f);
        const float* w3 = &sW3T[j * H];
        #pragma unroll
        for (int o = 0; o < H; ++o) out[o] = fmaf(w3[o], acc, out[o]);
    }
    float* as = a + (size_t)s * H;
    #pragma unroll
    for (int o = 0; o < H; ++o) atomicAdd(&as[o], out[o]);
}

// ---------------- GRU -------------------------------------------------------

__global__ __launch_bounds__(256) void gru_kernel(
    const float* __restrict__ h_in,
    const float* __restrict__ a,
    float* __restrict__ h_out,
    const float* __restrict__ W_ih, const float* __restrict__ b_ih,
    const float* __restrict__ W_hh, const float* __restrict__ b_hh)
{
    __shared__ float sWih[3 * H * H];
    __shared__ float sWhh[3 * H * H];
    __shared__ float sbih[3 * H];
    __shared__ float sbhh[3 * H];
    for (int i = threadIdx.x; i < 3 * H * H; i += blockDim.x) { sWih[i] = W_ih[i]; sWhh[i] = W_hh[i]; }
    if (threadIdx.x < 3 * H) { sbih[threadIdx.x] = b_ih[threadIdx.x]; sbhh[threadIdx.x] = b_hh[threadIdx.x]; }
    __syncthreads();

    int n = blockIdx.x * blockDim.x + threadIdx.x;
    if (n >= N_NODES) return;

    float av[H], hv[H];
    #pragma unroll
    for (int k = 0; k < H; ++k) { av[k] = a[(size_t)n * H + k]; hv[k] = h_in[(size_t)n * H + k]; }

    float gi[3 * H], gh[3 * H];
    #pragma unroll
    for (int g = 0; g < 3 * H; ++g) {
        float ai = sbih[g], hh = sbhh[g];
        const float* wi = &sWih[g * H];
        const float* wh = &sWhh[g * H];
        #pragma unroll
        for (int k = 0; k < H; ++k) {
            ai = fmaf(wi[k], av[k], ai);
            hh = fmaf(wh[k], hv[k], hh);
        }
        gi[g] = ai; gh[g] = hh;
    }

    #pragma unroll
    for (int o = 0; o < H; ++o) {
        float r = sigmoidf_(gi[o] + gh[o]);
        float z = sigmoidf_(gi[H + o] + gh[H + o]);
        float nn = tanhf_(gi[2 * H + o] + r * gh[2 * H + o]);
        h_out[(size_t)n * H + o] = (1.0f - z) * nn + z * hv[o];
    }
}

static inline size_t align256(size_t x) { return (x + 255) & ~(size_t)255; }

extern "C" void kernel_launch(void* const* d_in, const int* in_sizes, int n_in,
                              void* d_out, int out_size, void* d_ws, size_t ws_size,
                              hipStream_t stream) {
    const float* node_features = (const float*)d_in[0];
    const int*   edges         = (const int*)d_in[1];
    const float* W1 = (const float*)d_in[2];
    const float* b1 = (const float*)d_in[3];
    const float* W2 = (const float*)d_in[4];
    const float* b2 = (const float*)d_in[5];
    const float* W3 = (const float*)d_in[6];
    const float* b3 = (const float*)d_in[7];
    const float* W_ih = (const float*)d_in[8];
    const float* b_ih = (const float*)d_in[9];
    const float* W_hh = (const float*)d_in[10];
    const float* b_hh = (const float*)d_in[11];

    char* ws = (char*)d_ws;
    size_t off = 0;
    float* a = (float*)(ws + off);          off = align256(off + (size_t)N_NODES * H * sizeof(float));
    int* cnt = (int*)(ws + off);            off = align256(off + (size_t)N_NODES * sizeof(int));
    int* cursor = (int*)(ws + off);         off = align256(off + (size_t)N_NODES * sizeof(int));
    int* partials = (int*)(ws + off);       off = align256(off + (size_t)NB_SCAN * sizeof(int));
    int2* pairs = (int2*)(ws + off);        off = align256(off + (size_t)E2 * sizeof(int2));
    const bool use_csr = (ws_size >= off);

    float* hbuf = (float*)d_out;
    const int edge_blocks = E2 / 256;                 // 12500
    const int node_blocks = (N_NODES + 255) / 256;    // 391

    if (use_csr) {
        hipMemsetAsync(cnt, 0, (size_t)N_NODES * sizeof(int), stream);
        hist_kernel<<<edge_blocks, 256, 0, stream>>>(edges, cnt);
        scan1_kernel<<<NB_SCAN, 256, 0, stream>>>(cnt, cursor, partials);
        scan2_kernel<<<1, 64, 0, stream>>>(partials, NB_SCAN);
        scan3_kernel<<<node_blocks, 256, 0, stream>>>(cursor, partials);
        scatter_kernel<<<edge_blocks, 256, 0, stream>>>(edges, cursor, pairs);
    }

    for (int it = 0; it < 3; ++it) {
        hipMemsetAsync(a, 0, (size_t)N_NODES * H * sizeof(float), stream);
        const float* hin = (it == 0) ? node_features : hbuf;
        if (use_csr) {
            edge_mlp_mfma_kernel<<<edge_blocks, 256, 0, stream>>>(
                hin, pairs, W1, b1, W2, b2, W3, b3, a);
        } else {
            edge_mlp_kernel<<<edge_blocks, 256, 0, stream>>>(
                hin, edges, W1, b1, W2, b2, W3, b3, a);
        }
        gru_kernel<<<node_blocks, 256, 0, stream>>>(
            hin, a, hbuf, W_ih, b_ih, W_hh, b_hh);
    }
}

// Round 5
// 770.336 us; speedup vs baseline: 6.9835x; 1.7615x over previous
//
#include <hip/hip_runtime.h>
#include <hip/hip_bf16.h>
#include <math.h>

#define N_NODES 100000
#define N_EDGES 1600000
#define H 10
#define HID 64
#define E2 (2 * N_EDGES)          // 3,200,000 (12500 blocks of 256)
#define SCAN_CHUNK 1024
#define NB_SCAN ((N_NODES + SCAN_CHUNK - 1) / SCAN_CHUNK)   // 98

typedef __attribute__((ext_vector_type(8))) short short8;
typedef __attribute__((ext_vector_type(4))) float f32x4;
typedef __attribute__((ext_vector_type(2))) unsigned int uint2v;
typedef __attribute__((ext_vector_type(4))) unsigned int uint4v;
typedef unsigned int uint4u __attribute__((ext_vector_type(4), aligned(4)));

#define MFMA16(a, b, c) __builtin_amdgcn_mfma_f32_16x16x32_bf16((a), (b), (c), 0, 0, 0)

__device__ __forceinline__ float sigmoidf_(float x) {
    return 1.0f / (1.0f + __expf(-x));
}
__device__ __forceinline__ float tanhf_(float x) {
    float ax = fabsf(x);
    float t = 1.0f - 2.0f / (__expf(2.0f * ax) + 1.0f);
    return copysignf(t, x);
}
__device__ __forceinline__ unsigned short f2bf(float f) {
    union { __hip_bfloat16 b; unsigned short u; } cv;
    cv.b = __float2bfloat16(f);   // RNE
    return cv.u;
}
__device__ __forceinline__ unsigned pack2(float lo, float hi) {
    return (unsigned)f2bf(lo) | ((unsigned)f2bf(hi) << 16);
}

// ---------------- CSR build (once per launch; edges static) -----------------

__global__ __launch_bounds__(256) void hist_kernel(
    const int* __restrict__ edges, int* __restrict__ cnt)
{
    int e = blockIdx.x * 256 + threadIdx.x;
    if (e < E2) atomicAdd(&cnt[edges[e]], 1);
}

__global__ __launch_bounds__(256) void scan1_kernel(
    const int* __restrict__ cnt, int* __restrict__ excl, int* __restrict__ partials)
{
    __shared__ int sdata[256];
    int tid = threadIdx.x;
    int base = blockIdx.x * SCAN_CHUNK + tid * 4;
    int v0 = (base + 0 < N_NODES) ? cnt[base + 0] : 0;
    int v1 = (base + 1 < N_NODES) ? cnt[base + 1] : 0;
    int v2 = (base + 2 < N_NODES) ? cnt[base + 2] : 0;
    int v3 = (base + 3 < N_NODES) ? cnt[base + 3] : 0;
    int sum = v0 + v1 + v2 + v3;
    sdata[tid] = sum;
    __syncthreads();
    for (int off = 1; off < 256; off <<= 1) {
        int t = (tid >= off) ? sdata[tid - off] : 0;
        __syncthreads();
        sdata[tid] += t;
        __syncthreads();
    }
    int run = sdata[tid] - sum;
    if (tid == 255) partials[blockIdx.x] = sdata[255];
    if (base + 0 < N_NODES) { excl[base + 0] = run; run += v0; }
    if (base + 1 < N_NODES) { excl[base + 1] = run; run += v1; }
    if (base + 2 < N_NODES) { excl[base + 2] = run; run += v2; }
    if (base + 3 < N_NODES) { excl[base + 3] = run; run += v3; }
}

__global__ void scan2_kernel(int* partials, int nb) {
    if (threadIdx.x == 0 && blockIdx.x == 0) {
        int run = 0;
        for (int b = 0; b < nb; ++b) { int t = partials[b]; partials[b] = run; run += t; }
    }
}

__global__ __launch_bounds__(256) void scan3_kernel(
    int* __restrict__ excl, const int* __restrict__ partials)
{
    int i = blockIdx.x * 256 + threadIdx.x;
    if (i < N_NODES) excl[i] += partials[i / SCAN_CHUNK];
}

__global__ __launch_bounds__(256) void scatter_kernel(
    const int* __restrict__ edges, int* __restrict__ cursor, int2* __restrict__ pairs)
{
    int e = blockIdx.x * 256 + threadIdx.x;
    if (e >= E2) return;
    int s = edges[e];
    int d = (e < N_EDGES) ? edges[N_EDGES + e] : edges[e - N_EDGES];
    int pos = atomicAdd(&cursor[s], 1);
    pairs[pos] = make_int2(s, d);
}

// ---------------- one-time precompute ---------------------------------------
// wbuf layout: 14 fragments x 64 lanes x 16B (bf16 A-operands), then b3 padded
// to 16 floats. Frags: 0..3 = W1 (b1 embedded at k==20), 4..11 = W2[nt][ks],
// 12..13 = W3 (rows >=10 zero).

#define WBUF_B3_OFF 14336   // 14*64*16

__global__ __launch_bounds__(256) void prep_weights_kernel(
    const float* __restrict__ W1, const float* __restrict__ b1,
    const float* __restrict__ W2,
    const float* __restrict__ W3, const float* __restrict__ b3,
    unsigned char* __restrict__ wbuf)
{
    int idx = blockIdx.x * 256 + threadIdx.x;   // grid=4 -> 1024 threads
    if (idx < 896) {
        int f = idx >> 6, l = idx & 63, l15 = l & 15, lo4 = l >> 4;
        unsigned short v[8];
        #pragma unroll
        for (int i = 0; i < 8; ++i) {
            int kk = lo4 * 8 + i;     // k within 32
            float val = 0.0f;
            if (f < 4) {
                int row = f * 16 + l15;
                val = (kk < 20) ? W1[row * 20 + kk] : (kk == 20 ? b1[row] : 0.0f);
            } else if (f < 12) {
                int g = f - 4, nt = g >> 1, ks = g & 1;
                val = W2[(nt * 16 + l15) * 64 + ks * 32 + kk];
            } else {
                int ks = f - 12;
                val = (l15 < 10) ? W3[l15 * 64 + ks * 32 + kk] : 0.0f;
            }
            v[i] = f2bf(val);
        }
        uint4v pk = { (unsigned)v[0] | ((unsigned)v[1] << 16),
                      (unsigned)v[2] | ((unsigned)v[3] << 16),
                      (unsigned)v[4] | ((unsigned)v[5] << 16),
                      (unsigned)v[6] | ((unsigned)v[7] << 16) };
        *(uint4v*)(wbuf + (size_t)idx * 16) = pk;
    } else if (idx < 896 + 16) {
        int o = idx - 896;
        *(float*)(wbuf + WBUF_B3_OFF + o * 4) = (o < 10) ? b3[o] : 0.0f;
    }
}

__global__ __launch_bounds__(256) void convert_h_kernel(
    const float* __restrict__ h, unsigned char* __restrict__ hbf)
{
    int n = blockIdx.x * 256 + threadIdx.x;
    if (n >= N_NODES) return;
    const float* r = h + (size_t)n * 10;
    unsigned w0 = pack2(r[0], r[1]), w1 = pack2(r[2], r[3]), w2 = pack2(r[4], r[5]),
             w3 = pack2(r[6], r[7]), w4 = pack2(r[8], r[9]);
    unsigned char* o = hbf + (size_t)n * 20;
    *(uint4u*)o = (uint4u){w0, w1, w2, w3};
    *(unsigned int*)(o + 16) = w4;
}

// ---------------- MFMA edge MLP v2 ------------------------------------------
// 256 threads = 4 waves; block handles 256 src-sorted edges. Wave w owns LDS
// rows [w*64, w*64+64) exclusively through gather + all 3 GEMMs -> NO barriers
// until the cross-wave segment reduction (2 barriers total).
// X rows are 128B with T2 XOR swizzle: 16B slot j of row r lives at j^(r&7).
// Segment heads are BLOCK-LOCAL (t==0 is always a head): boundary-spanning
// runs are split and each block atomically adds its partial sum (R4 bug fix).

__global__ __launch_bounds__(256) void edge_mlp_mfma2_kernel(
    const unsigned char* __restrict__ hbf,   // [N][20B] bf16
    const int2* __restrict__ pairs,
    const unsigned char* __restrict__ wbuf,
    const float* __restrict__ b2,
    float* __restrict__ a)
{
    __shared__ __align__(16) unsigned char sX[256 * 128];
    __shared__ unsigned long long smask[4];
    __shared__ int sheadpos[256];
    __shared__ int sheadnode[256];

    char* sXp = (char*)sX;
    const int t = threadIdx.x;
    const int w = t >> 6, l = t & 63, l15 = l & 15, lo4 = l >> 4;
    const int mbase = w * 64;

    // weight fragments (precomputed layout; L1-resident, coalesced per wave)
    short8 W1f[4], W2f[4][2], W3f[2];
    #pragma unroll
    for (int nt = 0; nt < 4; ++nt)
        W1f[nt] = *(const short8*)(wbuf + ((nt * 64 + l) << 4));
    #pragma unroll
    for (int nt = 0; nt < 4; ++nt)
        #pragma unroll
        for (int ks = 0; ks < 2; ++ks)
            W2f[nt][ks] = *(const short8*)(wbuf + (((4 + nt * 2 + ks) * 64 + l) << 4));
    #pragma unroll
    for (int ks = 0; ks < 2; ++ks)
        W3f[ks] = *(const short8*)(wbuf + (((12 + ks) * 64 + l) << 4));
    const float* b3p = (const float*)(wbuf + WBUF_B3_OFF);

    // ---- gather (bf16 rows, no conversion)
    const int k = blockIdx.x * 256 + t;
    const int2 p = pairs[k];
    const int2 pm = pairs[(k > 0) ? (k - 1) : 0];
    const bool head = (t == 0) || (pm.x != p.x);   // BLOCK-local heads

    const unsigned char* sp = hbf + (size_t)p.x * 20;
    const unsigned char* dp = hbf + (size_t)p.y * 20;
    uint4u s4 = *(const uint4u*)sp;
    unsigned int st = *(const unsigned int*)(sp + 16);
    uint4u d4 = *(const uint4u*)dp;
    unsigned int dt = *(const unsigned int*)(dp + 16);

    {
        char* row = sXp + (t << 7);
        const int sw = (t & 7) << 4;
        // cols 0-9 src, 10-19 dst, col 20 = 1.0 (bias), rest 0
        *(uint4v*)(row + (0  ^ sw)) = (uint4v){s4.x, s4.y, s4.z, s4.w};
        *(uint4v*)(row + (16 ^ sw)) = (uint4v){st, d4.x, d4.y, d4.z};
        *(uint4v*)(row + (32 ^ sw)) = (uint4v){d4.w, dt, 0x00003F80u, 0u};
        *(uint4v*)(row + (48 ^ sw)) = (uint4v){0u, 0u, 0u, 0u};
    }
    // no barrier: wave reads only its own lanes' rows (intra-wave LDS order)

    const int srow = (l15 & 7) << 4;

    // ---- GEMM1: K=32 (slots 0-3); bias embedded in W1 col 20
    #pragma unroll
    for (int mt = 0; mt < 4; ++mt) {
        const int rb = (mbase + mt * 16 + l15) << 7;
        short8 Bf = *(const short8*)(sXp + rb + ((lo4 << 4) ^ srow));
        #pragma unroll
        for (int nt = 0; nt < 4; ++nt) {
            f32x4 acc = {0.0f, 0.0f, 0.0f, 0.0f};
            acc = MFMA16(W1f[nt], Bf, acc);
            acc[0] = fmaxf(acc[0], 0.0f); acc[1] = fmaxf(acc[1], 0.0f);
            acc[2] = fmaxf(acc[2], 0.0f); acc[3] = fmaxf(acc[3], 0.0f);
            uint2v pk = { pack2(acc[0], acc[1]), pack2(acc[2], acc[3]) };
            const int jy = (nt * 2 + (lo4 >> 1)) << 4;
            *(uint2v*)(sXp + rb + (jy ^ srow) + ((lo4 & 1) << 3)) = pk;
        }
    }

    // ---- GEMM2: K=64 (slots 0-7), bias b2 (L1)
    #pragma unroll
    for (int mt = 0; mt < 4; ++mt) {
        const int rb = (mbase + mt * 16 + l15) << 7;
        short8 B0 = *(const short8*)(sXp + rb + ((lo4 << 4) ^ srow));
        short8 B1 = *(const short8*)(sXp + rb + (((4 + lo4) << 4) ^ srow));
        #pragma unroll
        for (int nt = 0; nt < 4; ++nt) {
            f32x4 acc = *(const f32x4*)(b2 + nt * 16 + lo4 * 4);
            acc = MFMA16(W2f[nt][0], B0, acc);
            acc = MFMA16(W2f[nt][1], B1, acc);
            acc[0] = fmaxf(acc[0], 0.0f); acc[1] = fmaxf(acc[1], 0.0f);
            acc[2] = fmaxf(acc[2], 0.0f); acc[3] = fmaxf(acc[3], 0.0f);
            uint2v pk = { pack2(acc[0], acc[1]), pack2(acc[2], acc[3]) };
            const int jy = (nt * 2 + (lo4 >> 1)) << 4;
            *(uint2v*)(sXp + rb + (jy ^ srow) + ((lo4 & 1) << 3)) = pk;
        }
    }

    // ---- GEMM3: 16 out-feats (10 valid), K=64; f32 out overwrites slots 0-3
    #pragma unroll
    for (int mt = 0; mt < 4; ++mt) {
        const int rb = (mbase + mt * 16 + l15) << 7;
        short8 B0 = *(const short8*)(sXp + rb + ((lo4 << 4) ^ srow));
        short8 B1 = *(const short8*)(sXp + rb + (((4 + lo4) << 4) ^ srow));
        f32x4 acc = *(const f32x4*)(b3p + lo4 * 4);
        acc = MFMA16(W3f[0], B0, acc);
        acc = MFMA16(W3f[1], B1, acc);
        *(f32x4*)(sXp + rb + ((lo4 << 4) ^ srow)) = acc;
    }

    // ---- segment list via ballot (block-local heads)
    unsigned long long m = __ballot(head);
    if ((t & 63) == 0) smask[w] = m;
    __syncthreads();   // A: out rows + smask visible

    int base = 0, nseg = 0;
    #pragma unroll
    for (int j = 0; j < 4; ++j) {
        int c = __popcll(smask[j]);
        if (j < w) base += c;
        nseg += c;
    }
    if (head) {
        int rank = base + __popcll(m & ((1ull << (t & 63)) - 1ull));
        sheadpos[rank] = t;
        sheadnode[rank] = p.x;
    }
    __syncthreads();   // B: head list visible

    // ---- one thread per (segment, feature): sum run, single atomic
    const int total = nseg * 10;
    for (int q = t; q < total; q += 256) {
        int seg = q / 10;
        int o = q - seg * 10;
        int r0 = sheadpos[seg];
        int r1 = (seg + 1 < nseg) ? sheadpos[seg + 1] : 256;
        const int obase = ((o >> 2) << 4) + ((o & 3) << 2);
        float acc = 0.0f;
        for (int r = r0; r < r1; ++r)
            acc += *(const float*)(sXp + (r << 7) + (obase ^ ((r & 7) << 4)));
        atomicAdd(&a[(size_t)sheadnode[seg] * H + o], acc);
    }
}

// ---------------- fallback VALU edge kernel (no CSR workspace) --------------

__global__ __launch_bounds__(256) void edge_mlp_kernel(
    const float* __restrict__ h,
    const int*   __restrict__ edges,
    const float* __restrict__ W1, const float* __restrict__ b1,
    const float* __restrict__ W2, const float* __restrict__ b2,
    const float* __restrict__ W3, const float* __restrict__ b3,
    float* __restrict__ a)
{
    __shared__ float sW1T[2 * H * HID];
    __shared__ float sb1[HID];
    __shared__ float sW2[HID * HID];
    __shared__ float sb2[HID];
    __shared__ float sW3T[HID * H];
    __shared__ float sb3[H];
    for (int i = threadIdx.x; i < 2 * H * HID; i += blockDim.x) {
        int kk = i >> 6, j = i & 63;
        sW1T[i] = W1[j * (2 * H) + kk];
    }
    for (int i = threadIdx.x; i < HID * HID; i += blockDim.x) sW2[i] = W2[i];
    for (int i = threadIdx.x; i < HID * H; i += blockDim.x) {
        int j = i / H, o = i - j * H;
        sW3T[i] = W3[o * HID + j];
    }
    if (threadIdx.x < HID) { sb1[threadIdx.x] = b1[threadIdx.x]; sb2[threadIdx.x] = b2[threadIdx.x]; }
    if (threadIdx.x < H)   { sb3[threadIdx.x] = b3[threadIdx.x]; }
    __syncthreads();
    int e = blockIdx.x * blockDim.x + threadIdx.x;
    if (e >= E2) return;
    int s = edges[e];
    int d = (e < N_EDGES) ? edges[N_EDGES + e] : edges[e - N_EDGES];
    const float* hs = h + (size_t)s * H;
    const float* hd = h + (size_t)d * H;
    float m1[HID];
    #pragma unroll
    for (int j = 0; j < HID; ++j) m1[j] = sb1[j];
    for (int kk = 0; kk < H; ++kk) {
        float xs = hs[kk], xd = hd[kk];
        const float* w_s = &sW1T[kk * HID];
        const float* w_d = &sW1T[(H + kk) * HID];
        #pragma unroll
        for (int j = 0; j < HID; ++j) {
            m1[j] = fmaf(w_s[j], xs, m1[j]);
            m1[j] = fmaf(w_d[j], xd, m1[j]);
        }
    }
    #pragma unroll
    for (int j = 0; j < HID; ++j) m1[j] = fmaxf(m1[j], 0.0f);
    float out[H];
    #pragma unroll
    for (int o = 0; o < H; ++o) out[o] = sb3[o];
    for (int j = 0; j < HID; ++j) {
        float acc = sb2[j];
        const float* wv = &sW2[j * HID];
        #pragma unroll
        for (int kk = 0; kk < HID; ++kk) acc = fmaf(wv[kk], m1[kk], acc);
        acc = fmaxf(acc, 0.0f);
        const float* w3 = &sW3T[j * H];
        #pragma unroll
        for (int o = 0; o < H; ++o) out[o] = fmaf(w3[o], acc, out[o]);
    }
    float* as = a + (size_t)s * H;
    #pragma unroll
    for (int o = 0; o < H; ++o) atomicAdd(&as[o], out[o]);
}

// ---------------- GRU (+ bf16 h epilogue) -----------------------------------

__global__ __launch_bounds__(256) void gru_kernel(
    const float* __restrict__ h_in,
    const float* __restrict__ a,
    float* __restrict__ h_out,
    const float* __restrict__ W_ih, const float* __restrict__ b_ih,
    const float* __restrict__ W_hh, const float* __restrict__ b_hh,
    unsigned char* __restrict__ hbf)
{
    __shared__ float sWih[3 * H * H];
    __shared__ float sWhh[3 * H * H];
    __shared__ float sbih[3 * H];
    __shared__ float sbhh[3 * H];
    for (int i = threadIdx.x; i < 3 * H * H; i += blockDim.x) { sWih[i] = W_ih[i]; sWhh[i] = W_hh[i]; }
    if (threadIdx.x < 3 * H) { sbih[threadIdx.x] = b_ih[threadIdx.x]; sbhh[threadIdx.x] = b_hh[threadIdx.x]; }
    __syncthreads();

    int n = blockIdx.x * blockDim.x + threadIdx.x;
    if (n >= N_NODES) return;

    float av[H], hv[H];
    #pragma unroll
    for (int kk = 0; kk < H; ++kk) { av[kk] = a[(size_t)n * H + kk]; hv[kk] = h_in[(size_t)n * H + kk]; }

    float gi[3 * H], gh[3 * H];
    #pragma unroll
    for (int g = 0; g < 3 * H; ++g) {
        float ai = sbih[g], hh = sbhh[g];
        const float* wi = &sWih[g * H];
        const float* wh = &sWhh[g * H];
        #pragma unroll
        for (int kk = 0; kk < H; ++kk) {
            ai = fmaf(wi[kk], av[kk], ai);
            hh = fmaf(wh[kk], hv[kk], hh);
        }
        gi[g] = ai; gh[g] = hh;
    }

    float ho[H];
    #pragma unroll
    for (int o = 0; o < H; ++o) {
        float r = sigmoidf_(gi[o] + gh[o]);
        float z = sigmoidf_(gi[H + o] + gh[H + o]);
        float nn = tanhf_(gi[2 * H + o] + r * gh[2 * H + o]);
        ho[o] = (1.0f - z) * nn + z * hv[o];
        h_out[(size_t)n * H + o] = ho[o];
    }
    if (hbf) {
        unsigned w0 = pack2(ho[0], ho[1]), w1 = pack2(ho[2], ho[3]), w2 = pack2(ho[4], ho[5]),
                 w3 = pack2(ho[6], ho[7]), w4 = pack2(ho[8], ho[9]);
        unsigned char* ob = hbf + (size_t)n * 20;
        *(uint4u*)ob = (uint4u){w0, w1, w2, w3};
        *(unsigned int*)(ob + 16) = w4;
    }
}

static inline size_t align256(size_t x) { return (x + 255) & ~(size_t)255; }

extern "C" void kernel_launch(void* const* d_in, const int* in_sizes, int n_in,
                              void* d_out, int out_size, void* d_ws, size_t ws_size,
                              hipStream_t stream) {
    const float* node_features = (const float*)d_in[0];
    const int*   edges         = (const int*)d_in[1];
    const float* W1 = (const float*)d_in[2];
    const float* b1 = (const float*)d_in[3];
    const float* W2 = (const float*)d_in[4];
    const float* b2 = (const float*)d_in[5];
    const float* W3 = (const float*)d_in[6];
    const float* b3 = (const float*)d_in[7];
    const float* W_ih = (const float*)d_in[8];
    const float* b_ih = (const float*)d_in[9];
    const float* W_hh = (const float*)d_in[10];
    const float* b_hh = (const float*)d_in[11];

    char* ws = (char*)d_ws;
    size_t off = 0;
    float* a = (float*)(ws + off);     off = align256(off + (size_t)N_NODES * H * sizeof(float));
    int2* pairs = (int2*)(ws + off);   off = align256(off + (size_t)E2 * sizeof(int2));
    // region C: CSR scratch (cnt/cursor/partials) is dead before hbf/wbuf are
    // written, so they overlap.
    size_t coff = off;
    int* cnt = (int*)(ws + coff);                 size_t c1 = align256(coff + (size_t)N_NODES * sizeof(int));
    int* cursor = (int*)(ws + c1);                size_t c2 = align256(c1 + (size_t)N_NODES * sizeof(int));
    int* partials = (int*)(ws + c2);              size_t c3 = align256(c2 + (size_t)NB_SCAN * sizeof(int));
    unsigned char* hbf = (unsigned char*)(ws + coff);  size_t h1 = align256(coff + (size_t)N_NODES * 20);
    unsigned char* wbuf = (unsigned char*)(ws + h1);   size_t h2 = align256(h1 + 14400);
    size_t need = (c3 > h2) ? c3 : h2;
    const bool use_csr = (ws_size >= need);

    float* hbuf = (float*)d_out;
    const int edge_blocks = E2 / 256;                 // 12500
    const int node_blocks = (N_NODES + 255) / 256;    // 391

    if (use_csr) {
        hipMemsetAsync(cnt, 0, (size_t)N_NODES * sizeof(int), stream);
        hist_kernel<<<edge_blocks, 256, 0, stream>>>(edges, cnt);
        scan1_kernel<<<NB_SCAN, 256, 0, stream>>>(cnt, cursor, partials);
        scan2_kernel<<<1, 64, 0, stream>>>(partials, NB_SCAN);
        scan3_kernel<<<node_blocks, 256, 0, stream>>>(cursor, partials);
        scatter_kernel<<<edge_blocks, 256, 0, stream>>>(edges, cursor, pairs);
        // CSR scratch now dead; safe to write hbf/wbuf over it
        prep_weights_kernel<<<4, 256, 0, stream>>>(W1, b1, W2, W3, b3, wbuf);
        convert_h_kernel<<<node_blocks, 256, 0, stream>>>(node_features, hbf);
    }

    for (int it = 0; it < 3; ++it) {
        hipMemsetAsync(a, 0, (size_t)N_NODES * H * sizeof(float), stream);
        const float* hin = (it == 0) ? node_features : hbuf;
        if (use_csr) {
            edge_mlp_mfma2_kernel<<<edge_blocks, 256, 0, stream>>>(
                hbf, pairs, wbuf, b2, a);
        } else {
            edge_mlp_kernel<<<edge_blocks, 256, 0, stream>>>(
                hin, edges, W1, b1, W2, b2, W3, b3, a);
        }
        gru_kernel<<<node_blocks, 256, 0, stream>>>(
            hin, a, hbuf, W_ih, b_ih, W_hh, b_hh, use_csr ? hbf : (unsigned char*)nullptr);
    }
}

// Round 6
// 622.079 us; speedup vs baseline: 8.6478x; 1.2383x over previous
//
#include <hip/hip_runtime.h>
#include <hip/hip_bf16.h>
#include <math.h>

#define N_NODES 100000
#define N_EDGES 1600000
#define H 10
#define HID 64
#define E2 (2 * N_EDGES)          // 3,200,000 (12500 blocks of 256)
#define SCAN_CHUNK 1024
#define NB_SCAN ((N_NODES + SCAN_CHUNK - 1) / SCAN_CHUNK)   // 98

// striped scatter: 8 stripes (XCD-affine via blockIdx&7) x 256 chunks
#define SC_CHUNKS 256
#define SC_CHUNK ((E2 + SC_CHUNKS - 1) / SC_CHUNKS)         // 12500
#define NODES_PER_STRIPE (N_NODES / 8)                      // 12500

typedef __attribute__((ext_vector_type(8))) short short8;
typedef __attribute__((ext_vector_type(4))) float f32x4;
typedef __attribute__((ext_vector_type(2))) unsigned int uint2v;
typedef __attribute__((ext_vector_type(4))) unsigned int uint4v;
typedef unsigned int uint4u __attribute__((ext_vector_type(4), aligned(4)));

#define MFMA16(a, b, c) __builtin_amdgcn_mfma_f32_16x16x32_bf16((a), (b), (c), 0, 0, 0)

__device__ __forceinline__ float sigmoidf_(float x) {
    return 1.0f / (1.0f + __expf(-x));
}
__device__ __forceinline__ float tanhf_(float x) {
    float ax = fabsf(x);
    float t = 1.0f - 2.0f / (__expf(2.0f * ax) + 1.0f);
    return copysignf(t, x);
}
__device__ __forceinline__ unsigned short f2bf(float f) {
    union { __hip_bfloat16 b; unsigned short u; } cv;
    cv.b = __float2bfloat16(f);   // RNE
    return cv.u;
}
__device__ __forceinline__ unsigned pack2(float lo, float hi) {
    return (unsigned)f2bf(lo) | ((unsigned)f2bf(hi) << 16);
}

// ---------------- CSR build (once per launch; edges static) -----------------

__global__ __launch_bounds__(256) void hist_kernel(
    const int* __restrict__ edges, int* __restrict__ cnt)
{
    int e = blockIdx.x * 256 + threadIdx.x;
    if (e < E2) atomicAdd(&cnt[edges[e]], 1);
}

__global__ __launch_bounds__(256) void scan1_kernel(
    const int* __restrict__ cnt, int* __restrict__ excl, int* __restrict__ partials)
{
    __shared__ int sdata[256];
    int tid = threadIdx.x;
    int base = blockIdx.x * SCAN_CHUNK + tid * 4;
    int v0 = (base + 0 < N_NODES) ? cnt[base + 0] : 0;
    int v1 = (base + 1 < N_NODES) ? cnt[base + 1] : 0;
    int v2 = (base + 2 < N_NODES) ? cnt[base + 2] : 0;
    int v3 = (base + 3 < N_NODES) ? cnt[base + 3] : 0;
    int sum = v0 + v1 + v2 + v3;
    sdata[tid] = sum;
    __syncthreads();
    for (int off = 1; off < 256; off <<= 1) {
        int t = (tid >= off) ? sdata[tid - off] : 0;
        __syncthreads();
        sdata[tid] += t;
        __syncthreads();
    }
    int run = sdata[tid] - sum;
    if (tid == 255) partials[blockIdx.x] = sdata[255];
    if (base + 0 < N_NODES) { excl[base + 0] = run; run += v0; }
    if (base + 1 < N_NODES) { excl[base + 1] = run; run += v1; }
    if (base + 2 < N_NODES) { excl[base + 2] = run; run += v2; }
    if (base + 3 < N_NODES) { excl[base + 3] = run; run += v3; }
}

__global__ void scan2_kernel(int* partials, int nb) {
    if (threadIdx.x == 0 && blockIdx.x == 0) {
        int run = 0;
        for (int b = 0; b < nb; ++b) { int t = partials[b]; partials[b] = run; run += t; }
    }
}

__global__ __launch_bounds__(256) void scan3_kernel(
    int* __restrict__ excl, const int* __restrict__ partials)
{
    int i = blockIdx.x * 256 + threadIdx.x;
    if (i < N_NODES) excl[i] += partials[i / SCAN_CHUNK];
}

// Striped scatter: stripe q = blockIdx&7 handles src in [q*12500,(q+1)*12500);
// its destination region (~3.2 MB) is contiguous and XCD-L2-resident, so the
// random 8B writes merge into full lines. Blocks 8c..8c+7 read chunk c at the
// same time -> L3 serves the 8x re-read; HBM read stays ~1x.
__global__ __launch_bounds__(256) void scatter_striped_kernel(
    const int* __restrict__ edges, int* __restrict__ cursor, int2* __restrict__ pairs)
{
    const int q = blockIdx.x & 7;
    const int c = blockIdx.x >> 3;
    const int lo = c * SC_CHUNK;
    const int hi = (lo + SC_CHUNK < E2) ? (lo + SC_CHUNK) : E2;
    for (int e = lo + threadIdx.x; e < hi; e += 256) {
        int s = edges[e];
        if (s / NODES_PER_STRIPE != q) continue;
        int d = (e < N_EDGES) ? edges[N_EDGES + e] : edges[e - N_EDGES];
        int pos = atomicAdd(&cursor[s], 1);
        pairs[pos] = make_int2(s, d);
    }
}

// ---------------- one-time precompute ---------------------------------------
// wbuf layout: 14 fragments x 64 lanes x 16B (bf16 A-operands), then b3 padded
// to 16 floats. Frags: 0..3 = W1 (b1 embedded at k==20), 4..11 = W2[nt][ks],
// 12..13 = W3 (rows >=10 zero).

#define WBUF_B3_OFF 14336   // 14*64*16

__global__ __launch_bounds__(256) void prep_weights_kernel(
    const float* __restrict__ W1, const float* __restrict__ b1,
    const float* __restrict__ W2,
    const float* __restrict__ W3, const float* __restrict__ b3,
    unsigned char* __restrict__ wbuf)
{
    int idx = blockIdx.x * 256 + threadIdx.x;   // grid=4 -> 1024 threads
    if (idx < 896) {
        int f = idx >> 6, l = idx & 63, l15 = l & 15, lo4 = l >> 4;
        unsigned short v[8];
        #pragma unroll
        for (int i = 0; i < 8; ++i) {
            int kk = lo4 * 8 + i;     // k within 32
            float val = 0.0f;
            if (f < 4) {
                int row = f * 16 + l15;
                val = (kk < 20) ? W1[row * 20 + kk] : (kk == 20 ? b1[row] : 0.0f);
            } else if (f < 12) {
                int g = f - 4, nt = g >> 1, ks = g & 1;
                val = W2[(nt * 16 + l15) * 64 + ks * 32 + kk];
            } else {
                int ks = f - 12;
                val = (l15 < 10) ? W3[l15 * 64 + ks * 32 + kk] : 0.0f;
            }
            v[i] = f2bf(val);
        }
        uint4v pk = { (unsigned)v[0] | ((unsigned)v[1] << 16),
                      (unsigned)v[2] | ((unsigned)v[3] << 16),
                      (unsigned)v[4] | ((unsigned)v[5] << 16),
                      (unsigned)v[6] | ((unsigned)v[7] << 16) };
        *(uint4v*)(wbuf + (size_t)idx * 16) = pk;
    } else if (idx < 896 + 16) {
        int o = idx - 896;
        *(float*)(wbuf + WBUF_B3_OFF + o * 4) = (o < 10) ? b3[o] : 0.0f;
    }
}

__global__ __launch_bounds__(256) void convert_h_kernel(
    const float* __restrict__ h, unsigned char* __restrict__ hbf)
{
    int n = blockIdx.x * 256 + threadIdx.x;
    if (n >= N_NODES) return;
    const float* r = h + (size_t)n * 10;
    unsigned w0 = pack2(r[0], r[1]), w1 = pack2(r[2], r[3]), w2 = pack2(r[4], r[5]),
             w3 = pack2(r[6], r[7]), w4 = pack2(r[8], r[9]);
    unsigned char* o = hbf + (size_t)n * 20;
    *(uint4u*)o = (uint4u){w0, w1, w2, w3};
    *(unsigned int*)(o + 16) = w4;
}

// ---------------- MFMA edge MLP v2 ------------------------------------------
// 256 threads = 4 waves; block handles 256 src-sorted edges. Wave w owns LDS
// rows [w*64, w*64+64) exclusively through gather + all 3 GEMMs -> NO barriers
// until the cross-wave segment reduction (2 barriers total).
// X rows are 128B with T2 XOR swizzle: 16B slot j of row r lives at j^(r&7).
// Segment heads are BLOCK-LOCAL (t==0 is always a head): boundary-spanning
// runs are split and each block atomically adds its partial sum.

__global__ __launch_bounds__(256) void edge_mlp_mfma2_kernel(
    const unsigned char* __restrict__ hbf,   // [N][20B] bf16
    const int2* __restrict__ pairs,
    const unsigned char* __restrict__ wbuf,
    const float* __restrict__ b2,
    float* __restrict__ a)
{
    __shared__ __align__(16) unsigned char sX[256 * 128];
    __shared__ unsigned long long smask[4];
    __shared__ int sheadpos[256];
    __shared__ int sheadnode[256];

    char* sXp = (char*)sX;
    const int t = threadIdx.x;
    const int w = t >> 6, l = t & 63, l15 = l & 15, lo4 = l >> 4;
    const int mbase = w * 64;

    // weight fragments (precomputed layout; L1-resident, coalesced per wave)
    short8 W1f[4], W2f[4][2], W3f[2];
    #pragma unroll
    for (int nt = 0; nt < 4; ++nt)
        W1f[nt] = *(const short8*)(wbuf + ((nt * 64 + l) << 4));
    #pragma unroll
    for (int nt = 0; nt < 4; ++nt)
        #pragma unroll
        for (int ks = 0; ks < 2; ++ks)
            W2f[nt][ks] = *(const short8*)(wbuf + (((4 + nt * 2 + ks) * 64 + l) << 4));
    #pragma unroll
    for (int ks = 0; ks < 2; ++ks)
        W3f[ks] = *(const short8*)(wbuf + (((12 + ks) * 64 + l) << 4));
    const float* b3p = (const float*)(wbuf + WBUF_B3_OFF);

    // ---- gather (bf16 rows, no conversion)
    const int k = blockIdx.x * 256 + t;
    const int2 p = pairs[k];
    const int2 pm = pairs[(k > 0) ? (k - 1) : 0];
    const bool head = (t == 0) || (pm.x != p.x);   // BLOCK-local heads

    const unsigned char* sp = hbf + (size_t)p.x * 20;
    const unsigned char* dp = hbf + (size_t)p.y * 20;
    uint4u s4 = *(const uint4u*)sp;
    unsigned int st = *(const unsigned int*)(sp + 16);
    uint4u d4 = *(const uint4u*)dp;
    unsigned int dt = *(const unsigned int*)(dp + 16);

    {
        char* row = sXp + (t << 7);
        const int sw = (t & 7) << 4;
        // cols 0-9 src, 10-19 dst, col 20 = 1.0 (bias), rest 0
        *(uint4v*)(row + (0  ^ sw)) = (uint4v){s4.x, s4.y, s4.z, s4.w};
        *(uint4v*)(row + (16 ^ sw)) = (uint4v){st, d4.x, d4.y, d4.z};
        *(uint4v*)(row + (32 ^ sw)) = (uint4v){d4.w, dt, 0x00003F80u, 0u};
        *(uint4v*)(row + (48 ^ sw)) = (uint4v){0u, 0u, 0u, 0u};
    }
    // no barrier: wave reads only its own lanes' rows (intra-wave LDS order)

    const int srow = (l15 & 7) << 4;

    // ---- GEMM1: K=32 (slots 0-3); bias embedded in W1 col 20
    #pragma unroll
    for (int mt = 0; mt < 4; ++mt) {
        const int rb = (mbase + mt * 16 + l15) << 7;
        short8 Bf = *(const short8*)(sXp + rb + ((lo4 << 4) ^ srow));
        #pragma unroll
        for (int nt = 0; nt < 4; ++nt) {
            f32x4 acc = {0.0f, 0.0f, 0.0f, 0.0f};
            acc = MFMA16(W1f[nt], Bf, acc);
            acc[0] = fmaxf(acc[0], 0.0f); acc[1] = fmaxf(acc[1], 0.0f);
            acc[2] = fmaxf(acc[2], 0.0f); acc[3] = fmaxf(acc[3], 0.0f);
            uint2v pk = { pack2(acc[0], acc[1]), pack2(acc[2], acc[3]) };
            const int jy = (nt * 2 + (lo4 >> 1)) << 4;
            *(uint2v*)(sXp + rb + (jy ^ srow) + ((lo4 & 1) << 3)) = pk;
        }
    }

    // ---- GEMM2: K=64 (slots 0-7), bias b2 (L1)
    #pragma unroll
    for (int mt = 0; mt < 4; ++mt) {
        const int rb = (mbase + mt * 16 + l15) << 7;
        short8 B0 = *(const short8*)(sXp + rb + ((lo4 << 4) ^ srow));
        short8 B1 = *(const short8*)(sXp + rb + (((4 + lo4) << 4) ^ srow));
        #pragma unroll
        for (int nt = 0; nt < 4; ++nt) {
            f32x4 acc = *(const f32x4*)(b2 + nt * 16 + lo4 * 4);
            acc = MFMA16(W2f[nt][0], B0, acc);
            acc = MFMA16(W2f[nt][1], B1, acc);
            acc[0] = fmaxf(acc[0], 0.0f); acc[1] = fmaxf(acc[1], 0.0f);
            acc[2] = fmaxf(acc[2], 0.0f); acc[3] = fmaxf(acc[3], 0.0f);
            uint2v pk = { pack2(acc[0], acc[1]), pack2(acc[2], acc[3]) };
            const int jy = (nt * 2 + (lo4 >> 1)) << 4;
            *(uint2v*)(sXp + rb + (jy ^ srow) + ((lo4 & 1) << 3)) = pk;
        }
    }

    // ---- GEMM3: 16 out-feats (10 valid), K=64; f32 out overwrites slots 0-3
    #pragma unroll
    for (int mt = 0; mt < 4; ++mt) {
        const int rb = (mbase + mt * 16 + l15) << 7;
        short8 B0 = *(const short8*)(sXp + rb + ((lo4 << 4) ^ srow));
        short8 B1 = *(const short8*)(sXp + rb + (((4 + lo4) << 4) ^ srow));
        f32x4 acc = *(const f32x4*)(b3p + lo4 * 4);
        acc = MFMA16(W3f[0], B0, acc);
        acc = MFMA16(W3f[1], B1, acc);
        *(f32x4*)(sXp + rb + ((lo4 << 4) ^ srow)) = acc;
    }

    // ---- segment list via ballot (block-local heads)
    unsigned long long m = __ballot(head);
    if ((t & 63) == 0) smask[w] = m;
    __syncthreads();   // A: out rows + smask visible

    int base = 0, nseg = 0;
    #pragma unroll
    for (int j = 0; j < 4; ++j) {
        int c = __popcll(smask[j]);
        if (j < w) base += c;
        nseg += c;
    }
    if (head) {
        int rank = base + __popcll(m & ((1ull << (t & 63)) - 1ull));
        sheadpos[rank] = t;
        sheadnode[rank] = p.x;
    }
    __syncthreads();   // B: head list visible

    // ---- one thread per (segment, feature): sum run, single atomic
    const int total = nseg * 10;
    for (int q = t; q < total; q += 256) {
        int seg = q / 10;
        int o = q - seg * 10;
        int r0 = sheadpos[seg];
        int r1 = (seg + 1 < nseg) ? sheadpos[seg + 1] : 256;
        const int obase = ((o >> 2) << 4) + ((o & 3) << 2);
        float acc = 0.0f;
        for (int r = r0; r < r1; ++r)
            acc += *(const float*)(sXp + (r << 7) + (obase ^ ((r & 7) << 4)));
        atomicAdd(&a[(size_t)sheadnode[seg] * H + o], acc);
    }
}

// ---------------- fallback VALU edge kernel (no CSR workspace) --------------

__global__ __launch_bounds__(256) void edge_mlp_kernel(
    const float* __restrict__ h,
    const int*   __restrict__ edges,
    const float* __restrict__ W1, const float* __restrict__ b1,
    const float* __restrict__ W2, const float* __restrict__ b2,
    const float* __restrict__ W3, const float* __restrict__ b3,
    float* __restrict__ a)
{
    __shared__ float sW1T[2 * H * HID];
    __shared__ float sb1[HID];
    __shared__ float sW2[HID * HID];
    __shared__ float sb2[HID];
    __shared__ float sW3T[HID * H];
    __shared__ float sb3[H];
    for (int i = threadIdx.x; i < 2 * H * HID; i += blockDim.x) {
        int kk = i >> 6, j = i & 63;
        sW1T[i] = W1[j * (2 * H) + kk];
    }
    for (int i = threadIdx.x; i < HID * HID; i += blockDim.x) sW2[i] = W2[i];
    for (int i = threadIdx.x; i < HID * H; i += blockDim.x) {
        int j = i / H, o = i - j * H;
        sW3T[i] = W3[o * HID + j];
    }
    if (threadIdx.x < HID) { sb1[threadIdx.x] = b1[threadIdx.x]; sb2[threadIdx.x] = b2[threadIdx.x]; }
    if (threadIdx.x < H)   { sb3[threadIdx.x] = b3[threadIdx.x]; }
    __syncthreads();
    int e = blockIdx.x * blockDim.x + threadIdx.x;
    if (e >= E2) return;
    int s = edges[e];
    int d = (e < N_EDGES) ? edges[N_EDGES + e] : edges[e - N_EDGES];
    const float* hs = h + (size_t)s * H;
    const float* hd = h + (size_t)d * H;
    float m1[HID];
    #pragma unroll
    for (int j = 0; j < HID; ++j) m1[j] = sb1[j];
    for (int kk = 0; kk < H; ++kk) {
        float xs = hs[kk], xd = hd[kk];
        const float* w_s = &sW1T[kk * HID];
        const float* w_d = &sW1T[(H + kk) * HID];
        #pragma unroll
        for (int j = 0; j < HID; ++j) {
            m1[j] = fmaf(w_s[j], xs, m1[j]);
            m1[j] = fmaf(w_d[j], xd, m1[j]);
        }
    }
    #pragma unroll
    for (int j = 0; j < HID; ++j) m1[j] = fmaxf(m1[j], 0.0f);
    float out[H];
    #pragma unroll
    for (int o = 0; o < H; ++o) out[o] = sb3[o];
    for (int j = 0; j < HID; ++j) {
        float acc = sb2[j];
        const float* wv = &sW2[j * HID];
        #pragma unroll
        for (int kk = 0; kk < HID; ++kk) acc = fmaf(wv[kk], m1[kk], acc);
        acc = fmaxf(acc, 0.0f);
        const float* w3 = &sW3T[j * H];
        #pragma unroll
        for (int o = 0; o < H; ++o) out[o] = fmaf(w3[o], acc, out[o]);
    }
    float* as = a + (size_t)s * H;
    #pragma unroll
    for (int o = 0; o < H; ++o) atomicAdd(&as[o], out[o]);
}

// ---------------- GRU (+ bf16 h epilogue) -----------------------------------

__global__ __launch_bounds__(256) void gru_kernel(
    const float* __restrict__ h_in,
    const float* __restrict__ a,
    float* __restrict__ h_out,
    const float* __restrict__ W_ih, const float* __restrict__ b_ih,
    const float* __restrict__ W_hh, const float* __restrict__ b_hh,
    unsigned char* __restrict__ hbf)
{
    __shared__ float sWih[3 * H * H];
    __shared__ float sWhh[3 * H * H];
    __shared__ float sbih[3 * H];
    __shared__ float sbhh[3 * H];
    for (int i = threadIdx.x; i < 3 * H * H; i += blockDim.x) { sWih[i] = W_ih[i]; sWhh[i] = W_hh[i]; }
    if (threadIdx.x < 3 * H) { sbih[threadIdx.x] = b_ih[threadIdx.x]; sbhh[threadIdx.x] = b_hh[threadIdx.x]; }
    __syncthreads();

    int n = blockIdx.x * blockDim.x + threadIdx.x;
    if (n >= N_NODES) return;

    float av[H], hv[H];
    #pragma unroll
    for (int kk = 0; kk < H; ++kk) { av[kk] = a[(size_t)n * H + kk]; hv[kk] = h_in[(size_t)n * H + kk]; }

    float gi[3 * H], gh[3 * H];
    #pragma unroll
    for (int g = 0; g < 3 * H; ++g) {
        float ai = sbih[g], hh = sbhh[g];
        const float* wi = &sWih[g * H];
        const float* wh = &sWhh[g * H];
        #pragma unroll
        for (int kk = 0; kk < H; ++kk) {
            ai = fmaf(wi[kk], av[kk], ai);
            hh = fmaf(wh[kk], hv[kk], hh);
        }
        gi[g] = ai; gh[g] = hh;
    }

    float ho[H];
    #pragma unroll
    for (int o = 0; o < H; ++o) {
        float r = sigmoidf_(gi[o] + gh[o]);
        float z = sigmoidf_(gi[H + o] + gh[H + o]);
        float nn = tanhf_(gi[2 * H + o] + r * gh[2 * H + o]);
        ho[o] = (1.0f - z) * nn + z * hv[o];
        h_out[(size_t)n * H + o] = ho[o];
    }
    if (hbf) {
        unsigned w0 = pack2(ho[0], ho[1]), w1 = pack2(ho[2], ho[3]), w2 = pack2(ho[4], ho[5]),
                 w3 = pack2(ho[6], ho[7]), w4 = pack2(ho[8], ho[9]);
        unsigned char* ob = hbf + (size_t)n * 20;
        *(uint4u*)ob = (uint4u){w0, w1, w2, w3};
        *(unsigned int*)(ob + 16) = w4;
    }
}

static inline size_t align256(size_t x) { return (x + 255) & ~(size_t)255; }

extern "C" void kernel_launch(void* const* d_in, const int* in_sizes, int n_in,
                              void* d_out, int out_size, void* d_ws, size_t ws_size,
                              hipStream_t stream) {
    const float* node_features = (const float*)d_in[0];
    const int*   edges         = (const int*)d_in[1];
    const float* W1 = (const float*)d_in[2];
    const float* b1 = (const float*)d_in[3];
    const float* W2 = (const float*)d_in[4];
    const float* b2 = (const float*)d_in[5];
    const float* W3 = (const float*)d_in[6];
    const float* b3 = (const float*)d_in[7];
    const float* W_ih = (const float*)d_in[8];
    const float* b_ih = (const float*)d_in[9];
    const float* W_hh = (const float*)d_in[10];
    const float* b_hh = (const float*)d_in[11];

    char* ws = (char*)d_ws;
    size_t off = 0;
    float* a = (float*)(ws + off);     off = align256(off + (size_t)N_NODES * H * sizeof(float));
    int2* pairs = (int2*)(ws + off);   off = align256(off + (size_t)E2 * sizeof(int2));
    // region C: CSR scratch (cnt/cursor/partials) is dead before hbf/wbuf are
    // written, so they overlap.
    size_t coff = off;
    int* cnt = (int*)(ws + coff);                 size_t c1 = align256(coff + (size_t)N_NODES * sizeof(int));
    int* cursor = (int*)(ws + c1);                size_t c2 = align256(c1 + (size_t)N_NODES * sizeof(int));
    int* partials = (int*)(ws + c2);              size_t c3 = align256(c2 + (size_t)NB_SCAN * sizeof(int));
    unsigned char* hbf = (unsigned char*)(ws + coff);  size_t h1 = align256(coff + (size_t)N_NODES * 20);
    unsigned char* wbuf = (unsigned char*)(ws + h1);   size_t h2 = align256(h1 + 14400);
    size_t need = (c3 > h2) ? c3 : h2;
    const bool use_csr = (ws_size >= need);

    float* hbuf = (float*)d_out;
    const int edge_blocks = E2 / 256;                 // 12500
    const int node_blocks = (N_NODES + 255) / 256;    // 391

    if (use_csr) {
        hipMemsetAsync(cnt, 0, (size_t)N_NODES * sizeof(int), stream);
        hist_kernel<<<edge_blocks, 256, 0, stream>>>(edges, cnt);
        scan1_kernel<<<NB_SCAN, 256, 0, stream>>>(cnt, cursor, partials);
        scan2_kernel<<<1, 64, 0, stream>>>(partials, NB_SCAN);
        scan3_kernel<<<node_blocks, 256, 0, stream>>>(cursor, partials);
        scatter_striped_kernel<<<SC_CHUNKS * 8, 256, 0, stream>>>(edges, cursor, pairs);
        // CSR scratch now dead; safe to write hbf/wbuf over it
        prep_weights_kernel<<<4, 256, 0, stream>>>(W1, b1, W2, W3, b3, wbuf);
        convert_h_kernel<<<node_blocks, 256, 0, stream>>>(node_features, hbf);
    }

    for (int it = 0; it < 3; ++it) {
        hipMemsetAsync(a, 0, (size_t)N_NODES * H * sizeof(float), stream);
        const float* hin = (it == 0) ? node_features : hbuf;
        if (use_csr) {
            edge_mlp_mfma2_kernel<<<edge_blocks, 256, 0, stream>>>(
                hbf, pairs, wbuf, b2, a);
        } else {
            edge_mlp_kernel<<<edge_blocks, 256, 0, stream>>>(
                hin, edges, W1, b1, W2, b2, W3, b3, a);
        }
        gru_kernel<<<node_blocks, 256, 0, stream>>>(
            hin, a, hbuf, W_ih, b_ih, W_hh, b_hh, use_csr ? hbf : (unsigned char*)nullptr);
    }
}

// Round 8
// 620.303 us; speedup vs baseline: 8.6726x; 1.0029x over previous
//
#include <hip/hip_runtime.h>
#include <hip/hip_bf16.h>
#include <math.h>

#define N_NODES 100000
#define N_EDGES 1600000
#define H 10
#define HID 64
#define E2 (2 * N_EDGES)          // 3,200,000 (12500 blocks of 256)
#define SCAN_CHUNK 1024
#define NB_SCAN ((N_NODES + SCAN_CHUNK - 1) / SCAN_CHUNK)   // 98

// striped scatter: 8 stripes (XCD-affine via blockIdx&7) x 256 chunks
#define SC_CHUNKS 256
#define SC_CHUNK ((E2 + SC_CHUNKS - 1) / SC_CHUNKS)         // 12500
#define NODES_PER_STRIPE (N_NODES / 8)                      // 12500

typedef __attribute__((ext_vector_type(8))) short short8;
typedef __attribute__((ext_vector_type(4))) float f32x4;
typedef __attribute__((ext_vector_type(2))) unsigned int uint2v;
typedef __attribute__((ext_vector_type(4))) unsigned int uint4v;
typedef unsigned int uint4u __attribute__((ext_vector_type(4), aligned(4)));

#define MFMA16(a, b, c) __builtin_amdgcn_mfma_f32_16x16x32_bf16((a), (b), (c), 0, 0, 0)

__device__ __forceinline__ float sigmoidf_(float x) {
    return 1.0f / (1.0f + __expf(-x));
}
__device__ __forceinline__ float tanhf_(float x) {
    float ax = fabsf(x);
    float t = 1.0f - 2.0f / (__expf(2.0f * ax) + 1.0f);
    return copysignf(t, x);
}
__device__ __forceinline__ unsigned short f2bf(float f) {
    union { __hip_bfloat16 b; unsigned short u; } cv;
    cv.b = __float2bfloat16(f);   // RNE
    return cv.u;
}
__device__ __forceinline__ unsigned pack2(float lo, float hi) {
    return (unsigned)f2bf(lo) | ((unsigned)f2bf(hi) << 16);
}
// nt load of an int2 via 8B integer (builtin rejects HIP_vector_type ptrs)
__device__ __forceinline__ int2 nt_load_int2(const int2* p) {
    long long v = __builtin_nontemporal_load((const long long*)p);
    int2 r;
    r.x = (int)(v & 0xffffffffll);
    r.y = (int)(v >> 32);
    return r;
}

// ---------------- CSR build (once per launch; edges static) -----------------

__global__ __launch_bounds__(256) void hist_kernel(
    const int* __restrict__ edges, int* __restrict__ cnt)
{
    int e = blockIdx.x * 256 + threadIdx.x;
    if (e < E2) {
        int s = __builtin_nontemporal_load(edges + e);   // nt: don't thrash cnt lines
        atomicAdd(&cnt[s], 1);
    }
}

__global__ __launch_bounds__(256) void scan1_kernel(
    const int* __restrict__ cnt, int* __restrict__ excl, int* __restrict__ partials)
{
    __shared__ int sdata[256];
    int tid = threadIdx.x;
    int base = blockIdx.x * SCAN_CHUNK + tid * 4;
    int v0 = (base + 0 < N_NODES) ? cnt[base + 0] : 0;
    int v1 = (base + 1 < N_NODES) ? cnt[base + 1] : 0;
    int v2 = (base + 2 < N_NODES) ? cnt[base + 2] : 0;
    int v3 = (base + 3 < N_NODES) ? cnt[base + 3] : 0;
    int sum = v0 + v1 + v2 + v3;
    sdata[tid] = sum;
    __syncthreads();
    for (int off = 1; off < 256; off <<= 1) {
        int t = (tid >= off) ? sdata[tid - off] : 0;
        __syncthreads();
        sdata[tid] += t;
        __syncthreads();
    }
    int run = sdata[tid] - sum;
    if (tid == 255) partials[blockIdx.x] = sdata[255];
    if (base + 0 < N_NODES) { excl[base + 0] = run; run += v0; }
    if (base + 1 < N_NODES) { excl[base + 1] = run; run += v1; }
    if (base + 2 < N_NODES) { excl[base + 2] = run; run += v2; }
    if (base + 3 < N_NODES) { excl[base + 3] = run; run += v3; }
}

// parallel exclusive scan over NB_SCAN (<=128) block partials, one 128-thr block
__global__ __launch_bounds__(128) void scan2_kernel(int* partials, int nb) {
    __shared__ int s[128];
    int tid = threadIdx.x;
    int v = (tid < nb) ? partials[tid] : 0;
    s[tid] = v;
    __syncthreads();
    for (int off = 1; off < 128; off <<= 1) {
        int t = (tid >= off) ? s[tid - off] : 0;
        __syncthreads();
        s[tid] += t;
        __syncthreads();
    }
    if (tid < nb) partials[tid] = s[tid] - v;   // exclusive
}

__global__ __launch_bounds__(256) void scan3_kernel(
    int* __restrict__ excl, const int* __restrict__ partials)
{
    int i = blockIdx.x * 256 + threadIdx.x;
    if (i < N_NODES) excl[i] += partials[i / SCAN_CHUNK];
}

// Striped scatter: stripe q = blockIdx&7 handles src in [q*12500,(q+1)*12500);
// its destination region (~3.2 MB) is contiguous and XCD-L2-resident. Edge
// reads are NON-TEMPORAL so the streaming 25.6MB/stripe does not evict the
// partially-filled pairs lines from L2 -> full-line writebacks (~25.6MB total).
__global__ __launch_bounds__(256) void scatter_striped_kernel(
    const int* __restrict__ edges, int* __restrict__ cursor, int2* __restrict__ pairs)
{
    const int q = blockIdx.x & 7;
    const int c = blockIdx.x >> 3;
    const int lo = c * SC_CHUNK;
    const int hi = (lo + SC_CHUNK < E2) ? (lo + SC_CHUNK) : E2;
    for (int e = lo + threadIdx.x; e < hi; e += 256) {
        int s = __builtin_nontemporal_load(edges + e);
        if (s / NODES_PER_STRIPE != q) continue;
        int di = (e < N_EDGES) ? (N_EDGES + e) : (e - N_EDGES);
        int d = __builtin_nontemporal_load(edges + di);
        int pos = atomicAdd(&cursor[s], 1);
        pairs[pos] = make_int2(s, d);
    }
}

// ---------------- one-time precompute ---------------------------------------
// wbuf layout: 14 fragments x 64 lanes x 16B (bf16 A-operands), then b3 padded
// to 16 floats. Frags: 0..3 = W1 (b1 embedded at k==20), 4..11 = W2[nt][ks],
// 12..13 = W3 (rows >=10 zero).

#define WBUF_B3_OFF 14336   // 14*64*16

__global__ __launch_bounds__(256) void prep_weights_kernel(
    const float* __restrict__ W1, const float* __restrict__ b1,
    const float* __restrict__ W2,
    const float* __restrict__ W3, const float* __restrict__ b3,
    unsigned char* __restrict__ wbuf)
{
    int idx = blockIdx.x * 256 + threadIdx.x;   // grid=4 -> 1024 threads
    if (idx < 896) {
        int f = idx >> 6, l = idx & 63, l15 = l & 15, lo4 = l >> 4;
        unsigned short v[8];
        #pragma unroll
        for (int i = 0; i < 8; ++i) {
            int kk = lo4 * 8 + i;     // k within 32
            float val = 0.0f;
            if (f < 4) {
                int row = f * 16 + l15;
                val = (kk < 20) ? W1[row * 20 + kk] : (kk == 20 ? b1[row] : 0.0f);
            } else if (f < 12) {
                int g = f - 4, nt = g >> 1, ks = g & 1;
                val = W2[(nt * 16 + l15) * 64 + ks * 32 + kk];
            } else {
                int ks = f - 12;
                val = (l15 < 10) ? W3[l15 * 64 + ks * 32 + kk] : 0.0f;
            }
            v[i] = f2bf(val);
        }
        uint4v pk = { (unsigned)v[0] | ((unsigned)v[1] << 16),
                      (unsigned)v[2] | ((unsigned)v[3] << 16),
                      (unsigned)v[4] | ((unsigned)v[5] << 16),
                      (unsigned)v[6] | ((unsigned)v[7] << 16) };
        *(uint4v*)(wbuf + (size_t)idx * 16) = pk;
    } else if (idx < 896 + 16) {
        int o = idx - 896;
        *(float*)(wbuf + WBUF_B3_OFF + o * 4) = (o < 10) ? b3[o] : 0.0f;
    }
}

__global__ __launch_bounds__(256) void convert_h_kernel(
    const float* __restrict__ h, unsigned char* __restrict__ hbf)
{
    int n = blockIdx.x * 256 + threadIdx.x;
    if (n >= N_NODES) return;
    const float* r = h + (size_t)n * 10;
    unsigned w0 = pack2(r[0], r[1]), w1 = pack2(r[2], r[3]), w2 = pack2(r[4], r[5]),
             w3 = pack2(r[6], r[7]), w4 = pack2(r[8], r[9]);
    unsigned char* o = hbf + (size_t)n * 20;
    *(uint4u*)o = (uint4u){w0, w1, w2, w3};
    *(unsigned int*)(o + 16) = w4;
}

// ---------------- MFMA edge MLP v2 ------------------------------------------
// 256 threads = 4 waves; block handles 256 src-sorted edges. Wave w owns LDS
// rows [w*64, w*64+64) exclusively through gather + all 3 GEMMs -> NO barriers
// until the cross-wave segment reduction (2 barriers total).
// X rows are 128B with T2 XOR swizzle: 16B slot j of row r lives at j^(r&7).
// Segment heads are BLOCK-LOCAL (t==0 is always a head): boundary-spanning
// runs are split and each block atomically adds its partial sum.

__global__ __launch_bounds__(256) void edge_mlp_mfma2_kernel(
    const unsigned char* __restrict__ hbf,   // [N][20B] bf16
    const int2* __restrict__ pairs,
    const unsigned char* __restrict__ wbuf,
    const float* __restrict__ b2,
    float* __restrict__ a)
{
    __shared__ __align__(16) unsigned char sX[256 * 128];
    __shared__ unsigned long long smask[4];
    __shared__ int sheadpos[256];
    __shared__ int sheadnode[256];

    char* sXp = (char*)sX;
    const int t = threadIdx.x;
    const int w = t >> 6, l = t & 63, l15 = l & 15, lo4 = l >> 4;
    const int mbase = w * 64;

    // weight fragments (precomputed layout; L1-resident, coalesced per wave)
    short8 W1f[4], W2f[4][2], W3f[2];
    #pragma unroll
    for (int nt = 0; nt < 4; ++nt)
        W1f[nt] = *(const short8*)(wbuf + ((nt * 64 + l) << 4));
    #pragma unroll
    for (int nt = 0; nt < 4; ++nt)
        #pragma unroll
        for (int ks = 0; ks < 2; ++ks)
            W2f[nt][ks] = *(const short8*)(wbuf + (((4 + nt * 2 + ks) * 64 + l) << 4));
    #pragma unroll
    for (int ks = 0; ks < 2; ++ks)
        W3f[ks] = *(const short8*)(wbuf + (((12 + ks) * 64 + l) << 4));
    const float* b3p = (const float*)(wbuf + WBUF_B3_OFF);

    // ---- gather (bf16 rows, no conversion); nt loads for the pairs stream
    const int k = blockIdx.x * 256 + t;
    const int2 p = nt_load_int2(pairs + k);
    const int2 pm = nt_load_int2(pairs + ((k > 0) ? (k - 1) : 0));
    const bool head = (t == 0) || (pm.x != p.x);   // BLOCK-local heads

    const unsigned char* sp = hbf + (size_t)p.x * 20;
    const unsigned char* dp = hbf + (size_t)p.y * 20;
    uint4u s4 = *(const uint4u*)sp;
    unsigned int st = *(const unsigned int*)(sp + 16);
    uint4u d4 = *(const uint4u*)dp;
    unsigned int dt = *(const unsigned int*)(dp + 16);

    {
        char* row = sXp + (t << 7);
        const int sw = (t & 7) << 4;
        // cols 0-9 src, 10-19 dst, col 20 = 1.0 (bias), rest 0
        *(uint4v*)(row + (0  ^ sw)) = (uint4v){s4.x, s4.y, s4.z, s4.w};
        *(uint4v*)(row + (16 ^ sw)) = (uint4v){st, d4.x, d4.y, d4.z};
        *(uint4v*)(row + (32 ^ sw)) = (uint4v){d4.w, dt, 0x00003F80u, 0u};
        *(uint4v*)(row + (48 ^ sw)) = (uint4v){0u, 0u, 0u, 0u};
    }
    // no barrier: wave reads only its own lanes' rows (intra-wave LDS order)

    const int srow = (l15 & 7) << 4;

    // ---- GEMM1: K=32 (slots 0-3); bias embedded in W1 col 20
    #pragma unroll
    for (int mt = 0; mt < 4; ++mt) {
        const int rb = (mbase + mt * 16 + l15) << 7;
        short8 Bf = *(const short8*)(sXp + rb + ((lo4 << 4) ^ srow));
        #pragma unroll
        for (int nt = 0; nt < 4; ++nt) {
            f32x4 acc = {0.0f, 0.0f, 0.0f, 0.0f};
            acc = MFMA16(W1f[nt], Bf, acc);
            acc[0] = fmaxf(acc[0], 0.0f); acc[1] = fmaxf(acc[1], 0.0f);
            acc[2] = fmaxf(acc[2], 0.0f); acc[3] = fmaxf(acc[3], 0.0f);
            uint2v pk = { pack2(acc[0], acc[1]), pack2(acc[2], acc[3]) };
            const int jy = (nt * 2 + (lo4 >> 1)) << 4;
            *(uint2v*)(sXp + rb + (jy ^ srow) + ((lo4 & 1) << 3)) = pk;
        }
    }

    // ---- GEMM2: K=64 (slots 0-7), bias b2 (L1)
    #pragma unroll
    for (int mt = 0; mt < 4; ++mt) {
        const int rb = (mbase + mt * 16 + l15) << 7;
        short8 B0 = *(const short8*)(sXp + rb + ((lo4 << 4) ^ srow));
        short8 B1 = *(const short8*)(sXp + rb + (((4 + lo4) << 4) ^ srow));
        #pragma unroll
        for (int nt = 0; nt < 4; ++nt) {
            f32x4 acc = *(const f32x4*)(b2 + nt * 16 + lo4 * 4);
            acc = MFMA16(W2f[nt][0], B0, acc);
            acc = MFMA16(W2f[nt][1], B1, acc);
            acc[0] = fmaxf(acc[0], 0.0f); acc[1] = fmaxf(acc[1], 0.0f);
            acc[2] = fmaxf(acc[2], 0.0f); acc[3] = fmaxf(acc[3], 0.0f);
            uint2v pk = { pack2(acc[0], acc[1]), pack2(acc[2], acc[3]) };
            const int jy = (nt * 2 + (lo4 >> 1)) << 4;
            *(uint2v*)(sXp + rb + (jy ^ srow) + ((lo4 & 1) << 3)) = pk;
        }
    }

    // ---- GEMM3: 16 out-feats (10 valid), K=64; f32 out overwrites slots 0-3
    #pragma unroll
    for (int mt = 0; mt < 4; ++mt) {
        const int rb = (mbase + mt * 16 + l15) << 7;
        short8 B0 = *(const short8*)(sXp + rb + ((lo4 << 4) ^ srow));
        short8 B1 = *(const short8*)(sXp + rb + (((4 + lo4) << 4) ^ srow));
        f32x4 acc = *(const f32x4*)(b3p + lo4 * 4);
        acc = MFMA16(W3f[0], B0, acc);
        acc = MFMA16(W3f[1], B1, acc);
        *(f32x4*)(sXp + rb + ((lo4 << 4) ^ srow)) = acc;
    }

    // ---- segment list via ballot (block-local heads)
    unsigned long long m = __ballot(head);
    if ((t & 63) == 0) smask[w] = m;
    __syncthreads();   // A: out rows + smask visible

    int base = 0, nseg = 0;
    #pragma unroll
    for (int j = 0; j < 4; ++j) {
        int c = __popcll(smask[j]);
        if (j < w) base += c;
        nseg += c;
    }
    if (head) {
        int rank = base + __popcll(m & ((1ull << (t & 63)) - 1ull));
        sheadpos[rank] = t;
        sheadnode[rank] = p.x;
    }
    __syncthreads();   // B: head list visible

    // ---- one thread per (segment, feature): sum run, single atomic
    const int total = nseg * 10;
    for (int q = t; q < total; q += 256) {
        int seg = q / 10;
        int o = q - seg * 10;
        int r0 = sheadpos[seg];
        int r1 = (seg + 1 < nseg) ? sheadpos[seg + 1] : 256;
        const int obase = ((o >> 2) << 4) + ((o & 3) << 2);
        float acc = 0.0f;
        for (int r = r0; r < r1; ++r)
            acc += *(const float*)(sXp + (r << 7) + (obase ^ ((r & 7) << 4)));
        atomicAdd(&a[(size_t)sheadnode[seg] * H + o], acc);
    }
}

// ---------------- fallback VALU edge kernel (no CSR workspace) --------------

__global__ __launch_bounds__(256) void edge_mlp_kernel(
    const float* __restrict__ h,
    const int*   __restrict__ edges,
    const float* __restrict__ W1, const float* __restrict__ b1,
    const float* __restrict__ W2, const float* __restrict__ b2,
    const float* __restrict__ W3, const float* __restrict__ b3,
    float* __restrict__ a)
{
    __shared__ float sW1T[2 * H * HID];
    __shared__ float sb1[HID];
    __shared__ float sW2[HID * HID];
    __shared__ float sb2[HID];
    __shared__ float sW3T[HID * H];
    __shared__ float sb3[H];
    for (int i = threadIdx.x; i < 2 * H * HID; i += blockDim.x) {
        int kk = i >> 6, j = i & 63;
        sW1T[i] = W1[j * (2 * H) + kk];
    }
    for (int i = threadIdx.x; i < HID * HID; i += blockDim.x) sW2[i] = W2[i];
    for (int i = threadIdx.x; i < HID * H; i += blockDim.x) {
        int j = i / H, o = i - j * H;
        sW3T[i] = W3[o * HID + j];
    }
    if (threadIdx.x < HID) { sb1[threadIdx.x] = b1[threadIdx.x]; sb2[threadIdx.x] = b2[threadIdx.x]; }
    if (threadIdx.x < H)   { sb3[threadIdx.x] = b3[threadIdx.x]; }
    __syncthreads();
    int e = blockIdx.x * blockDim.x + threadIdx.x;
    if (e >= E2) return;
    int s = edges[e];
    int d = (e < N_EDGES) ? edges[N_EDGES + e] : edges[e - N_EDGES];
    const float* hs = h + (size_t)s * H;
    const float* hd = h + (size_t)d * H;
    float m1[HID];
    #pragma unroll
    for (int j = 0; j < HID; ++j) m1[j] = sb1[j];
    for (int kk = 0; kk < H; ++kk) {
        float xs = hs[kk], xd = hd[kk];
        const float* w_s = &sW1T[kk * HID];
        const float* w_d = &sW1T[(H + kk) * HID];
        #pragma unroll
        for (int j = 0; j < HID; ++j) {
            m1[j] = fmaf(w_s[j], xs, m1[j]);
            m1[j] = fmaf(w_d[j], xd, m1[j]);
        }
    }
    #pragma unroll
    for (int j = 0; j < HID; ++j) m1[j] = fmaxf(m1[j], 0.0f);
    float out[H];
    #pragma unroll
    for (int o = 0; o < H; ++o) out[o] = sb3[o];
    for (int j = 0; j < HID; ++j) {
        float acc = sb2[j];
        const float* wv = &sW2[j * HID];
        #pragma unroll
        for (int kk = 0; kk < HID; ++kk) acc = fmaf(wv[kk], m1[kk], acc);
        acc = fmaxf(acc, 0.0f);
        const float* w3 = &sW3T[j * H];
        #pragma unroll
        for (int o = 0; o < H; ++o) out[o] = fmaf(w3[o], acc, out[o]);
    }
    float* as = a + (size_t)s * H;
    #pragma unroll
    for (int o = 0; o < H; ++o) atomicAdd(&as[o], out[o]);
}

// ---------------- GRU (+ bf16 h epilogue) -----------------------------------

__global__ __launch_bounds__(256) void gru_kernel(
    const float* __restrict__ h_in,
    const float* __restrict__ a,
    float* __restrict__ h_out,
    const float* __restrict__ W_ih, const float* __restrict__ b_ih,
    const float* __restrict__ W_hh, const float* __restrict__ b_hh,
    unsigned char* __restrict__ hbf)
{
    __shared__ float sWih[3 * H * H];
    __shared__ float sWhh[3 * H * H];
    __shared__ float sbih[3 * H];
    __shared__ float sbhh[3 * H];
    for (int i = threadIdx.x; i < 3 * H * H; i += blockDim.x) { sWih[i] = W_ih[i]; sWhh[i] = W_hh[i]; }
    if (threadIdx.x < 3 * H) { sbih[threadIdx.x] = b_ih[threadIdx.x]; sbhh[threadIdx.x] = b_hh[threadIdx.x]; }
    __syncthreads();

    int n = blockIdx.x * blockDim.x + threadIdx.x;
    if (n >= N_NODES) return;

    float av[H], hv[H];
    #pragma unroll
    for (int kk = 0; kk < H; ++kk) { av[kk] = a[(size_t)n * H + kk]; hv[kk] = h_in[(size_t)n * H + kk]; }

    float gi[3 * H], gh[3 * H];
    #pragma unroll
    for (int g = 0; g < 3 * H; ++g) {
        float ai = sbih[g], hh = sbhh[g];
        const float* wi = &sWih[g * H];
        const float* wh = &sWhh[g * H];
        #pragma unroll
        for (int kk = 0; kk < H; ++kk) {
            ai = fmaf(wi[kk], av[kk], ai);
            hh = fmaf(wh[kk], hv[kk], hh);
        }
        gi[g] = ai; gh[g] = hh;
    }

    float ho[H];
    #pragma unroll
    for (int o = 0; o < H; ++o) {
        float r = sigmoidf_(gi[o] + gh[o]);
        float z = sigmoidf_(gi[H + o] + gh[H + o]);
        float nn = tanhf_(gi[2 * H + o] + r * gh[2 * H + o]);
        ho[o] = (1.0f - z) * nn + z * hv[o];
        h_out[(size_t)n * H + o] = ho[o];
    }
    if (hbf) {
        unsigned w0 = pack2(ho[0], ho[1]), w1 = pack2(ho[2], ho[3]), w2 = pack2(ho[4], ho[5]),
                 w3 = pack2(ho[6], ho[7]), w4 = pack2(ho[8], ho[9]);
        unsigned char* ob = hbf + (size_t)n * 20;
        *(uint4u*)ob = (uint4u){w0, w1, w2, w3};
        *(unsigned int*)(ob + 16) = w4;
    }
}

static inline size_t align256(size_t x) { return (x + 255) & ~(size_t)255; }

extern "C" void kernel_launch(void* const* d_in, const int* in_sizes, int n_in,
                              void* d_out, int out_size, void* d_ws, size_t ws_size,
                              hipStream_t stream) {
    const float* node_features = (const float*)d_in[0];
    const int*   edges         = (const int*)d_in[1];
    const float* W1 = (const float*)d_in[2];
    const float* b1 = (const float*)d_in[3];
    const float* W2 = (const float*)d_in[4];
    const float* b2 = (const float*)d_in[5];
    const float* W3 = (const float*)d_in[6];
    const float* b3 = (const float*)d_in[7];
    const float* W_ih = (const float*)d_in[8];
    const float* b_ih = (const float*)d_in[9];
    const float* W_hh = (const float*)d_in[10];
    const float* b_hh = (const float*)d_in[11];

    char* ws = (char*)d_ws;
    size_t off = 0;
    float* a = (float*)(ws + off);     off = align256(off + (size_t)N_NODES * H * sizeof(float));
    int2* pairs = (int2*)(ws + off);   off = align256(off + (size_t)E2 * sizeof(int2));
    // region C: CSR scratch (cnt/cursor/partials) is dead before hbf/wbuf are
    // written, so they overlap.
    size_t coff = off;
    int* cnt = (int*)(ws + coff);                 size_t c1 = align256(coff + (size_t)N_NODES * sizeof(int));
    int* cursor = (int*)(ws + c1);                size_t c2 = align256(c1 + (size_t)N_NODES * sizeof(int));
    int* partials = (int*)(ws + c2);              size_t c3 = align256(c2 + (size_t)NB_SCAN * sizeof(int));
    unsigned char* hbf = (unsigned char*)(ws + coff);  size_t h1 = align256(coff + (size_t)N_NODES * 20);
    unsigned char* wbuf = (unsigned char*)(ws + h1);   size_t h2 = align256(h1 + 14400);
    size_t need = (c3 > h2) ? c3 : h2;
    const bool use_csr = (ws_size >= need);

    float* hbuf = (float*)d_out;
    const int edge_blocks = E2 / 256;                 // 12500
    const int node_blocks = (N_NODES + 255) / 256;    // 391

    if (use_csr) {
        hipMemsetAsync(cnt, 0, (size_t)N_NODES * sizeof(int), stream);
        hist_kernel<<<edge_blocks, 256, 0, stream>>>(edges, cnt);
        scan1_kernel<<<NB_SCAN, 256, 0, stream>>>(cnt, cursor, partials);
        scan2_kernel<<<1, 128, 0, stream>>>(partials, NB_SCAN);
        scan3_kernel<<<node_blocks, 256, 0, stream>>>(cursor, partials);
        scatter_striped_kernel<<<SC_CHUNKS * 8, 256, 0, stream>>>(edges, cursor, pairs);
        // CSR scratch now dead; safe to write hbf/wbuf over it
        prep_weights_kernel<<<4, 256, 0, stream>>>(W1, b1, W2, W3, b3, wbuf);
        convert_h_kernel<<<node_blocks, 256, 0, stream>>>(node_features, hbf);
    }

    for (int it = 0; it < 3; ++it) {
        hipMemsetAsync(a, 0, (size_t)N_NODES * H * sizeof(float), stream);
        const float* hin = (it == 0) ? node_features : hbuf;
        if (use_csr) {
            edge_mlp_mfma2_kernel<<<edge_blocks, 256, 0, stream>>>(
                hbf, pairs, wbuf, b2, a);
        } else {
            edge_mlp_kernel<<<edge_blocks, 256, 0, stream>>>(
                hin, edges, W1, b1, W2, b2, W3, b3, a);
        }
        gru_kernel<<<node_blocks, 256, 0, stream>>>(
            hin, a, hbuf, W_ih, b_ih, W_hh, b_hh, use_csr ? hbf : (unsigned char*)nullptr);
    }
}

// Round 9
// 417.154 us; speedup vs baseline: 12.8961x; 1.4870x over previous
//
#include <hip/hip_runtime.h>
#include <hip/hip_bf16.h>
#include <math.h>

#define N_NODES 100000
#define N_EDGES 1600000
#define H 10
#define HID 64
#define E2 (2 * N_EDGES)          // 3,200,000

// two-level counting sort: 391 buckets of 256 nodes (b = src >> 8)
#define NBKT 391                  // ceil(100000/256)
#define NCHUNK 256
#define CHUNK (E2 / NCHUNK)       // 12500 exact
#define BKT_CAP 12032             // LDS staging cap (mean 8192, sigma ~90 -> 42 sigma)

typedef __attribute__((ext_vector_type(8))) short short8;
typedef __attribute__((ext_vector_type(4))) float f32x4;
typedef __attribute__((ext_vector_type(2))) unsigned int uint2v;
typedef __attribute__((ext_vector_type(4))) unsigned int uint4v;
typedef unsigned int uint4u __attribute__((ext_vector_type(4), aligned(4)));

#define MFMA16(a, b, c) __builtin_amdgcn_mfma_f32_16x16x32_bf16((a), (b), (c), 0, 0, 0)

__device__ __forceinline__ float sigmoidf_(float x) {
    return 1.0f / (1.0f + __expf(-x));
}
__device__ __forceinline__ float tanhf_(float x) {
    float ax = fabsf(x);
    float t = 1.0f - 2.0f / (__expf(2.0f * ax) + 1.0f);
    return copysignf(t, x);
}
__device__ __forceinline__ unsigned short f2bf(float f) {
    union { __hip_bfloat16 b; unsigned short u; } cv;
    cv.b = __float2bfloat16(f);   // RNE
    return cv.u;
}
__device__ __forceinline__ unsigned pack2(float lo, float hi) {
    return (unsigned)f2bf(lo) | ((unsigned)f2bf(hi) << 16);
}
__device__ __forceinline__ int2 ll2int2(long long v) {
    int2 r;
    r.x = (int)(v & 0xffffffffll);   // src in low word
    r.y = (int)(v >> 32);            // dst in high word
    return r;
}

// ---------------- CSR build v2: deterministic counting sort -----------------

// k1: per-chunk histogram over 391 buckets (LDS atomics only)
__global__ __launch_bounds__(256) void binhist_kernel(
    const int* __restrict__ edges, int* __restrict__ cntmat)
{
    __shared__ int cnt[NBKT];
    for (int i = threadIdx.x; i < NBKT; i += 256) cnt[i] = 0;
    __syncthreads();
    const int c = blockIdx.x, lo = c * CHUNK;
    for (int i = threadIdx.x; i < CHUNK; i += 256) {
        int s = edges[lo + i];
        atomicAdd(&cnt[s >> 8], 1);
    }
    __syncthreads();
    for (int i = threadIdx.x; i < NBKT; i += 256) cntmat[i * NCHUNK + c] = cnt[i];
}

// k2: per-bucket exclusive scan over its 256 chunk-counts; totals[b] = sum
__global__ __launch_bounds__(256) void bucketscan_kernel(
    const int* __restrict__ cntmat, int* __restrict__ offmat, int* __restrict__ totals)
{
    __shared__ int s[NCHUNK];
    const int b = blockIdx.x, tid = threadIdx.x;
    int v = cntmat[b * NCHUNK + tid];
    s[tid] = v;
    __syncthreads();
    for (int off = 1; off < 256; off <<= 1) {
        int t = (tid >= off) ? s[tid - off] : 0;
        __syncthreads();
        s[tid] += t;
        __syncthreads();
    }
    offmat[b * NCHUNK + tid] = s[tid] - v;
    if (tid == 255) totals[b] = s[255];
}

// k3: exclusive scan over bucket totals -> bases
__global__ __launch_bounds__(512) void basescan_kernel(
    const int* __restrict__ totals, int* __restrict__ bases)
{
    __shared__ int s[512];
    const int tid = threadIdx.x;
    int v = (tid < NBKT) ? totals[tid] : 0;
    s[tid] = v;
    __syncthreads();
    for (int off = 1; off < 512; off <<= 1) {
        int t = (tid >= off) ? s[tid - off] : 0;
        __syncthreads();
        s[tid] += t;
        __syncthreads();
    }
    if (tid < NBKT) bases[tid] = s[tid] - v;
}

// k4: scatter edges grouped by bucket at precomputed offsets (no global
// atomics; runs of ~32 edges per (block,bucket) -> near-coalesced writes)
__global__ __launch_bounds__(256) void binscatter_kernel(
    const int* __restrict__ edges, const int* __restrict__ offmat,
    const int* __restrict__ bases, long long* __restrict__ pairsLL)
{
    __shared__ int cursor[NBKT];
    const int c = blockIdx.x, lo = c * CHUNK;
    for (int i = threadIdx.x; i < NBKT; i += 256)
        cursor[i] = bases[i] + offmat[i * NCHUNK + c];
    __syncthreads();
    for (int i = threadIdx.x; i < CHUNK; i += 256) {
        int e = lo + i;
        int s = edges[e];
        int d = (e < N_EDGES) ? edges[e + N_EDGES] : edges[e - N_EDGES];
        int pos = atomicAdd(&cursor[s >> 8], 1);   // LDS atomic
        pairsLL[pos] = (long long)(unsigned)s | ((long long)d << 32);
    }
}

// k5: sort each bucket by node in LDS (96KB staging), write back in place.
// If a bucket exceeded BKT_CAP (statistically impossible) it stays unsorted,
// which is still CORRECT: the MLP's segmented reduction is order-agnostic.
__global__ __launch_bounds__(256) void bucketsort_kernel(
    const int* __restrict__ totals, const int* __restrict__ bases,
    long long* __restrict__ pairsLL)
{
    __shared__ long long sE[BKT_CAP];
    __shared__ int cnt[256];
    __shared__ int cur[256];
    const int b = blockIdx.x, tid = threadIdx.x;
    const int tot = totals[b], base = bases[b];
    if (tot > BKT_CAP) return;
    for (int i = tid; i < tot; i += 256) sE[i] = pairsLL[base + i];
    cnt[tid] = 0;
    __syncthreads();
    for (int i = tid; i < tot; i += 256)
        atomicAdd(&cnt[((int)sE[i]) & 255], 1);
    __syncthreads();
    int v = cnt[tid];
    cur[tid] = v;
    __syncthreads();
    for (int off = 1; off < 256; off <<= 1) {
        int t = (tid >= off) ? cur[tid - off] : 0;
        __syncthreads();
        cur[tid] += t;
        __syncthreads();
    }
    cnt[tid] = cur[tid] - v;   // exclusive start -> running cursor
    __syncthreads();
    for (int i = tid; i < tot; i += 256) {
        long long e = sE[i];
        int r = atomicAdd(&cnt[((int)e) & 255], 1);
        pairsLL[base + r] = e;   // random within ~65KB L2-resident region
    }
}

// ---------------- one-time precompute ---------------------------------------
// wbuf layout: 14 fragments x 64 lanes x 16B (bf16 A-operands), then b3 padded
// to 16 floats. Frags: 0..3 = W1 (b1 embedded at k==20), 4..11 = W2[nt][ks],
// 12..13 = W3 (rows >=10 zero).

#define WBUF_B3_OFF 14336   // 14*64*16

__global__ __launch_bounds__(256) void prep_weights_kernel(
    const float* __restrict__ W1, const float* __restrict__ b1,
    const float* __restrict__ W2,
    const float* __restrict__ W3, const float* __restrict__ b3,
    unsigned char* __restrict__ wbuf)
{
    int idx = blockIdx.x * 256 + threadIdx.x;   // grid=4 -> 1024 threads
    if (idx < 896) {
        int f = idx >> 6, l = idx & 63, l15 = l & 15, lo4 = l >> 4;
        unsigned short v[8];
        #pragma unroll
        for (int i = 0; i < 8; ++i) {
            int kk = lo4 * 8 + i;     // k within 32
            float val = 0.0f;
            if (f < 4) {
                int row = f * 16 + l15;
                val = (kk < 20) ? W1[row * 20 + kk] : (kk == 20 ? b1[row] : 0.0f);
            } else if (f < 12) {
                int g = f - 4, nt = g >> 1, ks = g & 1;
                val = W2[(nt * 16 + l15) * 64 + ks * 32 + kk];
            } else {
                int ks = f - 12;
                val = (l15 < 10) ? W3[l15 * 64 + ks * 32 + kk] : 0.0f;
            }
            v[i] = f2bf(val);
        }
        uint4v pk = { (unsigned)v[0] | ((unsigned)v[1] << 16),
                      (unsigned)v[2] | ((unsigned)v[3] << 16),
                      (unsigned)v[4] | ((unsigned)v[5] << 16),
                      (unsigned)v[6] | ((unsigned)v[7] << 16) };
        *(uint4v*)(wbuf + (size_t)idx * 16) = pk;
    } else if (idx < 896 + 16) {
        int o = idx - 896;
        *(float*)(wbuf + WBUF_B3_OFF + o * 4) = (o < 10) ? b3[o] : 0.0f;
    }
}

__global__ __launch_bounds__(256) void convert_h_kernel(
    const float* __restrict__ h, unsigned char* __restrict__ hbf)
{
    int n = blockIdx.x * 256 + threadIdx.x;
    if (n >= N_NODES) return;
    const float* r = h + (size_t)n * 10;
    unsigned w0 = pack2(r[0], r[1]), w1 = pack2(r[2], r[3]), w2 = pack2(r[4], r[5]),
             w3 = pack2(r[6], r[7]), w4 = pack2(r[8], r[9]);
    unsigned char* o = hbf + (size_t)n * 20;
    *(uint4u*)o = (uint4u){w0, w1, w2, w3};
    *(unsigned int*)(o + 16) = w4;
}

// ---------------- MFMA edge MLP ---------------------------------------------
// 256 threads = 4 waves; block handles 256 src-sorted edges. Wave w owns LDS
// rows [w*64, w*64+64) exclusively through gather + all 3 GEMMs -> NO barriers
// until the cross-wave segment reduction (2 barriers total).
// X rows are 128B with T2 XOR swizzle: 16B slot j of row r lives at j^(r&7).
// Segment heads are BLOCK-LOCAL (t==0 is always a head).

__global__ __launch_bounds__(256) void edge_mlp_mfma2_kernel(
    const unsigned char* __restrict__ hbf,   // [N][20B] bf16
    const long long* __restrict__ pairsLL,
    const unsigned char* __restrict__ wbuf,
    const float* __restrict__ b2,
    float* __restrict__ a)
{
    __shared__ __align__(16) unsigned char sX[256 * 128];
    __shared__ unsigned long long smask[4];
    __shared__ int sheadpos[256];
    __shared__ int sheadnode[256];

    char* sXp = (char*)sX;
    const int t = threadIdx.x;
    const int w = t >> 6, l = t & 63, l15 = l & 15, lo4 = l >> 4;
    const int mbase = w * 64;

    // weight fragments (precomputed layout; L1-resident, coalesced per wave)
    short8 W1f[4], W2f[4][2], W3f[2];
    #pragma unroll
    for (int nt = 0; nt < 4; ++nt)
        W1f[nt] = *(const short8*)(wbuf + ((nt * 64 + l) << 4));
    #pragma unroll
    for (int nt = 0; nt < 4; ++nt)
        #pragma unroll
        for (int ks = 0; ks < 2; ++ks)
            W2f[nt][ks] = *(const short8*)(wbuf + (((4 + nt * 2 + ks) * 64 + l) << 4));
    #pragma unroll
    for (int ks = 0; ks < 2; ++ks)
        W3f[ks] = *(const short8*)(wbuf + (((12 + ks) * 64 + l) << 4));
    const float* b3p = (const float*)(wbuf + WBUF_B3_OFF);

    // ---- gather (bf16 rows, no conversion)
    const int k = blockIdx.x * 256 + t;
    const int2 p = ll2int2(__builtin_nontemporal_load(pairsLL + k));
    const int2 pm = ll2int2(__builtin_nontemporal_load(pairsLL + ((k > 0) ? (k - 1) : 0)));
    const bool head = (t == 0) || (pm.x != p.x);   // BLOCK-local heads

    const unsigned char* sp = hbf + (size_t)p.x * 20;
    const unsigned char* dp = hbf + (size_t)p.y * 20;
    uint4u s4 = *(const uint4u*)sp;
    unsigned int st = *(const unsigned int*)(sp + 16);
    uint4u d4 = *(const uint4u*)dp;
    unsigned int dt = *(const unsigned int*)(dp + 16);

    {
        char* row = sXp + (t << 7);
        const int sw = (t & 7) << 4;
        // cols 0-9 src, 10-19 dst, col 20 = 1.0 (bias), rest 0
        *(uint4v*)(row + (0  ^ sw)) = (uint4v){s4.x, s4.y, s4.z, s4.w};
        *(uint4v*)(row + (16 ^ sw)) = (uint4v){st, d4.x, d4.y, d4.z};
        *(uint4v*)(row + (32 ^ sw)) = (uint4v){d4.w, dt, 0x00003F80u, 0u};
        *(uint4v*)(row + (48 ^ sw)) = (uint4v){0u, 0u, 0u, 0u};
    }
    // no barrier: wave reads only its own lanes' rows (intra-wave LDS order)

    const int srow = (l15 & 7) << 4;

    // ---- GEMM1: K=32 (slots 0-3); bias embedded in W1 col 20
    #pragma unroll
    for (int mt = 0; mt < 4; ++mt) {
        const int rb = (mbase + mt * 16 + l15) << 7;
        short8 Bf = *(const short8*)(sXp + rb + ((lo4 << 4) ^ srow));
        #pragma unroll
        for (int nt = 0; nt < 4; ++nt) {
            f32x4 acc = {0.0f, 0.0f, 0.0f, 0.0f};
            acc = MFMA16(W1f[nt], Bf, acc);
            acc[0] = fmaxf(acc[0], 0.0f); acc[1] = fmaxf(acc[1], 0.0f);
            acc[2] = fmaxf(acc[2], 0.0f); acc[3] = fmaxf(acc[3], 0.0f);
            uint2v pk = { pack2(acc[0], acc[1]), pack2(acc[2], acc[3]) };
            const int jy = (nt * 2 + (lo4 >> 1)) << 4;
            *(uint2v*)(sXp + rb + (jy ^ srow) + ((lo4 & 1) << 3)) = pk;
        }
    }

    // ---- GEMM2: K=64 (slots 0-7), bias b2 (L1)
    #pragma unroll
    for (int mt = 0; mt < 4; ++mt) {
        const int rb = (mbase + mt * 16 + l15) << 7;
        short8 B0 = *(const short8*)(sXp + rb + ((lo4 << 4) ^ srow));
        short8 B1 = *(const short8*)(sXp + rb + (((4 + lo4) << 4) ^ srow));
        #pragma unroll
        for (int nt = 0; nt < 4; ++nt) {
            f32x4 acc = *(const f32x4*)(b2 + nt * 16 + lo4 * 4);
            acc = MFMA16(W2f[nt][0], B0, acc);
            acc = MFMA16(W2f[nt][1], B1, acc);
            acc[0] = fmaxf(acc[0], 0.0f); acc[1] = fmaxf(acc[1], 0.0f);
            acc[2] = fmaxf(acc[2], 0.0f); acc[3] = fmaxf(acc[3], 0.0f);
            uint2v pk = { pack2(acc[0], acc[1]), pack2(acc[2], acc[3]) };
            const int jy = (nt * 2 + (lo4 >> 1)) << 4;
            *(uint2v*)(sXp + rb + (jy ^ srow) + ((lo4 & 1) << 3)) = pk;
        }
    }

    // ---- GEMM3: 16 out-feats (10 valid), K=64; f32 out overwrites slots 0-3
    #pragma unroll
    for (int mt = 0; mt < 4; ++mt) {
        const int rb = (mbase + mt * 16 + l15) << 7;
        short8 B0 = *(const short8*)(sXp + rb + ((lo4 << 4) ^ srow));
        short8 B1 = *(const short8*)(sXp + rb + (((4 + lo4) << 4) ^ srow));
        f32x4 acc = *(const f32x4*)(b3p + lo4 * 4);
        acc = MFMA16(W3f[0], B0, acc);
        acc = MFMA16(W3f[1], B1, acc);
        *(f32x4*)(sXp + rb + ((lo4 << 4) ^ srow)) = acc;
    }

    // ---- segment list via ballot (block-local heads)
    unsigned long long m = __ballot(head);
    if ((t & 63) == 0) smask[w] = m;
    __syncthreads();   // A: out rows + smask visible

    int base = 0, nseg = 0;
    #pragma unroll
    for (int j = 0; j < 4; ++j) {
        int c = __popcll(smask[j]);
        if (j < w) base += c;
        nseg += c;
    }
    if (head) {
        int rank = base + __popcll(m & ((1ull << (t & 63)) - 1ull));
        sheadpos[rank] = t;
        sheadnode[rank] = p.x;
    }
    __syncthreads();   // B: head list visible

    // ---- one thread per (segment, feature): sum run, single atomic
    const int total = nseg * 10;
    for (int q = t; q < total; q += 256) {
        int seg = q / 10;
        int o = q - seg * 10;
        int r0 = sheadpos[seg];
        int r1 = (seg + 1 < nseg) ? sheadpos[seg + 1] : 256;
        const int obase = ((o >> 2) << 4) + ((o & 3) << 2);
        float acc = 0.0f;
        for (int r = r0; r < r1; ++r)
            acc += *(const float*)(sXp + (r << 7) + (obase ^ ((r & 7) << 4)));
        atomicAdd(&a[(size_t)sheadnode[seg] * H + o], acc);
    }
}

// ---------------- fallback VALU edge kernel (no CSR workspace) --------------

__global__ __launch_bounds__(256) void edge_mlp_kernel(
    const float* __restrict__ h,
    const int*   __restrict__ edges,
    const float* __restrict__ W1, const float* __restrict__ b1,
    const float* __restrict__ W2, const float* __restrict__ b2,
    const float* __restrict__ W3, const float* __restrict__ b3,
    float* __restrict__ a)
{
    __shared__ float sW1T[2 * H * HID];
    __shared__ float sb1[HID];
    __shared__ float sW2[HID * HID];
    __shared__ float sb2[HID];
    __shared__ float sW3T[HID * H];
    __shared__ float sb3[H];
    for (int i = threadIdx.x; i < 2 * H * HID; i += blockDim.x) {
        int kk = i >> 6, j = i & 63;
        sW1T[i] = W1[j * (2 * H) + kk];
    }
    for (int i = threadIdx.x; i < HID * HID; i += blockDim.x) sW2[i] = W2[i];
    for (int i = threadIdx.x; i < HID * H; i += blockDim.x) {
        int j = i / H, o = i - j * H;
        sW3T[i] = W3[o * HID + j];
    }
    if (threadIdx.x < HID) { sb1[threadIdx.x] = b1[threadIdx.x]; sb2[threadIdx.x] = b2[threadIdx.x]; }
    if (threadIdx.x < H)   { sb3[threadIdx.x] = b3[threadIdx.x]; }
    __syncthreads();
    int e = blockIdx.x * blockDim.x + threadIdx.x;
    if (e >= E2) return;
    int s = edges[e];
    int d = (e < N_EDGES) ? edges[N_EDGES + e] : edges[e - N_EDGES];
    const float* hs = h + (size_t)s * H;
    const float* hd = h + (size_t)d * H;
    float m1[HID];
    #pragma unroll
    for (int j = 0; j < HID; ++j) m1[j] = sb1[j];
    for (int kk = 0; kk < H; ++kk) {
        float xs = hs[kk], xd = hd[kk];
        const float* w_s = &sW1T[kk * HID];
        const float* w_d = &sW1T[(H + kk) * HID];
        #pragma unroll
        for (int j = 0; j < HID; ++j) {
            m1[j] = fmaf(w_s[j], xs, m1[j]);
            m1[j] = fmaf(w_d[j], xd, m1[j]);
        }
    }
    #pragma unroll
    for (int j = 0; j < HID; ++j) m1[j] = fmaxf(m1[j], 0.0f);
    float out[H];
    #pragma unroll
    for (int o = 0; o < H; ++o) out[o] = sb3[o];
    for (int j = 0; j < HID; ++j) {
        float acc = sb2[j];
        const float* wv = &sW2[j * HID];
        #pragma unroll
        for (int kk = 0; kk < HID; ++kk) acc = fmaf(wv[kk], m1[kk], acc);
        acc = fmaxf(acc, 0.0f);
        const float* w3 = &sW3T[j * H];
        #pragma unroll
        for (int o = 0; o < H; ++o) out[o] = fmaf(w3[o], acc, out[o]);
    }
    float* as = a + (size_t)s * H;
    #pragma unroll
    for (int o = 0; o < H; ++o) atomicAdd(&as[o], out[o]);
}

// ---------------- GRU (+ bf16 h epilogue) -----------------------------------

__global__ __launch_bounds__(256) void gru_kernel(
    const float* __restrict__ h_in,
    const float* __restrict__ a,
    float* __restrict__ h_out,
    const float* __restrict__ W_ih, const float* __restrict__ b_ih,
    const float* __restrict__ W_hh, const float* __restrict__ b_hh,
    unsigned char* __restrict__ hbf)
{
    __shared__ float sWih[3 * H * H];
    __shared__ float sWhh[3 * H * H];
    __shared__ float sbih[3 * H];
    __shared__ float sbhh[3 * H];
    for (int i = threadIdx.x; i < 3 * H * H; i += blockDim.x) { sWih[i] = W_ih[i]; sWhh[i] = W_hh[i]; }
    if (threadIdx.x < 3 * H) { sbih[threadIdx.x] = b_ih[threadIdx.x]; sbhh[threadIdx.x] = b_hh[threadIdx.x]; }
    __syncthreads();

    int n = blockIdx.x * blockDim.x + threadIdx.x;
    if (n >= N_NODES) return;

    float av[H], hv[H];
    #pragma unroll
    for (int kk = 0; kk < H; ++kk) { av[kk] = a[(size_t)n * H + kk]; hv[kk] = h_in[(size_t)n * H + kk]; }

    float gi[3 * H], gh[3 * H];
    #pragma unroll
    for (int g = 0; g < 3 * H; ++g) {
        float ai = sbih[g], hh = sbhh[g];
        const float* wi = &sWih[g * H];
        const float* wh = &sWhh[g * H];
        #pragma unroll
        for (int kk = 0; kk < H; ++kk) {
            ai = fmaf(wi[kk], av[kk], ai);
            hh = fmaf(wh[kk], hv[kk], hh);
        }
        gi[g] = ai; gh[g] = hh;
    }

    float ho[H];
    #pragma unroll
    for (int o = 0; o < H; ++o) {
        float r = sigmoidf_(gi[o] + gh[o]);
        float z = sigmoidf_(gi[H + o] + gh[H + o]);
        float nn = tanhf_(gi[2 * H + o] + r * gh[2 * H + o]);
        ho[o] = (1.0f - z) * nn + z * hv[o];
        h_out[(size_t)n * H + o] = ho[o];
    }
    if (hbf) {
        unsigned w0 = pack2(ho[0], ho[1]), w1 = pack2(ho[2], ho[3]), w2 = pack2(ho[4], ho[5]),
                 w3 = pack2(ho[6], ho[7]), w4 = pack2(ho[8], ho[9]);
        unsigned char* ob = hbf + (size_t)n * 20;
        *(uint4u*)ob = (uint4u){w0, w1, w2, w3};
        *(unsigned int*)(ob + 16) = w4;
    }
}

static inline size_t align256(size_t x) { return (x + 255) & ~(size_t)255; }

extern "C" void kernel_launch(void* const* d_in, const int* in_sizes, int n_in,
                              void* d_out, int out_size, void* d_ws, size_t ws_size,
                              hipStream_t stream) {
    const float* node_features = (const float*)d_in[0];
    const int*   edges         = (const int*)d_in[1];
    const float* W1 = (const float*)d_in[2];
    const float* b1 = (const float*)d_in[3];
    const float* W2 = (const float*)d_in[4];
    const float* b2 = (const float*)d_in[5];
    const float* W3 = (const float*)d_in[6];
    const float* b3 = (const float*)d_in[7];
    const float* W_ih = (const float*)d_in[8];
    const float* b_ih = (const float*)d_in[9];
    const float* W_hh = (const float*)d_in[10];
    const float* b_hh = (const float*)d_in[11];

    char* ws = (char*)d_ws;
    size_t off = 0;
    float* a = (float*)(ws + off);          off = align256(off + (size_t)N_NODES * H * sizeof(float));
    long long* pairsLL = (long long*)(ws + off);  off = align256(off + (size_t)E2 * sizeof(long long));
    // region C: counting-sort scratch is dead before hbf/wbuf are written
    size_t coff = off;
    int* cntmat = (int*)(ws + coff);              size_t c1 = align256(coff + (size_t)NBKT * NCHUNK * sizeof(int));
    int* offmat = (int*)(ws + c1);                size_t c2 = align256(c1 + (size_t)NBKT * NCHUNK * sizeof(int));
    int* totals = (int*)(ws + c2);                size_t c3 = align256(c2 + (size_t)NBKT * sizeof(int));
    int* bases  = (int*)(ws + c3);                size_t c4 = align256(c3 + (size_t)NBKT * sizeof(int));
    unsigned char* hbf = (unsigned char*)(ws + coff);  size_t h1 = align256(coff + (size_t)N_NODES * 20);
    unsigned char* wbuf = (unsigned char*)(ws + h1);   size_t h2 = align256(h1 + 14400);
    size_t need = (c4 > h2) ? c4 : h2;
    const bool use_fast = (ws_size >= need);

    float* hbuf = (float*)d_out;
    const int edge_blocks = E2 / 256;                 // 12500
    const int node_blocks = (N_NODES + 255) / 256;    // 391

    if (use_fast) {
        // NOTE: totals/bases are consumed by bucketsort BEFORE hbf/wbuf
        // overwrite region C (stream-ordered).
        binhist_kernel<<<NCHUNK, 256, 0, stream>>>(edges, cntmat);
        bucketscan_kernel<<<NBKT, 256, 0, stream>>>(cntmat, offmat, totals);
        basescan_kernel<<<1, 512, 0, stream>>>(totals, bases);
        binscatter_kernel<<<NCHUNK, 256, 0, stream>>>(edges, offmat, bases, pairsLL);
        bucketsort_kernel<<<NBKT, 256, 0, stream>>>(totals, bases, pairsLL);
        prep_weights_kernel<<<4, 256, 0, stream>>>(W1, b1, W2, W3, b3, wbuf);
        convert_h_kernel<<<node_blocks, 256, 0, stream>>>(node_features, hbf);
    }

    for (int it = 0; it < 3; ++it) {
        hipMemsetAsync(a, 0, (size_t)N_NODES * H * sizeof(float), stream);
        const float* hin = (it == 0) ? node_features : hbuf;
        if (use_fast) {
            edge_mlp_mfma2_kernel<<<edge_blocks, 256, 0, stream>>>(
                hbf, pairsLL, wbuf, b2, a);
        } else {
            edge_mlp_kernel<<<edge_blocks, 256, 0, stream>>>(
                hin, edges, W1, b1, W2, b2, W3, b3, a);
        }
        gru_kernel<<<node_blocks, 256, 0, stream>>>(
            hin, a, hbuf, W_ih, b_ih, W_hh, b_hh, use_fast ? hbf : (unsigned char*)nullptr);
    }
}

// Round 10
// 405.808 us; speedup vs baseline: 13.2566x; 1.0280x over previous
//
#include <hip/hip_runtime.h>
#include <hip/hip_bf16.h>
#include <math.h>

#define N_NODES 100000
#define N_EDGES 1600000
#define H 10
#define HID 64
#define E2 (2 * N_EDGES)          // 3,200,000

// two-level counting sort: 391 buckets of 256 nodes (b = src >> 8)
#define NBKT 391                  // ceil(100000/256)
#define NCHUNK 256
#define CHUNK (E2 / NCHUNK)       // 12500 exact
#define BKT_CAP 12032             // LDS staging cap (mean 8192, sigma ~90)

typedef __attribute__((ext_vector_type(8))) short short8;
typedef __attribute__((ext_vector_type(4))) float f32x4;
typedef __attribute__((ext_vector_type(2))) unsigned int uint2v;
typedef __attribute__((ext_vector_type(4))) unsigned int uint4v;
typedef unsigned int uint4u __attribute__((ext_vector_type(4), aligned(4)));

#define MFMA16(a, b, c) __builtin_amdgcn_mfma_f32_16x16x32_bf16((a), (b), (c), 0, 0, 0)

__device__ __forceinline__ float sigmoidf_(float x) {
    return 1.0f / (1.0f + __expf(-x));
}
__device__ __forceinline__ float tanhf_(float x) {
    float ax = fabsf(x);
    float t = 1.0f - 2.0f / (__expf(2.0f * ax) + 1.0f);
    return copysignf(t, x);
}
__device__ __forceinline__ unsigned short f2bf(float f) {
    union { __hip_bfloat16 b; unsigned short u; } cv;
    cv.b = __float2bfloat16(f);   // RNE, NaN-safe (cold paths only)
    return cv.u;
}
__device__ __forceinline__ unsigned pack2(float lo, float hi) {
    return (unsigned)f2bf(lo) | ((unsigned)f2bf(hi) << 16);
}
// hot-path packed cvt: 1 inst, RNE; inputs guaranteed finite (post-relu)
__device__ __forceinline__ unsigned cvt_pk(float lo, float hi) {
    unsigned r;
    asm("v_cvt_pk_bf16_f32 %0, %1, %2" : "=v"(r) : "v"(lo), "v"(hi));
    return r;
}
__device__ __forceinline__ int2 ll2int2(long long v) {
    int2 r;
    r.x = (int)(v & 0xffffffffll);   // src in low word
    r.y = (int)(v >> 32);            // dst in high word
    return r;
}

// ---------------- CSR build: deterministic counting sort --------------------

__global__ __launch_bounds__(256) void binhist_kernel(
    const int* __restrict__ edges, int* __restrict__ cntmat)
{
    __shared__ int cnt[NBKT];
    for (int i = threadIdx.x; i < NBKT; i += 256) cnt[i] = 0;
    __syncthreads();
    const int c = blockIdx.x, lo = c * CHUNK;
    for (int i = threadIdx.x; i < CHUNK; i += 256) {
        int s = edges[lo + i];
        atomicAdd(&cnt[s >> 8], 1);
    }
    __syncthreads();
    for (int i = threadIdx.x; i < NBKT; i += 256) cntmat[i * NCHUNK + c] = cnt[i];
}

__global__ __launch_bounds__(256) void bucketscan_kernel(
    const int* __restrict__ cntmat, int* __restrict__ offmat, int* __restrict__ totals)
{
    __shared__ int s[NCHUNK];
    const int b = blockIdx.x, tid = threadIdx.x;
    int v = cntmat[b * NCHUNK + tid];
    s[tid] = v;
    __syncthreads();
    for (int off = 1; off < 256; off <<= 1) {
        int t = (tid >= off) ? s[tid - off] : 0;
        __syncthreads();
        s[tid] += t;
        __syncthreads();
    }
    offmat[b * NCHUNK + tid] = s[tid] - v;
    if (tid == 255) totals[b] = s[255];
}

__global__ __launch_bounds__(512) void basescan_kernel(
    const int* __restrict__ totals, int* __restrict__ bases)
{
    __shared__ int s[512];
    const int tid = threadIdx.x;
    int v = (tid < NBKT) ? totals[tid] : 0;
    s[tid] = v;
    __syncthreads();
    for (int off = 1; off < 512; off <<= 1) {
        int t = (tid >= off) ? s[tid - off] : 0;
        __syncthreads();
        s[tid] += t;
        __syncthreads();
    }
    if (tid < NBKT) bases[tid] = s[tid] - v;
}

__global__ __launch_bounds__(256) void binscatter_kernel(
    const int* __restrict__ edges, const int* __restrict__ offmat,
    const int* __restrict__ bases, long long* __restrict__ pairsLL)
{
    __shared__ int cursor[NBKT];
    const int c = blockIdx.x, lo = c * CHUNK;
    for (int i = threadIdx.x; i < NBKT; i += 256)
        cursor[i] = bases[i] + offmat[i * NCHUNK + c];
    __syncthreads();
    for (int i = threadIdx.x; i < CHUNK; i += 256) {
        int e = lo + i;
        int s = edges[e];
        int d = (e < N_EDGES) ? edges[e + N_EDGES] : edges[e - N_EDGES];
        int pos = atomicAdd(&cursor[s >> 8], 1);   // LDS atomic
        pairsLL[pos] = (long long)(unsigned)s | ((long long)d << 32);
    }
}

__global__ __launch_bounds__(256) void bucketsort_kernel(
    const int* __restrict__ totals, const int* __restrict__ bases,
    long long* __restrict__ pairsLL)
{
    __shared__ long long sE[BKT_CAP];
    __shared__ int cnt[256];
    __shared__ int cur[256];
    const int b = blockIdx.x, tid = threadIdx.x;
    const int tot = totals[b], base = bases[b];
    if (tot > BKT_CAP) return;   // unsorted bucket is still CORRECT (order-agnostic reduce)
    for (int i = tid; i < tot; i += 256) sE[i] = pairsLL[base + i];
    cnt[tid] = 0;
    __syncthreads();
    for (int i = tid; i < tot; i += 256)
        atomicAdd(&cnt[((int)sE[i]) & 255], 1);
    __syncthreads();
    int v = cnt[tid];
    cur[tid] = v;
    __syncthreads();
    for (int off = 1; off < 256; off <<= 1) {
        int t = (tid >= off) ? cur[tid - off] : 0;
        __syncthreads();
        cur[tid] += t;
        __syncthreads();
    }
    cnt[tid] = cur[tid] - v;
    __syncthreads();
    for (int i = tid; i < tot; i += 256) {
        long long e = sE[i];
        int r = atomicAdd(&cnt[((int)e) & 255], 1);
        pairsLL[base + r] = e;
    }
}

// ---------------- one-time precompute ---------------------------------------

#define WBUF_B3_OFF 14336   // 14*64*16

__global__ __launch_bounds__(256) void prep_weights_kernel(
    const float* __restrict__ W1, const float* __restrict__ b1,
    const float* __restrict__ W2,
    const float* __restrict__ W3, const float* __restrict__ b3,
    unsigned char* __restrict__ wbuf)
{
    int idx = blockIdx.x * 256 + threadIdx.x;   // grid=4 -> 1024 threads
    if (idx < 896) {
        int f = idx >> 6, l = idx & 63, l15 = l & 15, lo4 = l >> 4;
        unsigned short v[8];
        #pragma unroll
        for (int i = 0; i < 8; ++i) {
            int kk = lo4 * 8 + i;
            float val = 0.0f;
            if (f < 4) {
                int row = f * 16 + l15;
                val = (kk < 20) ? W1[row * 20 + kk] : (kk == 20 ? b1[row] : 0.0f);
            } else if (f < 12) {
                int g = f - 4, nt = g >> 1, ks = g & 1;
                val = W2[(nt * 16 + l15) * 64 + ks * 32 + kk];
            } else {
                int ks = f - 12;
                val = (l15 < 10) ? W3[l15 * 64 + ks * 32 + kk] : 0.0f;
            }
            v[i] = f2bf(val);
        }
        uint4v pk = { (unsigned)v[0] | ((unsigned)v[1] << 16),
                      (unsigned)v[2] | ((unsigned)v[3] << 16),
                      (unsigned)v[4] | ((unsigned)v[5] << 16),
                      (unsigned)v[6] | ((unsigned)v[7] << 16) };
        *(uint4v*)(wbuf + (size_t)idx * 16) = pk;
    } else if (idx < 896 + 16) {
        int o = idx - 896;
        *(float*)(wbuf + WBUF_B3_OFF + o * 4) = (o < 10) ? b3[o] : 0.0f;
    }
}

__global__ __launch_bounds__(256) void convert_h_kernel(
    const float* __restrict__ h, unsigned char* __restrict__ hbf)
{
    int n = blockIdx.x * 256 + threadIdx.x;
    if (n >= N_NODES) return;
    const float* r = h + (size_t)n * 10;
    unsigned w0 = pack2(r[0], r[1]), w1 = pack2(r[2], r[3]), w2 = pack2(r[4], r[5]),
             w3 = pack2(r[6], r[7]), w4 = pack2(r[8], r[9]);
    unsigned char* o = hbf + (size_t)n * 20;
    *(uint4u*)o = (uint4u){w0, w1, w2, w3};
    *(unsigned int*)(o + 16) = w4;
}

// ---------------- MFMA edge MLP ---------------------------------------------
// 256 threads = 4 waves; block handles 256 src-sorted edges. Wave w owns LDS
// rows [w*64, w*64+64) exclusively through gather + all 3 GEMMs -> NO barriers
// until the cross-wave segment reduction (2 barriers total).
// X rows 128B, T2 XOR swizzle: 16B slot j of row r lives at j^(r&7).
// Heads are block-local AND runs split at 16 rows (bounded divergence).

__global__ __launch_bounds__(256) void edge_mlp_mfma2_kernel(
    const unsigned char* __restrict__ hbf,   // [N][20B] bf16
    const long long* __restrict__ pairsLL,
    const unsigned char* __restrict__ wbuf,
    const float* __restrict__ b2,
    float* __restrict__ a)
{
    __shared__ __align__(16) unsigned char sX[256 * 128];
    __shared__ unsigned long long smask[4];
    __shared__ int sheadpos[256];
    __shared__ int sheadnode[256];

    char* sXp = (char*)sX;
    const int t = threadIdx.x;
    const int w = t >> 6, l = t & 63, l15 = l & 15, lo4 = l >> 4;
    const int mbase = w * 64;

    short8 W1f[4], W2f[4][2], W3f[2];
    #pragma unroll
    for (int nt = 0; nt < 4; ++nt)
        W1f[nt] = *(const short8*)(wbuf + ((nt * 64 + l) << 4));
    #pragma unroll
    for (int nt = 0; nt < 4; ++nt)
        #pragma unroll
        for (int ks = 0; ks < 2; ++ks)
            W2f[nt][ks] = *(const short8*)(wbuf + (((4 + nt * 2 + ks) * 64 + l) << 4));
    #pragma unroll
    for (int ks = 0; ks < 2; ++ks)
        W3f[ks] = *(const short8*)(wbuf + (((12 + ks) * 64 + l) << 4));
    const float* b3p = (const float*)(wbuf + WBUF_B3_OFF);

    // ---- gather (pairs: plain loads -> L3 serves iters 2,3)
    const int k = blockIdx.x * 256 + t;
    const int2 p = ll2int2(pairsLL[k]);
    const int2 pm = ll2int2(pairsLL[(k > 0) ? (k - 1) : 0]);
    // heads: block-local + split runs at 16 rows
    const bool head = (t == 0) || ((t & 15) == 0) || (pm.x != p.x);

    const unsigned char* sp = hbf + (size_t)p.x * 20;
    const unsigned char* dp = hbf + (size_t)p.y * 20;
    uint4u s4 = *(const uint4u*)sp;
    unsigned int st = *(const unsigned int*)(sp + 16);
    uint4u d4 = *(const uint4u*)dp;
    unsigned int dt = *(const unsigned int*)(dp + 16);

    {
        char* row = sXp + (t << 7);
        const int sw = (t & 7) << 4;
        *(uint4v*)(row + (0  ^ sw)) = (uint4v){s4.x, s4.y, s4.z, s4.w};
        *(uint4v*)(row + (16 ^ sw)) = (uint4v){st, d4.x, d4.y, d4.z};
        *(uint4v*)(row + (32 ^ sw)) = (uint4v){d4.w, dt, 0x00003F80u, 0u};
        *(uint4v*)(row + (48 ^ sw)) = (uint4v){0u, 0u, 0u, 0u};
    }
    // no barrier: wave reads only its own 64 rows (intra-wave LDS ordering)

    const int srow = (l15 & 7) << 4;

    // ---- GEMM1: K=32; bias embedded in W1 col 20
    #pragma unroll
    for (int mt = 0; mt < 4; ++mt) {
        const int rb = (mbase + mt * 16 + l15) << 7;
        short8 Bf = *(const short8*)(sXp + rb + ((lo4 << 4) ^ srow));
        #pragma unroll
        for (int nt = 0; nt < 4; ++nt) {
            f32x4 acc = {0.0f, 0.0f, 0.0f, 0.0f};
            acc = MFMA16(W1f[nt], Bf, acc);
            acc[0] = fmaxf(acc[0], 0.0f); acc[1] = fmaxf(acc[1], 0.0f);
            acc[2] = fmaxf(acc[2], 0.0f); acc[3] = fmaxf(acc[3], 0.0f);
            uint2v pk = { cvt_pk(acc[0], acc[1]), cvt_pk(acc[2], acc[3]) };
            const int jy = (nt * 2 + (lo4 >> 1)) << 4;
            *(uint2v*)(sXp + rb + (jy ^ srow) + ((lo4 & 1) << 3)) = pk;
        }
    }

    // ---- GEMM2: K=64, bias b2
    #pragma unroll
    for (int mt = 0; mt < 4; ++mt) {
        const int rb = (mbase + mt * 16 + l15) << 7;
        short8 B0 = *(const short8*)(sXp + rb + ((lo4 << 4) ^ srow));
        short8 B1 = *(const short8*)(sXp + rb + (((4 + lo4) << 4) ^ srow));
        #pragma unroll
        for (int nt = 0; nt < 4; ++nt) {
            f32x4 acc = *(const f32x4*)(b2 + nt * 16 + lo4 * 4);
            acc = MFMA16(W2f[nt][0], B0, acc);
            acc = MFMA16(W2f[nt][1], B1, acc);
            acc[0] = fmaxf(acc[0], 0.0f); acc[1] = fmaxf(acc[1], 0.0f);
            acc[2] = fmaxf(acc[2], 0.0f); acc[3] = fmaxf(acc[3], 0.0f);
            uint2v pk = { cvt_pk(acc[0], acc[1]), cvt_pk(acc[2], acc[3]) };
            const int jy = (nt * 2 + (lo4 >> 1)) << 4;
            *(uint2v*)(sXp + rb + (jy ^ srow) + ((lo4 & 1) << 3)) = pk;
        }
    }

    // ---- GEMM3: 16 out-feats (10 valid), K=64; f32 out to slots 0-3
    #pragma unroll
    for (int mt = 0; mt < 4; ++mt) {
        const int rb = (mbase + mt * 16 + l15) << 7;
        short8 B0 = *(const short8*)(sXp + rb + ((lo4 << 4) ^ srow));
        short8 B1 = *(const short8*)(sXp + rb + (((4 + lo4) << 4) ^ srow));
        f32x4 acc = *(const f32x4*)(b3p + lo4 * 4);
        acc = MFMA16(W3f[0], B0, acc);
        acc = MFMA16(W3f[1], B1, acc);
        *(f32x4*)(sXp + rb + ((lo4 << 4) ^ srow)) = acc;
    }

    // ---- segment list via ballot
    unsigned long long m = __ballot(head);
    if ((t & 63) == 0) smask[w] = m;
    __syncthreads();   // A: out rows + smask visible

    int base = 0, nseg = 0;
    #pragma unroll
    for (int j = 0; j < 4; ++j) {
        int c = __popcll(smask[j]);
        if (j < w) base += c;
        nseg += c;
    }
    if (head) {
        int rank = base + __popcll(m & ((1ull << (t & 63)) - 1ull));
        sheadpos[rank] = t;
        sheadnode[rank] = p.x;
    }
    __syncthreads();   // B: head list visible

    // ---- one thread per (segment, feature): sum run (<=16), single atomic
    const int total = nseg * 10;
    for (int q = t; q < total; q += 256) {
        int seg = q / 10;
        int o = q - seg * 10;
        int r0 = sheadpos[seg];
        int r1 = (seg + 1 < nseg) ? sheadpos[seg + 1] : 256;
        const int obase = ((o >> 2) << 4) + ((o & 3) << 2);
        float acc = 0.0f;
        for (int r = r0; r < r1; ++r)
            acc += *(const float*)(sXp + (r << 7) + (obase ^ ((r & 7) << 4)));
        atomicAdd(&a[(size_t)sheadnode[seg] * H + o], acc);
    }
}

// ---------------- fallback VALU edge kernel (no workspace) ------------------

__global__ __launch_bounds__(256) void edge_mlp_kernel(
    const float* __restrict__ h,
    const int*   __restrict__ edges,
    const float* __restrict__ W1, const float* __restrict__ b1,
    const float* __restrict__ W2, const float* __restrict__ b2,
    const float* __restrict__ W3, const float* __restrict__ b3,
    float* __restrict__ a)
{
    __shared__ float sW1T[2 * H * HID];
    __shared__ float sb1[HID];
    __shared__ float sW2[HID * HID];
    __shared__ float sb2[HID];
    __shared__ float sW3T[HID * H];
    __shared__ float sb3[H];
    for (int i = threadIdx.x; i < 2 * H * HID; i += blockDim.x) {
        int kk = i >> 6, j = i & 63;
        sW1T[i] = W1[j * (2 * H) + kk];
    }
    for (int i = threadIdx.x; i < HID * HID; i += blockDim.x) sW2[i] = W2[i];
    for (int i = threadIdx.x; i < HID * H; i += blockDim.x) {
        int j = i / H, o = i - j * H;
        sW3T[i] = W3[o * HID + j];
    }
    if (threadIdx.x < HID) { sb1[threadIdx.x] = b1[threadIdx.x]; sb2[threadIdx.x] = b2[threadIdx.x]; }
    if (threadIdx.x < H)   { sb3[threadIdx.x] = b3[threadIdx.x]; }
    __syncthreads();
    int e = blockIdx.x * blockDim.x + threadIdx.x;
    if (e >= E2) return;
    int s = edges[e];
    int d = (e < N_EDGES) ? edges[N_EDGES + e] : edges[e - N_EDGES];
    const float* hs = h + (size_t)s * H;
    const float* hd = h + (size_t)d * H;
    float m1[HID];
    #pragma unroll
    for (int j = 0; j < HID; ++j) m1[j] = sb1[j];
    for (int kk = 0; kk < H; ++kk) {
        float xs = hs[kk], xd = hd[kk];
        const float* w_s = &sW1T[kk * HID];
        const float* w_d = &sW1T[(H + kk) * HID];
        #pragma unroll
        for (int j = 0; j < HID; ++j) {
            m1[j] = fmaf(w_s[j], xs, m1[j]);
            m1[j] = fmaf(w_d[j], xd, m1[j]);
        }
    }
    #pragma unroll
    for (int j = 0; j < HID; ++j) m1[j] = fmaxf(m1[j], 0.0f);
    float out[H];
    #pragma unroll
    for (int o = 0; o < H; ++o) out[o] = sb3[o];
    for (int j = 0; j < HID; ++j) {
        float acc = sb2[j];
        const float* wv = &sW2[j * HID];
        #pragma unroll
        for (int kk = 0; kk < HID; ++kk) acc = fmaf(wv[kk], m1[kk], acc);
        acc = fmaxf(acc, 0.0f);
        const float* w3 = &sW3T[j * H];
        #pragma unroll
        for (int o = 0; o < H; ++o) out[o] = fmaf(w3[o], acc, out[o]);
    }
    float* as = a + (size_t)s * H;
    #pragma unroll
    for (int o = 0; o < H; ++o) atomicAdd(&as[o], out[o]);
}

// ---------------- GRU (+ bf16 h epilogue + a re-zero) -----------------------

__global__ __launch_bounds__(256) void gru_kernel(
    const float* __restrict__ h_in,
    float* __restrict__ a,               // read, then zeroed for next iter
    float* __restrict__ h_out,
    const float* __restrict__ W_ih, const float* __restrict__ b_ih,
    const float* __restrict__ W_hh, const float* __restrict__ b_hh,
    unsigned char* __restrict__ hbf)
{
    __shared__ float sWih[3 * H * H];
    __shared__ float sWhh[3 * H * H];
    __shared__ float sbih[3 * H];
    __shared__ float sbhh[3 * H];
    for (int i = threadIdx.x; i < 3 * H * H; i += blockDim.x) { sWih[i] = W_ih[i]; sWhh[i] = W_hh[i]; }
    if (threadIdx.x < 3 * H) { sbih[threadIdx.x] = b_ih[threadIdx.x]; sbhh[threadIdx.x] = b_hh[threadIdx.x]; }
    __syncthreads();

    int n = blockIdx.x * blockDim.x + threadIdx.x;
    if (n >= N_NODES) return;

    float av[H], hv[H];
    #pragma unroll
    for (int kk = 0; kk < H; ++kk) { av[kk] = a[(size_t)n * H + kk]; hv[kk] = h_in[(size_t)n * H + kk]; }
    #pragma unroll
    for (int kk = 0; kk < H; ++kk) a[(size_t)n * H + kk] = 0.0f;   // re-zero for next iter

    float gi[3 * H], gh[3 * H];
    #pragma unroll
    for (int g = 0; g < 3 * H; ++g) {
        float ai = sbih[g], hh = sbhh[g];
        const float* wi = &sWih[g * H];
        const float* wh = &sWhh[g * H];
        #pragma unroll
        for (int kk = 0; kk < H; ++kk) {
            ai = fmaf(wi[kk], av[kk], ai);
            hh = fmaf(wh[kk], hv[kk], hh);
        }
        gi[g] = ai; gh[g] = hh;
    }

    float ho[H];
    #pragma unroll
    for (int o = 0; o < H; ++o) {
        float r = sigmoidf_(gi[o] + gh[o]);
        float z = sigmoidf_(gi[H + o] + gh[H + o]);
        float nn = tanhf_(gi[2 * H + o] + r * gh[2 * H + o]);
        ho[o] = (1.0f - z) * nn + z * hv[o];
        h_out[(size_t)n * H + o] = ho[o];
    }
    if (hbf) {
        unsigned w0 = pack2(ho[0], ho[1]), w1 = pack2(ho[2], ho[3]), w2 = pack2(ho[4], ho[5]),
                 w3 = pack2(ho[6], ho[7]), w4 = pack2(ho[8], ho[9]);
        unsigned char* ob = hbf + (size_t)n * 20;
        *(uint4u*)ob = (uint4u){w0, w1, w2, w3};
        *(unsigned int*)(ob + 16) = w4;
    }
}

static inline size_t align256(size_t x) { return (x + 255) & ~(size_t)255; }

extern "C" void kernel_launch(void* const* d_in, const int* in_sizes, int n_in,
                              void* d_out, int out_size, void* d_ws, size_t ws_size,
                              hipStream_t stream) {
    const float* node_features = (const float*)d_in[0];
    const int*   edges         = (const int*)d_in[1];
    const float* W1 = (const float*)d_in[2];
    const float* b1 = (const float*)d_in[3];
    const float* W2 = (const float*)d_in[4];
    const float* b2 = (const float*)d_in[5];
    const float* W3 = (const float*)d_in[6];
    const float* b3 = (const float*)d_in[7];
    const float* W_ih = (const float*)d_in[8];
    const float* b_ih = (const float*)d_in[9];
    const float* W_hh = (const float*)d_in[10];
    const float* b_hh = (const float*)d_in[11];

    char* ws = (char*)d_ws;
    size_t off = 0;
    float* a = (float*)(ws + off);          off = align256(off + (size_t)N_NODES * H * sizeof(float));
    long long* pairsLL = (long long*)(ws + off);  off = align256(off + (size_t)E2 * sizeof(long long));
    size_t coff = off;
    int* cntmat = (int*)(ws + coff);              size_t c1 = align256(coff + (size_t)NBKT * NCHUNK * sizeof(int));
    int* offmat = (int*)(ws + c1);                size_t c2 = align256(c1 + (size_t)NBKT * NCHUNK * sizeof(int));
    int* totals = (int*)(ws + c2);                size_t c3 = align256(c2 + (size_t)NBKT * sizeof(int));
    int* bases  = (int*)(ws + c3);                size_t c4 = align256(c3 + (size_t)NBKT * sizeof(int));
    unsigned char* hbf = (unsigned char*)(ws + coff);  size_t h1 = align256(coff + (size_t)N_NODES * 20);
    unsigned char* wbuf = (unsigned char*)(ws + h1);   size_t h2 = align256(h1 + 14400);
    size_t need = (c4 > h2) ? c4 : h2;
    const bool use_fast = (ws_size >= need);

    float* hbuf = (float*)d_out;
    const int edge_blocks = E2 / 256;                 // 12500
    const int node_blocks = (N_NODES + 255) / 256;    // 391

    if (use_fast) {
        binhist_kernel<<<NCHUNK, 256, 0, stream>>>(edges, cntmat);
        bucketscan_kernel<<<NBKT, 256, 0, stream>>>(cntmat, offmat, totals);
        basescan_kernel<<<1, 512, 0, stream>>>(totals, bases);
        binscatter_kernel<<<NCHUNK, 256, 0, stream>>>(edges, offmat, bases, pairsLL);
        bucketsort_kernel<<<NBKT, 256, 0, stream>>>(totals, bases, pairsLL);
        prep_weights_kernel<<<4, 256, 0, stream>>>(W1, b1, W2, W3, b3, wbuf);
        convert_h_kernel<<<node_blocks, 256, 0, stream>>>(node_features, hbf);
    }

    // one memset clears the 0xAA poison; gru re-zeros `a` each iteration
    hipMemsetAsync(a, 0, (size_t)N_NODES * H * sizeof(float), stream);

    for (int it = 0; it < 3; ++it) {
        const float* hin = (it == 0) ? node_features : hbuf;
        if (use_fast) {
            edge_mlp_mfma2_kernel<<<edge_blocks, 256, 0, stream>>>(
                hbf, pairsLL, wbuf, b2, a);
        } else {
            edge_mlp_kernel<<<edge_blocks, 256, 0, stream>>>(
                hin, edges, W1, b1, W2, b2, W3, b3, a);
        }
        gru_kernel<<<node_blocks, 256, 0, stream>>>(
            hin, a, hbuf, W_ih, b_ih, W_hh, b_hh, use_fast ? hbf : (unsigned char*)nullptr);
    }
}

// Round 12
// 358.165 us; speedup vs baseline: 15.0200x; 1.1330x over previous
//
#include <hip/hip_runtime.h>
#include <hip/hip_bf16.h>
#include <math.h>

#define N_NODES 100000
#define N_EDGES 1600000
#define H 10
#define HID 64
#define E2 (2 * N_EDGES)          // 3,200,000

// two-level counting sort: 391 buckets of 256 nodes (b = src >> 8)
#define NBKT 391                  // ceil(100000/256)
#define NCHUNK 256
#define CHUNK (E2 / NCHUNK)       // 12500 exact
#define BKT_CAP 12032             // LDS staging cap (mean 8192, sigma ~90)

typedef __attribute__((ext_vector_type(8))) short short8;
typedef __attribute__((ext_vector_type(4))) float f32x4;
typedef __attribute__((ext_vector_type(2))) unsigned int uint2v;
typedef __attribute__((ext_vector_type(4))) unsigned int uint4v;
typedef unsigned int uint4u __attribute__((ext_vector_type(4), aligned(4)));

#define MFMA16(a, b, c) __builtin_amdgcn_mfma_f32_16x16x32_bf16((a), (b), (c), 0, 0, 0)

__device__ __forceinline__ float sigmoidf_(float x) {
    return 1.0f / (1.0f + __expf(-x));
}
__device__ __forceinline__ float tanhf_(float x) {
    float ax = fabsf(x);
    float t = 1.0f - 2.0f / (__expf(2.0f * ax) + 1.0f);
    return copysignf(t, x);
}
__device__ __forceinline__ unsigned short f2bf(float f) {
    union { __hip_bfloat16 b; unsigned short u; } cv;
    cv.b = __float2bfloat16(f);   // RNE, NaN-safe (cold paths only)
    return cv.u;
}
__device__ __forceinline__ unsigned pack2(float lo, float hi) {
    return (unsigned)f2bf(lo) | ((unsigned)f2bf(hi) << 16);
}
// hot-path packed cvt: 1 inst, RNE; inputs guaranteed finite (post-relu)
__device__ __forceinline__ unsigned cvt_pk(float lo, float hi) {
    unsigned r;
    asm("v_cvt_pk_bf16_f32 %0, %1, %2" : "=v"(r) : "v"(lo), "v"(hi));
    return r;
}
__device__ __forceinline__ int2 ll2int2(long long v) {
    int2 r;
    r.x = (int)(v & 0xffffffffll);   // src in low word
    r.y = (int)(v >> 32);            // dst in high word
    return r;
}

// ---------------- CSR build: deterministic counting sort --------------------

__global__ __launch_bounds__(256) void binhist_kernel(
    const int* __restrict__ edges, int* __restrict__ cntmat)
{
    __shared__ int cnt[NBKT];
    for (int i = threadIdx.x; i < NBKT; i += 256) cnt[i] = 0;
    __syncthreads();
    const int c = blockIdx.x, lo = c * CHUNK;
    for (int i = threadIdx.x; i < CHUNK; i += 256) {
        int s = edges[lo + i];
        atomicAdd(&cnt[s >> 8], 1);
    }
    __syncthreads();
    for (int i = threadIdx.x; i < NBKT; i += 256) cntmat[i * NCHUNK + c] = cnt[i];
}

__global__ __launch_bounds__(256) void bucketscan_kernel(
    const int* __restrict__ cntmat, int* __restrict__ offmat, int* __restrict__ totals)
{
    __shared__ int s[NCHUNK];
    const int b = blockIdx.x, tid = threadIdx.x;
    int v = cntmat[b * NCHUNK + tid];
    s[tid] = v;
    __syncthreads();
    for (int off = 1; off < 256; off <<= 1) {
        int t = (tid >= off) ? s[tid - off] : 0;
        __syncthreads();
        s[tid] += t;
        __syncthreads();
    }
    offmat[b * NCHUNK + tid] = s[tid] - v;
    if (tid == 255) totals[b] = s[255];
}

__global__ __launch_bounds__(512) void basescan_kernel(
    const int* __restrict__ totals, int* __restrict__ bases)
{
    __shared__ int s[512];
    const int tid = threadIdx.x;
    int v = (tid < NBKT) ? totals[tid] : 0;
    s[tid] = v;
    __syncthreads();
    for (int off = 1; off < 512; off <<= 1) {
        int t = (tid >= off) ? s[tid - off] : 0;
        __syncthreads();
        s[tid] += t;
        __syncthreads();
    }
    if (tid < NBKT) bases[tid] = s[tid] - v;
}

__global__ __launch_bounds__(256) void binscatter_kernel(
    const int* __restrict__ edges, const int* __restrict__ offmat,
    const int* __restrict__ bases, long long* __restrict__ pairsLL)
{
    __shared__ int cursor[NBKT];
    const int c = blockIdx.x, lo = c * CHUNK;
    for (int i = threadIdx.x; i < NBKT; i += 256)
        cursor[i] = bases[i] + offmat[i * NCHUNK + c];
    __syncthreads();
    for (int i = threadIdx.x; i < CHUNK; i += 256) {
        int e = lo + i;
        int s = edges[e];
        int d = (e < N_EDGES) ? edges[e + N_EDGES] : edges[e - N_EDGES];
        int pos = atomicAdd(&cursor[s >> 8], 1);   // LDS atomic
        pairsLL[pos] = (long long)(unsigned)s | ((long long)d << 32);
    }
}

__global__ __launch_bounds__(256) void bucketsort_kernel(
    const int* __restrict__ totals, const int* __restrict__ bases,
    long long* __restrict__ pairsLL)
{
    __shared__ long long sE[BKT_CAP];
    __shared__ int cnt[256];
    __shared__ int cur[256];
    const int b = blockIdx.x, tid = threadIdx.x;
    const int tot = totals[b], base = bases[b];
    if (tot > BKT_CAP) return;   // unsorted bucket still CORRECT (order-agnostic reduce)
    for (int i = tid; i < tot; i += 256) sE[i] = pairsLL[base + i];
    cnt[tid] = 0;
    __syncthreads();
    for (int i = tid; i < tot; i += 256)
        atomicAdd(&cnt[((int)sE[i]) & 255], 1);
    __syncthreads();
    int v = cnt[tid];
    cur[tid] = v;
    __syncthreads();
    for (int off = 1; off < 256; off <<= 1) {
        int t = (tid >= off) ? cur[tid - off] : 0;
        __syncthreads();
        cur[tid] += t;
        __syncthreads();
    }
    cnt[tid] = cur[tid] - v;
    __syncthreads();
    for (int i = tid; i < tot; i += 256) {
        long long e = sE[i];
        int r = atomicAdd(&cnt[((int)e) & 255], 1);
        pairsLL[base + r] = e;
    }
}

// ---------------- one-time precompute ---------------------------------------

#define WBUF_B3_OFF 14336   // 14*64*16

__global__ __launch_bounds__(256) void prep_weights_kernel(
    const float* __restrict__ W1, const float* __restrict__ b1,
    const float* __restrict__ W2,
    const float* __restrict__ W3, const float* __restrict__ b3,
    unsigned char* __restrict__ wbuf)
{
    int idx = blockIdx.x * 256 + threadIdx.x;   // grid=4 -> 1024 threads
    if (idx < 896) {
        int f = idx >> 6, l = idx & 63, l15 = l & 15, lo4 = l >> 4;
        unsigned short v[8];
        #pragma unroll
        for (int i = 0; i < 8; ++i) {
            int kk = lo4 * 8 + i;
            float val = 0.0f;
            if (f < 4) {
                int row = f * 16 + l15;
                val = (kk < 20) ? W1[row * 20 + kk] : (kk == 20 ? b1[row] : 0.0f);
            } else if (f < 12) {
                int g = f - 4, nt = g >> 1, ks = g & 1;
                val = W2[(nt * 16 + l15) * 64 + ks * 32 + kk];
            } else {
                int ks = f - 12;
                val = (l15 < 10) ? W3[l15 * 64 + ks * 32 + kk] : 0.0f;
            }
            v[i] = f2bf(val);
        }
        uint4v pk = { (unsigned)v[0] | ((unsigned)v[1] << 16),
                      (unsigned)v[2] | ((unsigned)v[3] << 16),
                      (unsigned)v[4] | ((unsigned)v[5] << 16),
                      (unsigned)v[6] | ((unsigned)v[7] << 16) };
        *(uint4v*)(wbuf + (size_t)idx * 16) = pk;
    } else if (idx < 896 + 16) {
        int o = idx - 896;
        *(float*)(wbuf + WBUF_B3_OFF + o * 4) = (o < 10) ? b3[o] : 0.0f;
    }
}

__global__ __launch_bounds__(256) void convert_h_kernel(
    const float* __restrict__ h, unsigned char* __restrict__ hbf)
{
    int n = blockIdx.x * 256 + threadIdx.x;
    if (n >= N_NODES) return;
    const float* r = h + (size_t)n * 10;
    unsigned w0 = pack2(r[0], r[1]), w1 = pack2(r[2], r[3]), w2 = pack2(r[4], r[5]),
             w3 = pack2(r[6], r[7]), w4 = pack2(r[8], r[9]);
    unsigned char* o = hbf + (size_t)n * 20;
    *(uint4u*)o = (uint4u){w0, w1, w2, w3};
    *(unsigned int*)(o + 16) = w4;
}

// ---------------- MFMA edge MLP ---------------------------------------------
// 256 threads = 4 waves; block handles 256 src-sorted edges. Wave w owns LDS
// rows [w*64, w*64+64) exclusively through gather + GEMMs + REDUCTION ->
// ZERO barriers. Segments are WAVE-local. Head list in registers via
// ballot + ds_permute. Reduction loop is WAVE-UNIFORM (all 64 lanes active
// through every __shfl — R11's divergent-tail shfl read inactive lanes).

__global__ __launch_bounds__(256) void edge_mlp_mfma2_kernel(
    const unsigned char* __restrict__ hbf,   // [N][20B] bf16
    const long long* __restrict__ pairsLL,
    const unsigned char* __restrict__ wbuf,
    const float* __restrict__ b2,
    float* __restrict__ a)
{
    __shared__ __align__(16) unsigned char sX[256 * 128];   // exactly 32 KiB

    char* sXp = (char*)sX;
    const int t = threadIdx.x;
    const int w = t >> 6, l = t & 63, l15 = l & 15, lo4 = l >> 4;
    const int mbase = w * 64;

    short8 W1f[4], W2f[4][2], W3f[2];
    #pragma unroll
    for (int nt = 0; nt < 4; ++nt)
        W1f[nt] = *(const short8*)(wbuf + ((nt * 64 + l) << 4));
    #pragma unroll
    for (int nt = 0; nt < 4; ++nt)
        #pragma unroll
        for (int ks = 0; ks < 2; ++ks)
            W2f[nt][ks] = *(const short8*)(wbuf + (((4 + nt * 2 + ks) * 64 + l) << 4));
    #pragma unroll
    for (int ks = 0; ks < 2; ++ks)
        W3f[ks] = *(const short8*)(wbuf + (((12 + ks) * 64 + l) << 4));
    // hoisted bias fragments
    f32x4 bb2[4];
    #pragma unroll
    for (int nt = 0; nt < 4; ++nt)
        bb2[nt] = *(const f32x4*)(b2 + nt * 16 + lo4 * 4);
    const f32x4 bb3 = *(const f32x4*)((const float*)(wbuf + WBUF_B3_OFF) + lo4 * 4);

    // ---- gather
    const int k = blockIdx.x * 256 + t;
    const int2 p = ll2int2(pairsLL[k]);
    const int2 pm = ll2int2(pairsLL[(k > 0) ? (k - 1) : 0]);
    // WAVE-local heads: (l&15)==0 forces a head (bounds run <=16, covers l==0)
    const bool head = ((l & 15) == 0) || (pm.x != p.x);

    const unsigned char* sp = hbf + (size_t)p.x * 20;
    const unsigned char* dp = hbf + (size_t)p.y * 20;
    uint4u s4 = *(const uint4u*)sp;
    unsigned int st = *(const unsigned int*)(sp + 16);
    uint4u d4 = *(const uint4u*)dp;
    unsigned int dt = *(const unsigned int*)(dp + 16);

    {
        char* row = sXp + (t << 7);
        const int sw = (t & 7) << 4;
        *(uint4v*)(row + (0  ^ sw)) = (uint4v){s4.x, s4.y, s4.z, s4.w};
        *(uint4v*)(row + (16 ^ sw)) = (uint4v){st, d4.x, d4.y, d4.z};
        *(uint4v*)(row + (32 ^ sw)) = (uint4v){d4.w, dt, 0x00003F80u, 0u};
        *(uint4v*)(row + (48 ^ sw)) = (uint4v){0u, 0u, 0u, 0u};
    }
    // no barrier anywhere: wave touches only its own 64 rows

    const int srow = (l15 & 7) << 4;

    // ---- GEMM1: K=32; bias embedded in W1 col 20
    #pragma unroll
    for (int mt = 0; mt < 4; ++mt) {
        const int rb = (mbase + mt * 16 + l15) << 7;
        short8 Bf = *(const short8*)(sXp + rb + ((lo4 << 4) ^ srow));
        #pragma unroll
        for (int nt = 0; nt < 4; ++nt) {
            f32x4 acc = {0.0f, 0.0f, 0.0f, 0.0f};
            acc = MFMA16(W1f[nt], Bf, acc);
            acc[0] = fmaxf(acc[0], 0.0f); acc[1] = fmaxf(acc[1], 0.0f);
            acc[2] = fmaxf(acc[2], 0.0f); acc[3] = fmaxf(acc[3], 0.0f);
            uint2v pk = { cvt_pk(acc[0], acc[1]), cvt_pk(acc[2], acc[3]) };
            const int jy = (nt * 2 + (lo4 >> 1)) << 4;
            *(uint2v*)(sXp + rb + (jy ^ srow) + ((lo4 & 1) << 3)) = pk;
        }
    }

    // ---- GEMM2: K=64, bias b2 (hoisted frags)
    #pragma unroll
    for (int mt = 0; mt < 4; ++mt) {
        const int rb = (mbase + mt * 16 + l15) << 7;
        short8 B0 = *(const short8*)(sXp + rb + ((lo4 << 4) ^ srow));
        short8 B1 = *(const short8*)(sXp + rb + (((4 + lo4) << 4) ^ srow));
        #pragma unroll
        for (int nt = 0; nt < 4; ++nt) {
            f32x4 acc = bb2[nt];
            acc = MFMA16(W2f[nt][0], B0, acc);
            acc = MFMA16(W2f[nt][1], B1, acc);
            acc[0] = fmaxf(acc[0], 0.0f); acc[1] = fmaxf(acc[1], 0.0f);
            acc[2] = fmaxf(acc[2], 0.0f); acc[3] = fmaxf(acc[3], 0.0f);
            uint2v pk = { cvt_pk(acc[0], acc[1]), cvt_pk(acc[2], acc[3]) };
            const int jy = (nt * 2 + (lo4 >> 1)) << 4;
            *(uint2v*)(sXp + rb + (jy ^ srow) + ((lo4 & 1) << 3)) = pk;
        }
    }

    // ---- GEMM3: 16 out-feats (10 valid), K=64; f32 out to slots 0-3
    #pragma unroll
    for (int mt = 0; mt < 4; ++mt) {
        const int rb = (mbase + mt * 16 + l15) << 7;
        short8 B0 = *(const short8*)(sXp + rb + ((lo4 << 4) ^ srow));
        short8 B1 = *(const short8*)(sXp + rb + (((4 + lo4) << 4) ^ srow));
        f32x4 acc = bb3;
        acc = MFMA16(W3f[0], B0, acc);
        acc = MFMA16(W3f[1], B1, acc);
        *(f32x4*)(sXp + rb + ((lo4 << 4) ^ srow)) = acc;
    }

    // ---- wave-local segmented reduction (no barriers, wave-uniform loop)
    unsigned long long m = __ballot(head);
    const int nseg = __popcll(m);                       // wave-uniform
    const int rank = __popcll(m & ((1ull << l) - 1ull));
    // push head position to lane 'rank' (heads); non-heads push to lane 63,
    // whose value is garbage only if lane 63 isn't a rank target (never read)
    const int hp = __builtin_amdgcn_ds_permute((head ? rank : 63) << 2, l);

    const int total = nseg * 10;                        // wave-uniform (>= 40)
    const int niter = (total + 63) >> 6;                // wave-uniform
    for (int it2 = 0; it2 < niter; ++it2) {
        const int q = it2 * 64 + l;
        const bool live = (q < total);
        const int qa = live ? q : (total - 1);          // clamp: keep lane active
        const int seg = qa / 10;
        const int o = qa - seg * 10;
        const int segn = (seg + 1 < nseg) ? (seg + 1) : seg;
        const int r0 = __shfl(hp, seg);                 // all 64 lanes active
        const int rn = __shfl(hp, segn);
        const int r1 = (seg + 1 < nseg) ? rn : 64;
        const int node = __shfl(p.x, r0);
        const int obase = ((o >> 2) << 4) + ((o & 3) << 2);
        float acc = 0.0f;
        for (int r = r0; r < r1; ++r) {
            int row = mbase + r;
            acc += *(const float*)(sXp + (row << 7) + (obase ^ ((row & 7) << 4)));
        }
        if (live) atomicAdd(&a[(size_t)node * H + o], acc);
    }
}

// ---------------- fallback VALU edge kernel (no workspace) ------------------

__global__ __launch_bounds__(256) void edge_mlp_kernel(
    const float* __restrict__ h,
    const int*   __restrict__ edges,
    const float* __restrict__ W1, const float* __restrict__ b1,
    const float* __restrict__ W2, const float* __restrict__ b2,
    const float* __restrict__ W3, const float* __restrict__ b3,
    float* __restrict__ a)
{
    __shared__ float sW1T[2 * H * HID];
    __shared__ float sb1[HID];
    __shared__ float sW2[HID * HID];
    __shared__ float sb2[HID];
    __shared__ float sW3T[HID * H];
    __shared__ float sb3[H];
    for (int i = threadIdx.x; i < 2 * H * HID; i += blockDim.x) {
        int kk = i >> 6, j = i & 63;
        sW1T[i] = W1[j * (2 * H) + kk];
    }
    for (int i = threadIdx.x; i < HID * HID; i += blockDim.x) sW2[i] = W2[i];
    for (int i = threadIdx.x; i < HID * H; i += blockDim.x) {
        int j = i / H, o = i - j * H;
        sW3T[i] = W3[o * HID + j];
    }
    if (threadIdx.x < HID) { sb1[threadIdx.x] = b1[threadIdx.x]; sb2[threadIdx.x] = b2[threadIdx.x]; }
    if (threadIdx.x < H)   { sb3[threadIdx.x] = b3[threadIdx.x]; }
    __syncthreads();
    int e = blockIdx.x * blockDim.x + threadIdx.x;
    if (e >= E2) return;
    int s = edges[e];
    int d = (e < N_EDGES) ? edges[N_EDGES + e] : edges[e - N_EDGES];
    const float* hs = h + (size_t)s * H;
    const float* hd = h + (size_t)d * H;
    float m1[HID];
    #pragma unroll
    for (int j = 0; j < HID; ++j) m1[j] = sb1[j];
    for (int kk = 0; kk < H; ++kk) {
        float xs = hs[kk], xd = hd[kk];
        const float* w_s = &sW1T[kk * HID];
        const float* w_d = &sW1T[(H + kk) * HID];
        #pragma unroll
        for (int j = 0; j < HID; ++j) {
            m1[j] = fmaf(w_s[j], xs, m1[j]);
            m1[j] = fmaf(w_d[j], xd, m1[j]);
        }
    }
    #pragma unroll
    for (int j = 0; j < HID; ++j) m1[j] = fmaxf(m1[j], 0.0f);
    float out[H];
    #pragma unroll
    for (int o = 0; o < H; ++o) out[o] = sb3[o];
    for (int j = 0; j < HID; ++j) {
        float acc = sb2[j];
        const float* wv = &sW2[j * HID];
        #pragma unroll
        for (int kk = 0; kk < HID; ++kk) acc = fmaf(wv[kk], m1[kk], acc);
        acc = fmaxf(acc, 0.0f);
        const float* w3 = &sW3T[j * H];
        #pragma unroll
        for (int o = 0; o < H; ++o) out[o] = fmaf(w3[o], acc, out[o]);
    }
    float* as = a + (size_t)s * H;
    #pragma unroll
    for (int o = 0; o < H; ++o) atomicAdd(&as[o], out[o]);
}

// ---------------- GRU (+ bf16 h epilogue + a re-zero) -----------------------

__global__ __launch_bounds__(256) void gru_kernel(
    const float* __restrict__ h_in,
    float* __restrict__ a,               // read, then zeroed for next iter
    float* __restrict__ h_out,
    const float* __restrict__ W_ih, const float* __restrict__ b_ih,
    const float* __restrict__ W_hh, const float* __restrict__ b_hh,
    unsigned char* __restrict__ hbf)
{
    __shared__ float sWih[3 * H * H];
    __shared__ float sWhh[3 * H * H];
    __shared__ float sbih[3 * H];
    __shared__ float sbhh[3 * H];
    for (int i = threadIdx.x; i < 3 * H * H; i += blockDim.x) { sWih[i] = W_ih[i]; sWhh[i] = W_hh[i]; }
    if (threadIdx.x < 3 * H) { sbih[threadIdx.x] = b_ih[threadIdx.x]; sbhh[threadIdx.x] = b_hh[threadIdx.x]; }
    __syncthreads();

    int n = blockIdx.x * blockDim.x + threadIdx.x;
    if (n >= N_NODES) return;

    float av[H], hv[H];
    #pragma unroll
    for (int kk = 0; kk < H; ++kk) { av[kk] = a[(size_t)n * H + kk]; hv[kk] = h_in[(size_t)n * H + kk]; }
    #pragma unroll
    for (int kk = 0; kk < H; ++kk) a[(size_t)n * H + kk] = 0.0f;   // re-zero for next iter

    float gi[3 * H], gh[3 * H];
    #pragma unroll
    for (int g = 0; g < 3 * H; ++g) {
        float ai = sbih[g], hh = sbhh[g];
        const float* wi = &sWih[g * H];
        const float* wh = &sWhh[g * H];
        #pragma unroll
        for (int kk = 0; kk < H; ++kk) {
            ai = fmaf(wi[kk], av[kk], ai);
            hh = fmaf(wh[kk], hv[kk], hh);
        }
        gi[g] = ai; gh[g] = hh;
    }

    float ho[H];
    #pragma unroll
    for (int o = 0; o < H; ++o) {
        float r = sigmoidf_(gi[o] + gh[o]);
        float z = sigmoidf_(gi[H + o] + gh[H + o]);
        float nn = tanhf_(gi[2 * H + o] + r * gh[2 * H + o]);
        ho[o] = (1.0f - z) * nn + z * hv[o];
        h_out[(size_t)n * H + o] = ho[o];
    }
    if (hbf) {
        unsigned w0 = pack2(ho[0], ho[1]), w1 = pack2(ho[2], ho[3]), w2 = pack2(ho[4], ho[5]),
                 w3 = pack2(ho[6], ho[7]), w4 = pack2(ho[8], ho[9]);
        unsigned char* ob = hbf + (size_t)n * 20;
        *(uint4u*)ob = (uint4u){w0, w1, w2, w3};
        *(unsigned int*)(ob + 16) = w4;
    }
}

static inline size_t align256(size_t x) { return (x + 255) & ~(size_t)255; }

extern "C" void kernel_launch(void* const* d_in, const int* in_sizes, int n_in,
                              void* d_out, int out_size, void* d_ws, size_t ws_size,
                              hipStream_t stream) {
    const float* node_features = (const float*)d_in[0];
    const int*   edges         = (const int*)d_in[1];
    const float* W1 = (const float*)d_in[2];
    const float* b1 = (const float*)d_in[3];
    const float* W2 = (const float*)d_in[4];
    const float* b2 = (const float*)d_in[5];
    const float* W3 = (const float*)d_in[6];
    const float* b3 = (const float*)d_in[7];
    const float* W_ih = (const float*)d_in[8];
    const float* b_ih = (const float*)d_in[9];
    const float* W_hh = (const float*)d_in[10];
    const float* b_hh = (const float*)d_in[11];

    char* ws = (char*)d_ws;
    size_t off = 0;
    float* a = (float*)(ws + off);          off = align256(off + (size_t)N_NODES * H * sizeof(float));
    long long* pairsLL = (long long*)(ws + off);  off = align256(off + (size_t)E2 * sizeof(long long));
    size_t coff = off;
    int* cntmat = (int*)(ws + coff);              size_t c1 = align256(coff + (size_t)NBKT * NCHUNK * sizeof(int));
    int* offmat = (int*)(ws + c1);                size_t c2 = align256(c1 + (size_t)NBKT * NCHUNK * sizeof(int));
    int* totals = (int*)(ws + c2);                size_t c3 = align256(c2 + (size_t)NBKT * sizeof(int));
    int* bases  = (int*)(ws + c3);                size_t c4 = align256(c3 + (size_t)NBKT * sizeof(int));
    unsigned char* hbf = (unsigned char*)(ws + coff);  size_t h1 = align256(coff + (size_t)N_NODES * 20);
    unsigned char* wbuf = (unsigned char*)(ws + h1);   size_t h2 = align256(h1 + 14400);
    size_t need = (c4 > h2) ? c4 : h2;
    const bool use_fast = (ws_size >= need);

    float* hbuf = (float*)d_out;
    const int edge_blocks = E2 / 256;                 // 12500
    const int node_blocks = (N_NODES + 255) / 256;    // 391

    if (use_fast) {
        binhist_kernel<<<NCHUNK, 256, 0, stream>>>(edges, cntmat);
        bucketscan_kernel<<<NBKT, 256, 0, stream>>>(cntmat, offmat, totals);
        basescan_kernel<<<1, 512, 0, stream>>>(totals, bases);
        binscatter_kernel<<<NCHUNK, 256, 0, stream>>>(edges, offmat, bases, pairsLL);
        bucketsort_kernel<<<NBKT, 256, 0, stream>>>(totals, bases, pairsLL);
        prep_weights_kernel<<<4, 256, 0, stream>>>(W1, b1, W2, W3, b3, wbuf);
        convert_h_kernel<<<node_blocks, 256, 0, stream>>>(node_features, hbf);
    }

    // one memset clears the 0xAA poison; gru re-zeros `a` each iteration
    hipMemsetAsync(a, 0, (size_t)N_NODES * H * sizeof(float), stream);

    for (int it = 0; it < 3; ++it) {
        const float* hin = (it == 0) ? node_features : hbuf;
        if (use_fast) {
            edge_mlp_mfma2_kernel<<<edge_blocks, 256, 0, stream>>>(
                hbf, pairsLL, wbuf, b2, a);
        } else {
            edge_mlp_kernel<<<edge_blocks, 256, 0, stream>>>(
                hin, edges, W1, b1, W2, b2, W3, b3, a);
        }
        gru_kernel<<<node_blocks, 256, 0, stream>>>(
            hin, a, hbuf, W_ih, b_ih, W_hh, b_hh, use_fast ? hbf : (unsigned char*)nullptr);
    }
}